// Round 9
// baseline (24831.674 us; speedup 1.0000x reference)
//
#include <hip/hip_runtime.h>

#define NB 128
#define TT 1024
#define DI 64
#define DH 512
#define DB 128
#define GZ 2048
#define KZ 576

typedef unsigned short u16;
typedef unsigned char u8;
typedef unsigned int u32;
typedef unsigned long long u64;

#if defined(__has_builtin)
#if __has_builtin(__builtin_amdgcn_fdot2)
#define HAS_FDOT2 1
#endif
#if __has_builtin(__builtin_amdgcn_sdot4)
#define HAS_SDOT4 1
#endif
#endif

typedef _Float16 half2v __attribute__((ext_vector_type(2)));

__device__ __forceinline__ float bf2f(u16 u) {
  union { u32 i; float f; } v; v.i = ((u32)u) << 16; return v.f;
}
__device__ __forceinline__ float fsig(float x) {
  return __builtin_amdgcn_rcpf(1.f + __expf(-x));
}
__device__ __forceinline__ float ftanh(float x) {
  return 1.f - 2.f * __builtin_amdgcn_rcpf(__expf(2.f * x) + 1.f);
}
__device__ __forceinline__ float dot2p(u32 w, u32 a, float acc) {
#ifdef HAS_FDOT2
  return __builtin_amdgcn_fdot2(__builtin_bit_cast(half2v, w),
                                __builtin_bit_cast(half2v, a), acc, false);
#else
  half2v hw = __builtin_bit_cast(half2v, w), ha = __builtin_bit_cast(half2v, a);
  acc = fmaf((float)hw.x, (float)ha.x, acc);
  return fmaf((float)hw.y, (float)ha.y, acc);
#endif
}
__device__ __forceinline__ int dot4i(u32 w, u32 a, int acc) {
#ifdef HAS_SDOT4
  return __builtin_amdgcn_sdot4((int)w, (int)a, acc, false);
#else
  acc += (((int)(w << 24)) >> 24) * (((int)(a << 24)) >> 24);
  acc += (((int)(w << 16)) >> 24) * (((int)(a << 16)) >> 24);
  acc += (((int)(w << 8))  >> 24) * (((int)(a << 8))  >> 24);
  acc += (((int)w) >> 24)         * (((int)a) >> 24);
  return acc;
#endif
}
__device__ __forceinline__ u32 packf16(float x, float y) {
  half2v h; h.x = (_Float16)x; h.y = (_Float16)y;
  return __builtin_bit_cast(u32, h);
}
__device__ __forceinline__ u16 f16b(float x) {
  _Float16 h = (_Float16)x;
  return __builtin_bit_cast(u16, h);
}

// ---- ws layout (bytes, 256-aligned); GATE-INTERLEAVED content ----
#define O_WZX  256                       // wzxG: [k2][u] uint4 (4 gates f16-pairs): 32*2048 u32
#define O_WZ8  (O_WZX + 262144)          // wzG: [q][u] uint4 (4 gates i8-quads): 128*2048 u32
#define O_SWZ  (O_WZ8 + 1048576)         // swzG: [u][g] f32[2048]
#define O_BB8  (O_SWZ + 8192)            // bb i8 quads: 144*128 u32 (unchanged)
#define O_SBB  (O_BB8 + 73728)           // bb weight scales: f32[128]
#define O_FF8  (O_SBB + 512)             // ffG: [l][u] uint4 (4 mats): 32*2048 u32
#define O_SFF  (O_FF8 + 262144)          // sffG: [u][mat] f32[2048]
#define O_BIF  (O_SFF + 8192)            // bi f32[2048]
#define O_FFB  (O_BIF + 8192)            // ff biases f32[4*512]
#define O_BBBF (O_FFB + 8192)            // bbb f32[128]
#define O_HWP  (O_BBBF + 512)            // head pairs u32[512]
#define O_HBF  (O_HWP + 2048)            // hb f32[2]
#define WS_NEED ((u64)(O_HBF + 256))     // ~1.68 MB

// ---------------- dtype detection (validated rounds 3-8) ----------------
__global__ void detect_kernel(const u16* x, const u16* wi, const u16* wh, int* flag) {
  const int l = threadIdx.x;
  int cnt = (((x[2 * l] >> 7) & 0xFF) < 134)
          + (((wi[2 * l] >> 7) & 0xFF) < 134)
          + (((wh[2 * l] >> 7) & 0xFF) < 134);
#pragma unroll
  for (int off = 32; off > 0; off >>= 1) cnt += __shfl_down(cnt, off, 64);
  if (l == 0) *flag = (cnt >= 180) ? 1 : 0;
}

__device__ __forceinline__ float ldf(int f, const void* s, u32 i) {
  return f ? bf2f(((const u16*)s)[i]) : ((const float*)s)[i];
}

// ---- prep: Wz x-part f16 pairs, gate-interleaved ----
__global__ void pwzx_kernel(const void* Wi, const int* __restrict__ flag,
                            u32* __restrict__ wzxG) {
  const int o = blockIdx.x * 256 + threadIdx.x;   // z-row 0..2047
  const int k2 = blockIdx.y;
  const int f = *flag;
  const u32 i = (u32)o * DI + 2 * k2;
  wzxG[(u32)k2 * GZ + (((u32)(o & 511)) << 2) + (o >> 9)] =
      packf16(ldf(f, Wi, i), ldf(f, Wi, i + 1));
}

// ---- prep: Wz h-part -> i8, gate-interleaved; per-row scale ----
__global__ void qwz_kernel(const void* Wh, const int* __restrict__ flag,
                           u32* __restrict__ wzG, float* __restrict__ swzG) {
  const int o = blockIdx.x;       // z-row 0..2047
  const int l = threadIdx.x;
  const int f = *flag;
  float w[8]; float mx = 0.f;
#pragma unroll
  for (int qq = 0; qq < 2; ++qq) {
    const int q = l + 64 * qq;
#pragma unroll
    for (int e = 0; e < 4; ++e) {
      const float v = ldf(f, Wh, (u32)o * DH + 4 * q + e);
      w[qq * 4 + e] = v; mx = fmaxf(mx, fabsf(v));
    }
  }
#pragma unroll
  for (int off = 32; off > 0; off >>= 1) mx = fmaxf(mx, __shfl_xor(mx, off, 64));
  mx = fmaxf(mx, 1e-20f);
  const float inv = 127.f / mx;
  if (l == 0) swzG[(((u32)(o & 511)) << 2) + (o >> 9)] = mx / (127.f * 127.f);
#pragma unroll
  for (int qq = 0; qq < 2; ++qq) {
    const int q = l + 64 * qq;
    u32 p = 0;
#pragma unroll
    for (int e = 0; e < 4; ++e) {
      int b = (int)rintf(w[qq * 4 + e] * inv);
      b = b > 127 ? 127 : (b < -127 ? -127 : b);
      p |= ((u32)(b & 0xff)) << (8 * e);
    }
    wzG[(u32)q * GZ + (((u32)(o & 511)) << 2) + (o >> 9)] = p;
  }
}

// ---- prep: backbone -> i8, per-output scale (layout unchanged) ----
__global__ void qbb_kernel(const void* bb, const int* __restrict__ flag,
                           u32* __restrict__ bb8, float* __restrict__ sbb) {
  const int m = blockIdx.x;      // 0..127
  const int l = threadIdx.x;     // 0..63
  const int f = *flag;
  float mx = 0.f;
#pragma unroll
  for (int q = 0; q < 9; ++q)
    mx = fmaxf(mx, fabsf(ldf(f, bb, (u32)m * KZ + l + 64 * q)));
#pragma unroll
  for (int off = 32; off > 0; off >>= 1) mx = fmaxf(mx, __shfl_xor(mx, off, 64));
  mx = fmaxf(mx, 1e-20f);
  const float inv = 127.f / mx;
  if (l == 0) sbb[m] = mx / 127.f;
  for (int k4 = l; k4 < 144; k4 += 64) {
    u32 p = 0;
#pragma unroll
    for (int e = 0; e < 4; ++e) {
      int b = (int)rintf(ldf(f, bb, (u32)m * KZ + 4 * k4 + e) * inv);
      b = b > 127 ? 127 : (b < -127 ? -127 : b);
      p |= ((u32)(b & 0xff)) << (8 * e);
    }
    bb8[(u32)k4 * DB + m] = p;
  }
}

// ---- prep: ff -> i8, mat-interleaved uint4 per (l, unit) ----
__global__ void qff_kernel(const void* f1, const void* f2, const void* ta,
                           const void* tb, const int* __restrict__ flag,
                           u32* __restrict__ ffG, float* __restrict__ sffG) {
  const int o = blockIdx.x;      // 0..511 (unit)
  const int mat = blockIdx.y;    // 0..3
  const int l = threadIdx.x;     // 0..31 (k4)
  const void* s = (mat == 0) ? f1 : (mat == 1) ? f2 : (mat == 2) ? ta : tb;
  const int f = *flag;
  float w[4]; float mx = 0.f;
#pragma unroll
  for (int e = 0; e < 4; ++e) {
    w[e] = ldf(f, s, (u32)o * DB + 4 * l + e);
    mx = fmaxf(mx, fabsf(w[e]));
  }
#pragma unroll
  for (int off = 16; off > 0; off >>= 1) mx = fmaxf(mx, __shfl_xor(mx, off, 32));
  mx = fmaxf(mx, 1e-20f);
  const float inv = 127.f / mx;
  if (l == 0) sffG[((u32)o << 2) + mat] = (mx / 127.f) * (1.7159f / 127.f);
  u32 p = 0;
#pragma unroll
  for (int e = 0; e < 4; ++e) {
    int b = (int)rintf(w[e] * inv);
    b = b > 127 ? 127 : (b < -127 ? -127 : b);
    p |= ((u32)(b & 0xff)) << (8 * e);
  }
  ffG[(((u32)l * 512 + o) << 2) + mat] = p;
}

__global__ void psmall_kernel(const void* bi_s, const void* f1b_s, const void* f2b_s,
                              const void* tab_s, const void* tbb_s, const void* bbb_s,
                              const void* hw_s, const void* hb_s,
                              const int* __restrict__ flag,
                              float* __restrict__ bif, float* __restrict__ ffb,
                              float* __restrict__ bbbf, u32* __restrict__ hwp,
                              float* __restrict__ hbf) {
  const int f = *flag;
  for (int i = threadIdx.x; i < 2048; i += 1024) {
    bif[i] = ldf(f, bi_s, i);
    if (i < 512) {
      ffb[i]        = ldf(f, f1b_s, i);
      ffb[512 + i]  = ldf(f, f2b_s, i);
      ffb[1024 + i] = ldf(f, tab_s, i);
      ffb[1536 + i] = ldf(f, tbb_s, i);
      const int w = i >> 8, pr = i & 255;
      hwp[i] = packf16(ldf(f, hw_s, w * DH + 2 * pr), ldf(f, hw_s, w * DH + 2 * pr + 1));
    }
    if (i < 128) bbbf[i] = ldf(f, bbb_s, i);
    if (i < 2)   hbf[i] = ldf(f, hb_s, i);
  }
}

// ---- scan16 = scan15 + Zx 4-step window (wzxG amortized 4x, f32 bit-identical)
//              + phase-2 lane-pair split with shfl combine (no new barrier) ----
__global__ __launch_bounds__(1024, 1)
void scan16(const void* __restrict__ xraw, const int* __restrict__ flagp,
            const u32* __restrict__ wzxG, const u32* __restrict__ wzG,
            const float* __restrict__ swzG,
            const u32* __restrict__ bb8, const float* __restrict__ sbb,
            const u32* __restrict__ ffG, const float* __restrict__ sffG,
            const float* __restrict__ bif, const float* __restrict__ ffbv,
            const float* __restrict__ bbbf, const u32* __restrict__ hwp,
            const float* __restrict__ hbf, float* __restrict__ out)
{
  __shared__ __align__(16) u32   ah8q[256];      // h(t-1) i8 quads [k4][row]
  __shared__ __align__(16) u32   hfR[512];       // h(t) f16 [row][unit] (u16 view)
  __shared__ __align__(16) u32   vcat8[288];     // [x|h_lstm] i8 quads [k4][row]
  __shared__ __align__(16) float sxq[2];         // per-row x quant scale
  __shared__ __align__(16) u32   Fq8[64];        // F i8 quads [k4][row]
  __shared__ __align__(16) u32   bbL[144 * DB];  // bb weights resident: 72 KB
  __shared__ __align__(16) u32   xw[256];        // window x f16 pairs [s][k2][row]
  __shared__ __align__(16) float ZxL[16384];     // Zx window [(s*2+row)*512+u][4g]: 64 KB

  const int j = threadIdx.x;
  const int b = blockIdx.x;          // rows 2b, 2b+1
  const int bf16in = *flagp;
  const int u = j & 511;

  // persistent per-unit state (j<512)
  float c0 = 0.f, c1 = 0.f;
  float bgi = 0, bgg = 0, bgf = 0, bgo = 0, cb1 = 0, cb2 = 0, cba = 0, cbb = 0;
  float4 zscl = make_float4(0, 0, 0, 0), sfv = make_float4(0, 0, 0, 0);
  if (j < 512) {
    bgi = bif[0 * DH + u]; bgg = bif[1 * DH + u];
    bgf = bif[2 * DH + u]; bgo = bif[3 * DH + u];
    cb1 = ffbv[0 * DH + u]; cb2 = ffbv[1 * DH + u];
    cba = ffbv[2 * DH + u]; cbb = ffbv[3 * DH + u];
    zscl = *(const float4*)(swzG + 4 * u);
    sfv  = *(const float4*)(sffG + 4 * u);
  }
  float sbbr = 0.f, bbr = 0.f;
  if (j < 256) { sbbr = sbb[j >> 1]; bbr = bbbf[j >> 1]; }
  u32 hwreg[4] = {0, 0, 0, 0}; float hbr = 0.f;
  int hrow = 0, hw_ = 0, hl = 0;
  if (j >= 512 && j < 768) {
    const int jj = j - 512;
    hrow = jj >> 7; hw_ = (jj >> 6) & 1; hl = jj & 63;
#pragma unroll
    for (int i = 0; i < 4; ++i) hwreg[i] = hwp[hw_ * 256 + hl + 64 * i];
    hbr = hbf[hw_];
  }
  const float C127 = 1.f / 127.f;

  // ---- bb weights resident in LDS (once) ----
  for (int i = j; i < 144 * DB; i += 1024) bbL[i] = bb8[i];

  // ---- preamble: h0 = 0; stage x(0) i8 for bb ----
  if (j < 512) { hfR[j] = 0u; if (j < 256) ah8q[j] = 0u; }
  if (j >= 512 && j < 576) {
    const int i = j - 512, xr = i >> 5, k2 = i & 31;
    const size_t xi = ((size_t)(2 * b + xr) * TT + 0) * 32 + k2;
    float a, bb_;
    if (bf16in) {
      const u32 w = ((const u32*)xraw)[xi];
      a = bf2f((u16)(w & 0xffffu)); bb_ = bf2f((u16)(w >> 16));
    } else {
      const float2 v = ((const float2*)xraw)[xi];
      a = v.x; bb_ = v.y;
    }
    float m = fmaxf(fabsf(a), fabsf(bb_));
#pragma unroll
    for (int off = 16; off > 0; off >>= 1) m = fmaxf(m, __shfl_xor(m, off, 32));
    m = fmaxf(m, 1e-20f);
    if (k2 == 0) sxq[xr] = m * C127;
    const float inv = 127.f / m;
    const int q0 = (int)rintf(a * inv), q1 = (int)rintf(bb_ * inv);
    ((u16*)vcat8)[((k2 >> 1) * 2 + xr) * 2 + (k2 & 1)] =
        (u16)((q0 & 0xff) | ((q1 & 0xff) << 8));
  }
  __syncthreads();

  for (int t = 0; t < TT; ++t) {
    // ---- window phase (every 4 steps): stage x f16 + batch Zx for 4 steps ----
    if ((t & 3) == 0) {
      if (j < 256) {
        const int s = j >> 6, i = j & 63, xr = i >> 5, k2 = i & 31;
        const size_t xi = ((size_t)(2 * b + xr) * TT + (t + s)) * 32 + k2;
        float a, bb_;
        if (bf16in) {
          const u32 w = ((const u32*)xraw)[xi];
          a = bf2f((u16)(w & 0xffffu)); bb_ = bf2f((u16)(w >> 16));
        } else {
          const float2 v = ((const float2*)xraw)[xi];
          a = v.x; bb_ = v.y;
        }
        xw[s * 64 + k2 * 2 + xr] = packf16(a, bb_);
      }
      __syncthreads();                               // Bw1: xw ready
      if (j < 512) {
        float4 a0r0 = {0,0,0,0}, a0r1 = {0,0,0,0};
        float4 a1r0 = {0,0,0,0}, a1r1 = {0,0,0,0};
        float4 a2r0 = {0,0,0,0}, a2r1 = {0,0,0,0};
        float4 a3r0 = {0,0,0,0}, a3r1 = {0,0,0,0};
        const u32* wpx = wzxG + 4 * u;
#pragma unroll 4
        for (int k2 = 0; k2 < 32; ++k2) {
          const uint4 w = *(const uint4*)wpx; wpx += GZ;
          u32 a;
          a = xw[k2 * 2 + 0];
          a0r0.x = dot2p(w.x, a, a0r0.x); a0r0.y = dot2p(w.y, a, a0r0.y);
          a0r0.z = dot2p(w.z, a, a0r0.z); a0r0.w = dot2p(w.w, a, a0r0.w);
          a = xw[k2 * 2 + 1];
          a0r1.x = dot2p(w.x, a, a0r1.x); a0r1.y = dot2p(w.y, a, a0r1.y);
          a0r1.z = dot2p(w.z, a, a0r1.z); a0r1.w = dot2p(w.w, a, a0r1.w);
          a = xw[64 + k2 * 2 + 0];
          a1r0.x = dot2p(w.x, a, a1r0.x); a1r0.y = dot2p(w.y, a, a1r0.y);
          a1r0.z = dot2p(w.z, a, a1r0.z); a1r0.w = dot2p(w.w, a, a1r0.w);
          a = xw[64 + k2 * 2 + 1];
          a1r1.x = dot2p(w.x, a, a1r1.x); a1r1.y = dot2p(w.y, a, a1r1.y);
          a1r1.z = dot2p(w.z, a, a1r1.z); a1r1.w = dot2p(w.w, a, a1r1.w);
          a = xw[128 + k2 * 2 + 0];
          a2r0.x = dot2p(w.x, a, a2r0.x); a2r0.y = dot2p(w.y, a, a2r0.y);
          a2r0.z = dot2p(w.z, a, a2r0.z); a2r0.w = dot2p(w.w, a, a2r0.w);
          a = xw[128 + k2 * 2 + 1];
          a2r1.x = dot2p(w.x, a, a2r1.x); a2r1.y = dot2p(w.y, a, a2r1.y);
          a2r1.z = dot2p(w.z, a, a2r1.z); a2r1.w = dot2p(w.w, a, a2r1.w);
          a = xw[192 + k2 * 2 + 0];
          a3r0.x = dot2p(w.x, a, a3r0.x); a3r0.y = dot2p(w.y, a, a3r0.y);
          a3r0.z = dot2p(w.z, a, a3r0.z); a3r0.w = dot2p(w.w, a, a3r0.w);
          a = xw[192 + k2 * 2 + 1];
          a3r1.x = dot2p(w.x, a, a3r1.x); a3r1.y = dot2p(w.y, a, a3r1.y);
          a3r1.z = dot2p(w.z, a, a3r1.z); a3r1.w = dot2p(w.w, a, a3r1.w);
        }
        *(float4*)(ZxL + 0 * 2048 + 4 * u) = a0r0;
        *(float4*)(ZxL + 1 * 2048 + 4 * u) = a0r1;
        *(float4*)(ZxL + 2 * 2048 + 4 * u) = a1r0;
        *(float4*)(ZxL + 3 * 2048 + 4 * u) = a1r1;
        *(float4*)(ZxL + 4 * 2048 + 4 * u) = a2r0;
        *(float4*)(ZxL + 5 * 2048 + 4 * u) = a2r1;
        *(float4*)(ZxL + 6 * 2048 + 4 * u) = a3r0;
        *(float4*)(ZxL + 7 * 2048 + 4 * u) = a3r1;
      }
      __syncthreads();                               // Bw2: ZxL ready
    }

    // ---- phase 1: Z h-part (4 gates, both rows) + Zx from LDS + gates ----
    if (j < 512) {
      int ii0 = 0, ig0 = 0, if0 = 0, io0 = 0, ii1 = 0, ig1 = 0, if1 = 0, io1 = 0;
      const u32* wph = wzG + 4 * u;
#pragma unroll 8
      for (int q = 0; q < 128; ++q) {
        const uint4 w = *(const uint4*)wph; wph += GZ;
        const u32 a0 = ah8q[q * 2 + 0], a1 = ah8q[q * 2 + 1];
        ii0 = dot4i(w.x, a0, ii0); ig0 = dot4i(w.y, a0, ig0);
        if0 = dot4i(w.z, a0, if0); io0 = dot4i(w.w, a0, io0);
        ii1 = dot4i(w.x, a1, ii1); ig1 = dot4i(w.y, a1, ig1);
        if1 = dot4i(w.z, a1, if1); io1 = dot4i(w.w, a1, io1);
      }
      const float4 zx0 = *(const float4*)(ZxL + ((t & 3) * 2 + 0) * 2048 + 4 * u);
      const float4 zx1 = *(const float4*)(ZxL + ((t & 3) * 2 + 1) * 2048 + 4 * u);
      const float zi0 = bgi + zx0.x + zscl.x * (float)ii0;
      const float zg0 = bgg + zx0.y + zscl.y * (float)ig0;
      const float zf0 = bgf + zx0.z + zscl.z * (float)if0;
      const float zo0 = bgo + zx0.w + zscl.w * (float)io0;
      const float zi1 = bgi + zx1.x + zscl.x * (float)ii1;
      const float zg1 = bgg + zx1.y + zscl.y * (float)ig1;
      const float zf1 = bgf + zx1.z + zscl.z * (float)if1;
      const float zo1 = bgo + zx1.w + zscl.w * (float)io1;
      c0 = fmaf(c0, fsig(zf0 + 1.f), ftanh(zi0) * fsig(zg0));
      c1 = fmaf(c1, fsig(zf1 + 1.f), ftanh(zi1) * fsig(zg1));
      const float hl0 = ftanh(c0) * fsig(zo0);
      const float hl1 = ftanh(c1) * fsig(zo1);
      const int q0 = (int)rintf(hl0 * 127.f), q1 = (int)rintf(hl1 * 127.f);
      ((u8*)vcat8)[((16 + (u >> 2)) * 2 + 0) * 4 + (u & 3)] = (u8)(q0 & 0xff);
      ((u8*)vcat8)[((16 + (u >> 2)) * 2 + 1) * 4 + (u & 3)] = (u8)(q1 & 0xff);
    }
    __syncthreads();                                   // B1: h_lstm ready

    // ---- phase 2: backbone + F, lane-pair split (m=j>>1, s2=j&1), shfl combine ----
    if (j < 256) {
      const int m = j >> 1, s2 = j & 1;
      const int qb = s2 * 72;
      int aA0 = 0, aA1 = 0, aB0 = 0, aB1 = 0;
      const u32* bp = bbL + m;
#pragma unroll
      for (int q = 0; q < 16; ++q) {
        const u32 w = bp[(qb + q) * DB];
        aA0 = dot4i(w, vcat8[(qb + q) * 2 + 0], aA0);
        aA1 = dot4i(w, vcat8[(qb + q) * 2 + 1], aA1);
      }
#pragma unroll 14
      for (int q = 16; q < 72; ++q) {
        const u32 w = bp[(qb + q) * DB];
        aB0 = dot4i(w, vcat8[(qb + q) * 2 + 0], aB0);
        aB1 = dot4i(w, vcat8[(qb + q) * 2 + 1], aB1);
      }
      // s2==0: chunk quads 0..71 (first 16 are x-part) ; s2==1: quads 72..143 (all h)
      const int ax0 = s2 ? 0 : aA0, ax1 = s2 ? 0 : aA1;
      const int ah0 = s2 ? (aA0 + aB0) : aB0;
      const int ah1 = s2 ? (aA1 + aB1) : aB1;
      const int axp0 = __shfl_xor(ax0, 1, 64), axp1 = __shfl_xor(ax1, 1, 64);
      const int ahp0 = __shfl_xor(ah0, 1, 64), ahp1 = __shfl_xor(ah1, 1, 64);
      if (s2 == 0) {
        const int AX0 = ax0 + axp0, AX1 = ax1 + axp1;
        const int AH0 = ah0 + ahp0, AH1 = ah1 + ahp1;
        const float r0 = bbr + sbbr * (sxq[0] * (float)AX0 + C127 * (float)AH0);
        const float r1 = bbr + sbbr * (sxq[1] * (float)AX1 + C127 * (float)AH1);
        const float F0 = 1.7159f * ftanh(0.666f * r0);
        const float F1 = 1.7159f * ftanh(0.666f * r1);
        const int q0 = (int)rintf(F0 * (127.f / 1.7159f));
        const int q1 = (int)rintf(F1 * (127.f / 1.7159f));
        ((u8*)Fq8)[((m >> 2) * 2 + 0) * 4 + (m & 3)] = (u8)(q0 & 0xff);
        ((u8*)Fq8)[((m >> 2) * 2 + 1) * 4 + (m & 3)] = (u8)(q1 & 0xff);
      }
    }
    __syncthreads();                                   // B2: F ready

    // ---- phase 3: ff (4 mats) + combine fused || stage x(t+1) i8 ----
    if (j < 512) {
      int a10 = 0, a20 = 0, aa0 = 0, ab0 = 0, a11 = 0, a21 = 0, aa1 = 0, ab1 = 0;
      const u32* fw = ffG + 4 * u;
#pragma unroll 8
      for (int l = 0; l < 32; ++l) {
        const uint4 w = *(const uint4*)fw; fw += GZ;
        const u32 F0v = Fq8[l * 2 + 0], F1v = Fq8[l * 2 + 1];
        a10 = dot4i(w.x, F0v, a10); a20 = dot4i(w.y, F0v, a20);
        aa0 = dot4i(w.z, F0v, aa0); ab0 = dot4i(w.w, F0v, ab0);
        a11 = dot4i(w.x, F1v, a11); a21 = dot4i(w.y, F1v, a21);
        aa1 = dot4i(w.z, F1v, aa1); ab1 = dot4i(w.w, F1v, ab1);
      }
      const float z10 = sfv.x * (float)a10 + cb1, z20 = sfv.y * (float)a20 + cb2;
      const float za0 = sfv.z * (float)aa0 + cba, zb0 = sfv.w * (float)ab0 + cbb;
      const float z11 = sfv.x * (float)a11 + cb1, z21 = sfv.y * (float)a21 + cb2;
      const float za1 = sfv.z * (float)aa1 + cba, zb1 = sfv.w * (float)ab1 + cbb;
      const float ti0 = fsig(za0 + zb0), ti1 = fsig(za1 + zb1);
      const float hn0 = fmaf(ftanh(z10), 1.f - ti0, ti0 * ftanh(z20));
      const float hn1 = fmaf(ftanh(z11), 1.f - ti1, ti1 * ftanh(z21));
      ((u16*)hfR)[u] = f16b(hn0);
      ((u16*)hfR)[512 + u] = f16b(hn1);
      const int q0 = (int)rintf(hn0 * 127.f), q1 = (int)rintf(hn1 * 127.f);
      ((u8*)ah8q)[((u >> 2) * 2 + 0) * 4 + (u & 3)] = (u8)(q0 & 0xff);
      ((u8*)ah8q)[((u >> 2) * 2 + 1) * 4 + (u & 3)] = (u8)(q1 & 0xff);
      if (t == TT - 1) {
        out[(size_t)NB * TT * 2 + (size_t)(2 * b + 0) * DH + u] = hn0;
        out[(size_t)NB * TT * 2 + (size_t)(2 * b + 1) * DH + u] = hn1;
      }
    } else if (j < 576 && t + 1 < TT) {
      const int i = j - 512, xr = i >> 5, k2 = i & 31;
      const size_t xi = ((size_t)(2 * b + xr) * TT + (t + 1)) * 32 + k2;
      float a, bb_;
      if (bf16in) {
        const u32 w = ((const u32*)xraw)[xi];
        a = bf2f((u16)(w & 0xffffu)); bb_ = bf2f((u16)(w >> 16));
      } else {
        const float2 v = ((const float2*)xraw)[xi];
        a = v.x; bb_ = v.y;
      }
      float m = fmaxf(fabsf(a), fabsf(bb_));
#pragma unroll
      for (int off = 16; off > 0; off >>= 1) m = fmaxf(m, __shfl_xor(m, off, 32));
      m = fmaxf(m, 1e-20f);
      if (k2 == 0) sxq[xr] = m * C127;
      const float inv = 127.f / m;
      const int q0 = (int)rintf(a * inv), q1 = (int)rintf(bb_ * inv);
      ((u16*)vcat8)[((k2 >> 1) * 2 + xr) * 2 + (k2 & 1)] =
          (u16)((q0 & 0xff) | ((q1 & 0xff) << 8));
    }
    __syncthreads();                                   // B3: h_new + x(t+1) ready

    // ---- phase 4: head (waves 8-11), runs in the shadow of next phase 1 ----
    if (j >= 512 && j < 768) {
      float acc = 0.f;
#pragma unroll
      for (int i = 0; i < 4; ++i)
        acc = dot2p(hwreg[i], hfR[hrow * 256 + hl + 64 * i], acc);
#pragma unroll
      for (int off = 32; off > 0; off >>= 1) acc += __shfl_down(acc, off, 64);
      if (hl == 0) out[((size_t)(2 * b + hrow) * TT + t) * 2 + hw_] = acc + hbr;
    }
  }
}

// ---------------- fallback (round-3 verified, bf16 d_in, small ws) ----------------
__device__ __forceinline__ void fma8(float& acc, const uint4 u, const float* v) {
  union { u32 i; float f; } tt;
  tt.i = u.x << 16;          acc = fmaf(tt.f, v[0], acc);
  tt.i = u.x & 0xffff0000u;  acc = fmaf(tt.f, v[1], acc);
  tt.i = u.y << 16;          acc = fmaf(tt.f, v[2], acc);
  tt.i = u.y & 0xffff0000u;  acc = fmaf(tt.f, v[3], acc);
  tt.i = u.z << 16;          acc = fmaf(tt.f, v[4], acc);
  tt.i = u.z & 0xffff0000u;  acc = fmaf(tt.f, v[5], acc);
  tt.i = u.w << 16;          acc = fmaf(tt.f, v[6], acc);
  tt.i = u.w & 0xffff0000u;  acc = fmaf(tt.f, v[7], acc);
}
__global__ __launch_bounds__(256, 1)
void fb_scan(const u16* __restrict__ x,   const u16* __restrict__ Wi,
             const u16* __restrict__ bi,  const u16* __restrict__ Wh,
             const u16* __restrict__ bbW, const u16* __restrict__ bbb,
             const u16* __restrict__ f1W, const u16* __restrict__ f1b,
             const u16* __restrict__ f2W, const u16* __restrict__ f2b,
             const u16* __restrict__ taW, const u16* __restrict__ tab,
             const u16* __restrict__ tbW, const u16* __restrict__ tbb,
             const u16* __restrict__ hW,  const u16* __restrict__ hb,
             float* __restrict__ out)
{
  __shared__ __align__(16) float vcat[DI + DH];
  __shared__ __align__(16) float Fb2[DB];
  __shared__ __align__(16) float fpart[256];
  __shared__ __align__(16) float hprev[DH];
  const int j = threadIdx.x, b = blockIdx.x;
  const int u0 = j, u1 = j + 256;
  float bi_r[8];
#pragma unroll
  for (int k = 0; k < 8; ++k) bi_r[k] = bf2f(bi[j + 256 * k]);
  const float b_f1_0 = bf2f(f1b[u0]), b_f1_1 = bf2f(f1b[u1]);
  const float b_f2_0 = bf2f(f2b[u0]), b_f2_1 = bf2f(f2b[u1]);
  const float b_ta_0 = bf2f(tab[u0]), b_ta_1 = bf2f(tab[u1]);
  const float b_tb_0 = bf2f(tbb[u0]), b_tb_1 = bf2f(tbb[u1]);
  const float b_bb = (j < DB) ? bf2f(bbb[j]) : 0.f;
  float hwr[8]; float hbr = 0.f;
  if (j < 128) {
    const int w = j >> 6, l = j & 63;
#pragma unroll
    for (int q = 0; q < 8; ++q) hwr[q] = bf2f(hW[w * DH + q * 64 + l]);
    hbr = bf2f(hb[w]);
  }
  float c0 = 0.f, c1 = 0.f;
  hprev[u0] = 0.f; hprev[u1] = 0.f;
  const u16* xp = x + (size_t)b * TT * DI;
  __syncthreads();
  for (int t = 0; t < TT; ++t) {
    if (j < DI) vcat[j] = bf2f(xp[t * DI + j]);
    __syncthreads();
    float a[8];
#pragma unroll
    for (int k = 0; k < 8; ++k) a[k] = bi_r[k];
#pragma unroll
    for (int r = 0; r < 8; ++r) {
      const u16* wr = Wi + ((size_t)(j + 256 * r)) * DI;
      float acc = a[r];
#pragma unroll
      for (int kk = 0; kk < DI; kk += 8) fma8(acc, *(const uint4*)(wr + kk), vcat + kk);
      a[r] = acc;
    }
#pragma unroll 1
    for (int kb = 0; kb < DH; kb += 64) {
      float hreg[64];
#pragma unroll
      for (int q = 0; q < 16; ++q)
        *(float4*)(hreg + 4 * q) = *(const float4*)(hprev + kb + 4 * q);
#pragma unroll
      for (int r = 0; r < 8; ++r) {
        const u16* wr = Wh + ((size_t)(j + 256 * r)) * DH + kb;
        float acc = a[r];
#pragma unroll
        for (int cc = 0; cc < 8; ++cc) fma8(acc, *(const uint4*)(wr + 8 * cc), hreg + 8 * cc);
        a[r] = acc;
      }
    }
    {
      const float cn0 = fmaf(c0, fsig(a[4] + 1.f), ftanh(a[0]) * fsig(a[2]));
      const float cn1 = fmaf(c1, fsig(a[5] + 1.f), ftanh(a[1]) * fsig(a[3]));
      c0 = cn0; c1 = cn1;
      vcat[DI + u0] = ftanh(cn0) * fsig(a[6]);
      vcat[DI + u1] = ftanh(cn1) * fsig(a[7]);
    }
    __syncthreads();
    {
      const int mm = j & (DB - 1), pp = j >> 7;
      const u16* br = bbW + (size_t)mm * KZ + pp * 288;
      const float* vs = vcat + pp * 288;
      float s0 = 0.f, s1 = 0.f, s2v = 0.f, s3 = 0.f;
#pragma unroll
      for (int kk = 0; kk < 288; kk += 32) {
        fma8(s0, *(const uint4*)(br + kk), vs + kk);
        fma8(s1, *(const uint4*)(br + kk + 8), vs + kk + 8);
        fma8(s2v, *(const uint4*)(br + kk + 16), vs + kk + 16);
        fma8(s3, *(const uint4*)(br + kk + 24), vs + kk + 24);
      }
      fpart[j] = (s0 + s1) + (s2v + s3);
    }
    __syncthreads();
    if (j < DB) Fb2[j] = 1.7159f * ftanh(0.666f * (b_bb + fpart[j] + fpart[j + DB]));
    __syncthreads();
    {
      float Fr[DB];
#pragma unroll
      for (int q = 0; q < 32; ++q) *(float4*)(Fr + 4 * q) = *(const float4*)(Fb2 + 4 * q);
      const u16* rp[8] = {
        f1W + (size_t)u0 * DB, f1W + (size_t)u1 * DB,
        f2W + (size_t)u0 * DB, f2W + (size_t)u1 * DB,
        taW + (size_t)u0 * DB, taW + (size_t)u1 * DB,
        tbW + (size_t)u0 * DB, tbW + (size_t)u1 * DB };
      float sacc[8] = { b_f1_0, b_f1_1, b_f2_0, b_f2_1, b_ta_0, b_ta_1, b_tb_0, b_tb_1 };
#pragma unroll
      for (int rr = 0; rr < 8; ++rr) {
        float acc = sacc[rr];
        const u16* r = rp[rr];
#pragma unroll
        for (int kk = 0; kk < DB; kk += 8) fma8(acc, *(const uint4*)(r + kk), Fr + kk);
        sacc[rr] = acc;
      }
      const float ti0 = fsig(sacc[4] + sacc[6]);
      const float ti1 = fsig(sacc[5] + sacc[7]);
      hprev[u0] = fmaf(ftanh(sacc[0]), 1.f - ti0, ti0 * ftanh(sacc[2]));
      hprev[u1] = fmaf(ftanh(sacc[1]), 1.f - ti1, ti1 * ftanh(sacc[3]));
    }
    __syncthreads();
    if (j < 128) {
      const int l = j & 63;
      float acc = 0.f;
#pragma unroll
      for (int q = 0; q < 8; ++q) acc = fmaf(hprev[q * 64 + l], hwr[q], acc);
#pragma unroll
      for (int off = 32; off > 0; off >>= 1) acc += __shfl_down(acc, off, 64);
      if (l == 0) out[((size_t)b * TT + t) * 2 + (j >> 6)] = acc + hbr;
    }
  }
  out[(size_t)NB * TT * 2 + (size_t)b * DH + u0] = hprev[u0];
  out[(size_t)NB * TT * 2 + (size_t)b * DH + u1] = hprev[u1];
}

extern "C" void kernel_launch(void* const* d_in, const int* in_sizes, int n_in,
                              void* d_out, int out_size, void* d_ws, size_t ws_size,
                              hipStream_t stream) {
  (void)in_sizes; (void)n_in; (void)out_size;

  if (ws_size >= WS_NEED) {
    char* ws = (char*)d_ws;
    int* flag = (int*)ws;
    detect_kernel<<<dim3(1), dim3(64), 0, stream>>>(
        (const u16*)d_in[0], (const u16*)d_in[1], (const u16*)d_in[3], flag);
    pwzx_kernel<<<dim3(8, 32), dim3(256), 0, stream>>>(d_in[1], flag, (u32*)(ws + O_WZX));
    qwz_kernel<<<dim3(2048), dim3(64), 0, stream>>>(d_in[3], flag,
                                                    (u32*)(ws + O_WZ8), (float*)(ws + O_SWZ));
    qbb_kernel<<<dim3(128), dim3(64), 0, stream>>>(d_in[4], flag,
                                                   (u32*)(ws + O_BB8), (float*)(ws + O_SBB));
    qff_kernel<<<dim3(512, 4), dim3(32), 0, stream>>>(d_in[6], d_in[8], d_in[10],
                                                      d_in[12], flag,
                                                      (u32*)(ws + O_FF8), (float*)(ws + O_SFF));
    psmall_kernel<<<dim3(1), dim3(1024), 0, stream>>>(
        d_in[2], d_in[7], d_in[9], d_in[11], d_in[13], d_in[5], d_in[14], d_in[15],
        flag, (float*)(ws + O_BIF), (float*)(ws + O_FFB), (float*)(ws + O_BBBF),
        (u32*)(ws + O_HWP), (float*)(ws + O_HBF));

    scan16<<<dim3(64), dim3(1024), 0, stream>>>(
        d_in[0], flag,
        (const u32*)(ws + O_WZX), (const u32*)(ws + O_WZ8), (const float*)(ws + O_SWZ),
        (const u32*)(ws + O_BB8), (const float*)(ws + O_SBB),
        (const u32*)(ws + O_FF8), (const float*)(ws + O_SFF),
        (const float*)(ws + O_BIF), (const float*)(ws + O_FFB),
        (const float*)(ws + O_BBBF), (const u32*)(ws + O_HWP),
        (const float*)(ws + O_HBF), (float*)d_out);
  } else {
    fb_scan<<<dim3(NB), dim3(256), 0, stream>>>(
        (const u16*)d_in[0],  (const u16*)d_in[1],  (const u16*)d_in[2],
        (const u16*)d_in[3],  (const u16*)d_in[4],  (const u16*)d_in[5],
        (const u16*)d_in[6],  (const u16*)d_in[7],  (const u16*)d_in[8],
        (const u16*)d_in[9],  (const u16*)d_in[10], (const u16*)d_in[11],
        (const u16*)d_in[12], (const u16*)d_in[13], (const u16*)d_in[14],
        (const u16*)d_in[15], (float*)d_out);
  }
}

// Round 10
// 14736.389 us; speedup vs baseline: 1.6851x; 1.6851x over previous
//
#include <hip/hip_runtime.h>

#define NB 128
#define TT 1024
#define DI 64
#define DH 512
#define DB 128
#define GZ 2048
#define KZ 576

typedef unsigned short u16;
typedef unsigned char u8;
typedef unsigned int u32;
typedef unsigned long long u64;

#if defined(__has_builtin)
#if __has_builtin(__builtin_amdgcn_fdot2)
#define HAS_FDOT2 1
#endif
#if __has_builtin(__builtin_amdgcn_sdot4)
#define HAS_SDOT4 1
#endif
#endif

typedef _Float16 half2v __attribute__((ext_vector_type(2)));

__device__ __forceinline__ float bf2f(u16 u) {
  union { u32 i; float f; } v; v.i = ((u32)u) << 16; return v.f;
}
__device__ __forceinline__ float fsig(float x) {
  return __builtin_amdgcn_rcpf(1.f + __expf(-x));
}
__device__ __forceinline__ float ftanh(float x) {
  return 1.f - 2.f * __builtin_amdgcn_rcpf(__expf(2.f * x) + 1.f);
}
__device__ __forceinline__ float dot2p(u32 w, u32 a, float acc) {
#ifdef HAS_FDOT2
  return __builtin_amdgcn_fdot2(__builtin_bit_cast(half2v, w),
                                __builtin_bit_cast(half2v, a), acc, false);
#else
  half2v hw = __builtin_bit_cast(half2v, w), ha = __builtin_bit_cast(half2v, a);
  acc = fmaf((float)hw.x, (float)ha.x, acc);
  return fmaf((float)hw.y, (float)ha.y, acc);
#endif
}
__device__ __forceinline__ int dot4i(u32 w, u32 a, int acc) {
#ifdef HAS_SDOT4
  return __builtin_amdgcn_sdot4((int)w, (int)a, acc, false);
#else
  acc += (((int)(w << 24)) >> 24) * (((int)(a << 24)) >> 24);
  acc += (((int)(w << 16)) >> 24) * (((int)(a << 16)) >> 24);
  acc += (((int)(w << 8))  >> 24) * (((int)(a << 8))  >> 24);
  acc += (((int)w) >> 24)         * (((int)a) >> 24);
  return acc;
#endif
}
__device__ __forceinline__ u32 packf16(float x, float y) {
  half2v h; h.x = (_Float16)x; h.y = (_Float16)y;
  return __builtin_bit_cast(u32, h);
}
__device__ __forceinline__ u16 f16b(float x) {
  _Float16 h = (_Float16)x;
  return __builtin_bit_cast(u16, h);
}

// ---- ws layout (bytes, 256-aligned); GATE-INTERLEAVED content ----
#define O_WZX  256                       // wzxG: [k2][u] uint4 (4 gates f16-pairs): 32*2048 u32
#define O_WZ8  (O_WZX + 262144)          // wzG: [q][u] uint4 (4 gates i8-quads): 128*2048 u32
#define O_SWZ  (O_WZ8 + 1048576)         // swzG: [u][g] f32[2048]
#define O_BB8  (O_SWZ + 8192)            // bb i8 quads: 144*128 u32 (unchanged)
#define O_SBB  (O_BB8 + 73728)           // bb weight scales: f32[128]
#define O_FF8  (O_SBB + 512)             // ffG: [l][u] uint4 (4 mats): 32*2048 u32
#define O_SFF  (O_FF8 + 262144)          // sffG: [u][mat] f32[2048]
#define O_BIF  (O_SFF + 8192)            // bi f32[2048]
#define O_FFB  (O_BIF + 8192)            // ff biases f32[4*512]
#define O_BBBF (O_FFB + 8192)            // bbb f32[128]
#define O_HWP  (O_BBBF + 512)            // head pairs u32[512]
#define O_HBF  (O_HWP + 2048)            // hb f32[2]
#define WS_NEED ((u64)(O_HBF + 256))     // ~1.68 MB

// ---------------- dtype detection (validated rounds 3-8) ----------------
__global__ void detect_kernel(const u16* x, const u16* wi, const u16* wh, int* flag) {
  const int l = threadIdx.x;
  int cnt = (((x[2 * l] >> 7) & 0xFF) < 134)
          + (((wi[2 * l] >> 7) & 0xFF) < 134)
          + (((wh[2 * l] >> 7) & 0xFF) < 134);
#pragma unroll
  for (int off = 32; off > 0; off >>= 1) cnt += __shfl_down(cnt, off, 64);
  if (l == 0) *flag = (cnt >= 180) ? 1 : 0;
}

__device__ __forceinline__ float ldf(int f, const void* s, u32 i) {
  return f ? bf2f(((const u16*)s)[i]) : ((const float*)s)[i];
}

// ---- prep: Wz x-part f16 pairs, gate-interleaved ----
__global__ void pwzx_kernel(const void* Wi, const int* __restrict__ flag,
                            u32* __restrict__ wzxG) {
  const int o = blockIdx.x * 256 + threadIdx.x;   // z-row 0..2047
  const int k2 = blockIdx.y;
  const int f = *flag;
  const u32 i = (u32)o * DI + 2 * k2;
  wzxG[(u32)k2 * GZ + (((u32)(o & 511)) << 2) + (o >> 9)] =
      packf16(ldf(f, Wi, i), ldf(f, Wi, i + 1));
}

// ---- prep: Wz h-part -> i8, gate-interleaved; per-row scale ----
__global__ void qwz_kernel(const void* Wh, const int* __restrict__ flag,
                           u32* __restrict__ wzG, float* __restrict__ swzG) {
  const int o = blockIdx.x;       // z-row 0..2047
  const int l = threadIdx.x;
  const int f = *flag;
  float w[8]; float mx = 0.f;
#pragma unroll
  for (int qq = 0; qq < 2; ++qq) {
    const int q = l + 64 * qq;
#pragma unroll
    for (int e = 0; e < 4; ++e) {
      const float v = ldf(f, Wh, (u32)o * DH + 4 * q + e);
      w[qq * 4 + e] = v; mx = fmaxf(mx, fabsf(v));
    }
  }
#pragma unroll
  for (int off = 32; off > 0; off >>= 1) mx = fmaxf(mx, __shfl_xor(mx, off, 64));
  mx = fmaxf(mx, 1e-20f);
  const float inv = 127.f / mx;
  if (l == 0) swzG[(((u32)(o & 511)) << 2) + (o >> 9)] = mx / (127.f * 127.f);
#pragma unroll
  for (int qq = 0; qq < 2; ++qq) {
    const int q = l + 64 * qq;
    u32 p = 0;
#pragma unroll
    for (int e = 0; e < 4; ++e) {
      int b = (int)rintf(w[qq * 4 + e] * inv);
      b = b > 127 ? 127 : (b < -127 ? -127 : b);
      p |= ((u32)(b & 0xff)) << (8 * e);
    }
    wzG[(u32)q * GZ + (((u32)(o & 511)) << 2) + (o >> 9)] = p;
  }
}

// ---- prep: backbone -> i8, per-output scale (layout unchanged) ----
__global__ void qbb_kernel(const void* bb, const int* __restrict__ flag,
                           u32* __restrict__ bb8, float* __restrict__ sbb) {
  const int m = blockIdx.x;      // 0..127
  const int l = threadIdx.x;     // 0..63
  const int f = *flag;
  float mx = 0.f;
#pragma unroll
  for (int q = 0; q < 9; ++q)
    mx = fmaxf(mx, fabsf(ldf(f, bb, (u32)m * KZ + l + 64 * q)));
#pragma unroll
  for (int off = 32; off > 0; off >>= 1) mx = fmaxf(mx, __shfl_xor(mx, off, 64));
  mx = fmaxf(mx, 1e-20f);
  const float inv = 127.f / mx;
  if (l == 0) sbb[m] = mx / 127.f;
  for (int k4 = l; k4 < 144; k4 += 64) {
    u32 p = 0;
#pragma unroll
    for (int e = 0; e < 4; ++e) {
      int b = (int)rintf(ldf(f, bb, (u32)m * KZ + 4 * k4 + e) * inv);
      b = b > 127 ? 127 : (b < -127 ? -127 : b);
      p |= ((u32)(b & 0xff)) << (8 * e);
    }
    bb8[(u32)k4 * DB + m] = p;
  }
}

// ---- prep: ff -> i8, mat-interleaved uint4 per (l, unit) ----
__global__ void qff_kernel(const void* f1, const void* f2, const void* ta,
                           const void* tb, const int* __restrict__ flag,
                           u32* __restrict__ ffG, float* __restrict__ sffG) {
  const int o = blockIdx.x;      // 0..511 (unit)
  const int mat = blockIdx.y;    // 0..3
  const int l = threadIdx.x;     // 0..31 (k4)
  const void* s = (mat == 0) ? f1 : (mat == 1) ? f2 : (mat == 2) ? ta : tb;
  const int f = *flag;
  float w[4]; float mx = 0.f;
#pragma unroll
  for (int e = 0; e < 4; ++e) {
    w[e] = ldf(f, s, (u32)o * DB + 4 * l + e);
    mx = fmaxf(mx, fabsf(w[e]));
  }
#pragma unroll
  for (int off = 16; off > 0; off >>= 1) mx = fmaxf(mx, __shfl_xor(mx, off, 32));
  mx = fmaxf(mx, 1e-20f);
  const float inv = 127.f / mx;
  if (l == 0) sffG[((u32)o << 2) + mat] = (mx / 127.f) * (1.7159f / 127.f);
  u32 p = 0;
#pragma unroll
  for (int e = 0; e < 4; ++e) {
    int b = (int)rintf(w[e] * inv);
    b = b > 127 ? 127 : (b < -127 ? -127 : b);
    p |= ((u32)(b & 0xff)) << (8 * e);
  }
  ffG[(((u32)l * 512 + o) << 2) + mat] = p;
}

__global__ void psmall_kernel(const void* bi_s, const void* f1b_s, const void* f2b_s,
                              const void* tab_s, const void* tbb_s, const void* bbb_s,
                              const void* hw_s, const void* hb_s,
                              const int* __restrict__ flag,
                              float* __restrict__ bif, float* __restrict__ ffb,
                              float* __restrict__ bbbf, u32* __restrict__ hwp,
                              float* __restrict__ hbf) {
  const int f = *flag;
  for (int i = threadIdx.x; i < 2048; i += 1024) {
    bif[i] = ldf(f, bi_s, i);
    if (i < 512) {
      ffb[i]        = ldf(f, f1b_s, i);
      ffb[512 + i]  = ldf(f, f2b_s, i);
      ffb[1024 + i] = ldf(f, tab_s, i);
      ffb[1536 + i] = ldf(f, tbb_s, i);
      const int w = i >> 8, pr = i & 255;
      hwp[i] = packf16(ldf(f, hw_s, w * DH + 2 * pr), ldf(f, hw_s, w * DH + 2 * pr + 1));
    }
    if (i < 128) bbbf[i] = ldf(f, bbb_s, i);
    if (i < 2)   hbf[i] = ldf(f, hb_s, i);
  }
}

// ---- scan17 = scan15 (proven 15.38ms) + 4-way parallel phase 2 ----
// Phase 2 now uses 512 threads: m=j>>2 owns output m, s4=j&3 takes 36 of the
// 144 K-quads (branchless x/h accumulator select), combine via 2x shfl_xor
// (same wave, no new barrier). Int sums exact -> bit-identical to scan15.
__global__ __launch_bounds__(1024, 1)
void scan17(const void* __restrict__ xraw, const int* __restrict__ flagp,
            const u32* __restrict__ wzxG, const u32* __restrict__ wzG,
            const float* __restrict__ swzG,
            const u32* __restrict__ bb8, const float* __restrict__ sbb,
            const u32* __restrict__ ffG, const float* __restrict__ sffG,
            const float* __restrict__ bif, const float* __restrict__ ffbv,
            const float* __restrict__ bbbf, const u32* __restrict__ hwp,
            const float* __restrict__ hbf, float* __restrict__ out)
{
  __shared__ __align__(16) u32   xf16q[64];      // x(t) f16 pairs [k2][row]
  __shared__ __align__(16) u32   ah8q[256];      // h(t-1) i8 quads [k4][row]
  __shared__ __align__(16) u32   hfR[512];       // h(t) f16 [row][unit] (u16 view)
  __shared__ __align__(16) u32   vcat8[288];     // [x|h_lstm] i8 quads [k4][row]
  __shared__ __align__(16) float sxq[2];         // per-row x quant scale
  __shared__ __align__(16) u32   Fq8[64];        // F i8 quads [k4][row]
  __shared__ __align__(16) u32   bbL[144 * DB];  // bb weights resident: 72 KB

  const int j = threadIdx.x;
  const int b = blockIdx.x;          // rows 2b, 2b+1
  const int bf16in = *flagp;
  const int u = j & 511;

  // persistent per-unit state (j<512)
  float c0 = 0.f, c1 = 0.f;
  float bgi = 0, bgg = 0, bgf = 0, bgo = 0, cb1 = 0, cb2 = 0, cba = 0, cbb = 0;
  float4 zscl = make_float4(0, 0, 0, 0), sfv = make_float4(0, 0, 0, 0);
  if (j < 512) {
    bgi = bif[0 * DH + u]; bgg = bif[1 * DH + u];
    bgf = bif[2 * DH + u]; bgo = bif[3 * DH + u];
    cb1 = ffbv[0 * DH + u]; cb2 = ffbv[1 * DH + u];
    cba = ffbv[2 * DH + u]; cbb = ffbv[3 * DH + u];
    zscl = *(const float4*)(swzG + 4 * u);
    sfv  = *(const float4*)(sffG + 4 * u);
  }
  // phase-2 state: m = j>>2 (j<512), s4 = j&3
  float sbbr = 0.f, bbr = 0.f;
  if (j < 512) { sbbr = sbb[j >> 2]; bbr = bbbf[j >> 2]; }
  u32 hwreg[4] = {0, 0, 0, 0}; float hbr = 0.f;
  int hrow = 0, hw_ = 0, hl = 0;
  if (j >= 512 && j < 768) {
    const int jj = j - 512;
    hrow = jj >> 7; hw_ = (jj >> 6) & 1; hl = jj & 63;
#pragma unroll
    for (int i = 0; i < 4; ++i) hwreg[i] = hwp[hw_ * 256 + hl + 64 * i];
    hbr = hbf[hw_];
  }
  const float C127 = 1.f / 127.f;

  // ---- bb weights resident in LDS (once) ----
  for (int i = j; i < 144 * DB; i += 1024) bbL[i] = bb8[i];

  // ---- preamble: h0 = 0; stage x(0) ----
  if (j < 512) { hfR[j] = 0u; if (j < 256) ah8q[j] = 0u; }
  if (j >= 512 && j < 576) {
    const int i = j - 512, xr = i >> 5, k2 = i & 31;
    const size_t xi = ((size_t)(2 * b + xr) * TT + 0) * 32 + k2;
    float a, bb_;
    if (bf16in) {
      const u32 w = ((const u32*)xraw)[xi];
      a = bf2f((u16)(w & 0xffffu)); bb_ = bf2f((u16)(w >> 16));
    } else {
      const float2 v = ((const float2*)xraw)[xi];
      a = v.x; bb_ = v.y;
    }
    xf16q[k2 * 2 + xr] = packf16(a, bb_);
    float m = fmaxf(fabsf(a), fabsf(bb_));
#pragma unroll
    for (int off = 16; off > 0; off >>= 1) m = fmaxf(m, __shfl_xor(m, off, 32));
    m = fmaxf(m, 1e-20f);
    if (k2 == 0) sxq[xr] = m * C127;
    const float inv = 127.f / m;
    const int q0 = (int)rintf(a * inv), q1 = (int)rintf(bb_ * inv);
    ((u16*)vcat8)[((k2 >> 1) * 2 + xr) * 2 + (k2 & 1)] =
        (u16)((q0 & 0xff) | ((q1 & 0xff) << 8));
  }
  __syncthreads();

  for (int t = 0; t < TT; ++t) {
    // ---- phase 1: Z (all 4 gates, both rows) + LSTM gates, fused ----
    if (j < 512) {
      float xi0 = 0, xg0 = 0, xf0 = 0, xo0 = 0, xi1 = 0, xg1 = 0, xf1 = 0, xo1 = 0;
      const u32* wpx = wzxG + 4 * u;
#pragma unroll 8
      for (int k2 = 0; k2 < 32; ++k2) {
        const uint4 w = *(const uint4*)wpx; wpx += GZ;
        const u32 a0 = xf16q[k2 * 2 + 0], a1 = xf16q[k2 * 2 + 1];
        xi0 = dot2p(w.x, a0, xi0); xg0 = dot2p(w.y, a0, xg0);
        xf0 = dot2p(w.z, a0, xf0); xo0 = dot2p(w.w, a0, xo0);
        xi1 = dot2p(w.x, a1, xi1); xg1 = dot2p(w.y, a1, xg1);
        xf1 = dot2p(w.z, a1, xf1); xo1 = dot2p(w.w, a1, xo1);
      }
      int ii0 = 0, ig0 = 0, if0 = 0, io0 = 0, ii1 = 0, ig1 = 0, if1 = 0, io1 = 0;
      const u32* wph = wzG + 4 * u;
#pragma unroll 8
      for (int q = 0; q < 128; ++q) {
        const uint4 w = *(const uint4*)wph; wph += GZ;
        const u32 a0 = ah8q[q * 2 + 0], a1 = ah8q[q * 2 + 1];
        ii0 = dot4i(w.x, a0, ii0); ig0 = dot4i(w.y, a0, ig0);
        if0 = dot4i(w.z, a0, if0); io0 = dot4i(w.w, a0, io0);
        ii1 = dot4i(w.x, a1, ii1); ig1 = dot4i(w.y, a1, ig1);
        if1 = dot4i(w.z, a1, if1); io1 = dot4i(w.w, a1, io1);
      }
      const float zi0 = bgi + xi0 + zscl.x * (float)ii0;
      const float zg0 = bgg + xg0 + zscl.y * (float)ig0;
      const float zf0 = bgf + xf0 + zscl.z * (float)if0;
      const float zo0 = bgo + xo0 + zscl.w * (float)io0;
      const float zi1 = bgi + xi1 + zscl.x * (float)ii1;
      const float zg1 = bgg + xg1 + zscl.y * (float)ig1;
      const float zf1 = bgf + xf1 + zscl.z * (float)if1;
      const float zo1 = bgo + xo1 + zscl.w * (float)io1;
      c0 = fmaf(c0, fsig(zf0 + 1.f), ftanh(zi0) * fsig(zg0));
      c1 = fmaf(c1, fsig(zf1 + 1.f), ftanh(zi1) * fsig(zg1));
      const float hl0 = ftanh(c0) * fsig(zo0);
      const float hl1 = ftanh(c1) * fsig(zo1);
      const int q0 = (int)rintf(hl0 * 127.f), q1 = (int)rintf(hl1 * 127.f);
      ((u8*)vcat8)[((16 + (u >> 2)) * 2 + 0) * 4 + (u & 3)] = (u8)(q0 & 0xff);
      ((u8*)vcat8)[((16 + (u >> 2)) * 2 + 1) * 4 + (u & 3)] = (u8)(q1 & 0xff);
    }
    __syncthreads();                                   // B1: h_lstm ready

    // ---- phase 2: backbone + F, 4-lane split (m=j>>2, s4=j&3), shfl combine ----
    if (j < 512) {
      const int m = j >> 2, s4 = j & 3;
      const int qb = s4 * 36;
      int ax0 = 0, ax1 = 0, ah0 = 0, ah1 = 0;
#pragma unroll 12
      for (int q = 0; q < 36; ++q) {
        const int qq = qb + q;
        const u32 w = bbL[qq * DB + m];
        const int d0 = dot4i(w, vcat8[qq * 2 + 0], 0);
        const int d1 = dot4i(w, vcat8[qq * 2 + 1], 0);
        const bool isx = qq < 16;       // x segment = quads 0..15 (only in s4==0's range)
        ax0 += isx ? d0 : 0; ah0 += isx ? 0 : d0;
        ax1 += isx ? d1 : 0; ah1 += isx ? 0 : d1;
      }
      // combine across the 4 lanes of this m-group (same wave)
      ax0 += __shfl_xor(ax0, 1, 64); ax1 += __shfl_xor(ax1, 1, 64);
      ax0 += __shfl_xor(ax0, 2, 64); ax1 += __shfl_xor(ax1, 2, 64);
      ah0 += __shfl_xor(ah0, 1, 64); ah1 += __shfl_xor(ah1, 1, 64);
      ah0 += __shfl_xor(ah0, 2, 64); ah1 += __shfl_xor(ah1, 2, 64);
      if (s4 == 0) {
        const float r0 = bbr + sbbr * (sxq[0] * (float)ax0 + C127 * (float)ah0);
        const float r1 = bbr + sbbr * (sxq[1] * (float)ax1 + C127 * (float)ah1);
        const float F0 = 1.7159f * ftanh(0.666f * r0);
        const float F1 = 1.7159f * ftanh(0.666f * r1);
        const int q0 = (int)rintf(F0 * (127.f / 1.7159f));
        const int q1 = (int)rintf(F1 * (127.f / 1.7159f));
        ((u8*)Fq8)[((m >> 2) * 2 + 0) * 4 + (m & 3)] = (u8)(q0 & 0xff);
        ((u8*)Fq8)[((m >> 2) * 2 + 1) * 4 + (m & 3)] = (u8)(q1 & 0xff);
      }
    }
    __syncthreads();                                   // B2: F ready

    // ---- phase 3: ff (4 mats) + combine fused || stage x(t+1) ----
    if (j < 512) {
      int a10 = 0, a20 = 0, aa0 = 0, ab0 = 0, a11 = 0, a21 = 0, aa1 = 0, ab1 = 0;
      const u32* fw = ffG + 4 * u;
#pragma unroll 8
      for (int l = 0; l < 32; ++l) {
        const uint4 w = *(const uint4*)fw; fw += GZ;
        const u32 F0v = Fq8[l * 2 + 0], F1v = Fq8[l * 2 + 1];
        a10 = dot4i(w.x, F0v, a10); a20 = dot4i(w.y, F0v, a20);
        aa0 = dot4i(w.z, F0v, aa0); ab0 = dot4i(w.w, F0v, ab0);
        a11 = dot4i(w.x, F1v, a11); a21 = dot4i(w.y, F1v, a21);
        aa1 = dot4i(w.z, F1v, aa1); ab1 = dot4i(w.w, F1v, ab1);
      }
      const float z10 = sfv.x * (float)a10 + cb1, z20 = sfv.y * (float)a20 + cb2;
      const float za0 = sfv.z * (float)aa0 + cba, zb0 = sfv.w * (float)ab0 + cbb;
      const float z11 = sfv.x * (float)a11 + cb1, z21 = sfv.y * (float)a21 + cb2;
      const float za1 = sfv.z * (float)aa1 + cba, zb1 = sfv.w * (float)ab1 + cbb;
      const float ti0 = fsig(za0 + zb0), ti1 = fsig(za1 + zb1);
      const float hn0 = fmaf(ftanh(z10), 1.f - ti0, ti0 * ftanh(z20));
      const float hn1 = fmaf(ftanh(z11), 1.f - ti1, ti1 * ftanh(z21));
      ((u16*)hfR)[u] = f16b(hn0);
      ((u16*)hfR)[512 + u] = f16b(hn1);
      const int q0 = (int)rintf(hn0 * 127.f), q1 = (int)rintf(hn1 * 127.f);
      ((u8*)ah8q)[((u >> 2) * 2 + 0) * 4 + (u & 3)] = (u8)(q0 & 0xff);
      ((u8*)ah8q)[((u >> 2) * 2 + 1) * 4 + (u & 3)] = (u8)(q1 & 0xff);
      if (t == TT - 1) {
        out[(size_t)NB * TT * 2 + (size_t)(2 * b + 0) * DH + u] = hn0;
        out[(size_t)NB * TT * 2 + (size_t)(2 * b + 1) * DH + u] = hn1;
      }
    } else if (j < 576 && t + 1 < TT) {
      const int i = j - 512, xr = i >> 5, k2 = i & 31;
      const size_t xi = ((size_t)(2 * b + xr) * TT + (t + 1)) * 32 + k2;
      float a, bb_;
      if (bf16in) {
        const u32 w = ((const u32*)xraw)[xi];
        a = bf2f((u16)(w & 0xffffu)); bb_ = bf2f((u16)(w >> 16));
      } else {
        const float2 v = ((const float2*)xraw)[xi];
        a = v.x; bb_ = v.y;
      }
      xf16q[k2 * 2 + xr] = packf16(a, bb_);
      float m = fmaxf(fabsf(a), fabsf(bb_));
#pragma unroll
      for (int off = 16; off > 0; off >>= 1) m = fmaxf(m, __shfl_xor(m, off, 32));
      m = fmaxf(m, 1e-20f);
      if (k2 == 0) sxq[xr] = m * C127;
      const float inv = 127.f / m;
      const int q0 = (int)rintf(a * inv), q1 = (int)rintf(bb_ * inv);
      ((u16*)vcat8)[((k2 >> 1) * 2 + xr) * 2 + (k2 & 1)] =
          (u16)((q0 & 0xff) | ((q1 & 0xff) << 8));
    }
    __syncthreads();                                   // B3: h_new + x(t+1) ready

    // ---- phase 4: head (waves 8-11), runs in the shadow of next phase 1 ----
    if (j >= 512 && j < 768) {
      float acc = 0.f;
#pragma unroll
      for (int i = 0; i < 4; ++i)
        acc = dot2p(hwreg[i], hfR[hrow * 256 + hl + 64 * i], acc);
#pragma unroll
      for (int off = 32; off > 0; off >>= 1) acc += __shfl_down(acc, off, 64);
      if (hl == 0) out[((size_t)(2 * b + hrow) * TT + t) * 2 + hw_] = acc + hbr;
    }
  }
}

// ---------------- fallback (round-3 verified, bf16 d_in, small ws) ----------------
__device__ __forceinline__ void fma8(float& acc, const uint4 u, const float* v) {
  union { u32 i; float f; } tt;
  tt.i = u.x << 16;          acc = fmaf(tt.f, v[0], acc);
  tt.i = u.x & 0xffff0000u;  acc = fmaf(tt.f, v[1], acc);
  tt.i = u.y << 16;          acc = fmaf(tt.f, v[2], acc);
  tt.i = u.y & 0xffff0000u;  acc = fmaf(tt.f, v[3], acc);
  tt.i = u.z << 16;          acc = fmaf(tt.f, v[4], acc);
  tt.i = u.z & 0xffff0000u;  acc = fmaf(tt.f, v[5], acc);
  tt.i = u.w << 16;          acc = fmaf(tt.f, v[6], acc);
  tt.i = u.w & 0xffff0000u;  acc = fmaf(tt.f, v[7], acc);
}
__global__ __launch_bounds__(256, 1)
void fb_scan(const u16* __restrict__ x,   const u16* __restrict__ Wi,
             const u16* __restrict__ bi,  const u16* __restrict__ Wh,
             const u16* __restrict__ bbW, const u16* __restrict__ bbb,
             const u16* __restrict__ f1W, const u16* __restrict__ f1b,
             const u16* __restrict__ f2W, const u16* __restrict__ f2b,
             const u16* __restrict__ taW, const u16* __restrict__ tab,
             const u16* __restrict__ tbW, const u16* __restrict__ tbb,
             const u16* __restrict__ hW,  const u16* __restrict__ hb,
             float* __restrict__ out)
{
  __shared__ __align__(16) float vcat[DI + DH];
  __shared__ __align__(16) float Fb2[DB];
  __shared__ __align__(16) float fpart[256];
  __shared__ __align__(16) float hprev[DH];
  const int j = threadIdx.x, b = blockIdx.x;
  const int u0 = j, u1 = j + 256;
  float bi_r[8];
#pragma unroll
  for (int k = 0; k < 8; ++k) bi_r[k] = bf2f(bi[j + 256 * k]);
  const float b_f1_0 = bf2f(f1b[u0]), b_f1_1 = bf2f(f1b[u1]);
  const float b_f2_0 = bf2f(f2b[u0]), b_f2_1 = bf2f(f2b[u1]);
  const float b_ta_0 = bf2f(tab[u0]), b_ta_1 = bf2f(tab[u1]);
  const float b_tb_0 = bf2f(tbb[u0]), b_tb_1 = bf2f(tbb[u1]);
  const float b_bb = (j < DB) ? bf2f(bbb[j]) : 0.f;
  float hwr[8]; float hbr = 0.f;
  if (j < 128) {
    const int w = j >> 6, l = j & 63;
#pragma unroll
    for (int q = 0; q < 8; ++q) hwr[q] = bf2f(hW[w * DH + q * 64 + l]);
    hbr = bf2f(hb[w]);
  }
  float c0 = 0.f, c1 = 0.f;
  hprev[u0] = 0.f; hprev[u1] = 0.f;
  const u16* xp = x + (size_t)b * TT * DI;
  __syncthreads();
  for (int t = 0; t < TT; ++t) {
    if (j < DI) vcat[j] = bf2f(xp[t * DI + j]);
    __syncthreads();
    float a[8];
#pragma unroll
    for (int k = 0; k < 8; ++k) a[k] = bi_r[k];
#pragma unroll
    for (int r = 0; r < 8; ++r) {
      const u16* wr = Wi + ((size_t)(j + 256 * r)) * DI;
      float acc = a[r];
#pragma unroll
      for (int kk = 0; kk < DI; kk += 8) fma8(acc, *(const uint4*)(wr + kk), vcat + kk);
      a[r] = acc;
    }
#pragma unroll 1
    for (int kb = 0; kb < DH; kb += 64) {
      float hreg[64];
#pragma unroll
      for (int q = 0; q < 16; ++q)
        *(float4*)(hreg + 4 * q) = *(const float4*)(hprev + kb + 4 * q);
#pragma unroll
      for (int r = 0; r < 8; ++r) {
        const u16* wr = Wh + ((size_t)(j + 256 * r)) * DH + kb;
        float acc = a[r];
#pragma unroll
        for (int cc = 0; cc < 8; ++cc) fma8(acc, *(const uint4*)(wr + 8 * cc), hreg + 8 * cc);
        a[r] = acc;
      }
    }
    {
      const float cn0 = fmaf(c0, fsig(a[4] + 1.f), ftanh(a[0]) * fsig(a[2]));
      const float cn1 = fmaf(c1, fsig(a[5] + 1.f), ftanh(a[1]) * fsig(a[3]));
      c0 = cn0; c1 = cn1;
      vcat[DI + u0] = ftanh(cn0) * fsig(a[6]);
      vcat[DI + u1] = ftanh(cn1) * fsig(a[7]);
    }
    __syncthreads();
    {
      const int mm = j & (DB - 1), pp = j >> 7;
      const u16* br = bbW + (size_t)mm * KZ + pp * 288;
      const float* vs = vcat + pp * 288;
      float s0 = 0.f, s1 = 0.f, s2v = 0.f, s3 = 0.f;
#pragma unroll
      for (int kk = 0; kk < 288; kk += 32) {
        fma8(s0, *(const uint4*)(br + kk), vs + kk);
        fma8(s1, *(const uint4*)(br + kk + 8), vs + kk + 8);
        fma8(s2v, *(const uint4*)(br + kk + 16), vs + kk + 16);
        fma8(s3, *(const uint4*)(br + kk + 24), vs + kk + 24);
      }
      fpart[j] = (s0 + s1) + (s2v + s3);
    }
    __syncthreads();
    if (j < DB) Fb2[j] = 1.7159f * ftanh(0.666f * (b_bb + fpart[j] + fpart[j + DB]));
    __syncthreads();
    {
      float Fr[DB];
#pragma unroll
      for (int q = 0; q < 32; ++q) *(float4*)(Fr + 4 * q) = *(const float4*)(Fb2 + 4 * q);
      const u16* rp[8] = {
        f1W + (size_t)u0 * DB, f1W + (size_t)u1 * DB,
        f2W + (size_t)u0 * DB, f2W + (size_t)u1 * DB,
        taW + (size_t)u0 * DB, taW + (size_t)u1 * DB,
        tbW + (size_t)u0 * DB, tbW + (size_t)u1 * DB };
      float sacc[8] = { b_f1_0, b_f1_1, b_f2_0, b_f2_1, b_ta_0, b_ta_1, b_tb_0, b_tb_1 };
#pragma unroll
      for (int rr = 0; rr < 8; ++rr) {
        float acc = sacc[rr];
        const u16* r = rp[rr];
#pragma unroll
        for (int kk = 0; kk < DB; kk += 8) fma8(acc, *(const uint4*)(r + kk), Fr + kk);
        sacc[rr] = acc;
      }
      const float ti0 = fsig(sacc[4] + sacc[6]);
      const float ti1 = fsig(sacc[5] + sacc[7]);
      hprev[u0] = fmaf(ftanh(sacc[0]), 1.f - ti0, ti0 * ftanh(sacc[2]));
      hprev[u1] = fmaf(ftanh(sacc[1]), 1.f - ti1, ti1 * ftanh(sacc[3]));
    }
    __syncthreads();
    if (j < 128) {
      const int l = j & 63;
      float acc = 0.f;
#pragma unroll
      for (int q = 0; q < 8; ++q) acc = fmaf(hprev[q * 64 + l], hwr[q], acc);
#pragma unroll
      for (int off = 32; off > 0; off >>= 1) acc += __shfl_down(acc, off, 64);
      if (l == 0) out[((size_t)b * TT + t) * 2 + (j >> 6)] = acc + hbr;
    }
  }
  out[(size_t)NB * TT * 2 + (size_t)b * DH + u0] = hprev[u0];
  out[(size_t)NB * TT * 2 + (size_t)b * DH + u1] = hprev[u1];
}

extern "C" void kernel_launch(void* const* d_in, const int* in_sizes, int n_in,
                              void* d_out, int out_size, void* d_ws, size_t ws_size,
                              hipStream_t stream) {
  (void)in_sizes; (void)n_in; (void)out_size;

  if (ws_size >= WS_NEED) {
    char* ws = (char*)d_ws;
    int* flag = (int*)ws;
    detect_kernel<<<dim3(1), dim3(64), 0, stream>>>(
        (const u16*)d_in[0], (const u16*)d_in[1], (const u16*)d_in[3], flag);
    pwzx_kernel<<<dim3(8, 32), dim3(256), 0, stream>>>(d_in[1], flag, (u32*)(ws + O_WZX));
    qwz_kernel<<<dim3(2048), dim3(64), 0, stream>>>(d_in[3], flag,
                                                    (u32*)(ws + O_WZ8), (float*)(ws + O_SWZ));
    qbb_kernel<<<dim3(128), dim3(64), 0, stream>>>(d_in[4], flag,
                                                   (u32*)(ws + O_BB8), (float*)(ws + O_SBB));
    qff_kernel<<<dim3(512, 4), dim3(32), 0, stream>>>(d_in[6], d_in[8], d_in[10],
                                                      d_in[12], flag,
                                                      (u32*)(ws + O_FF8), (float*)(ws + O_SFF));
    psmall_kernel<<<dim3(1), dim3(1024), 0, stream>>>(
        d_in[2], d_in[7], d_in[9], d_in[11], d_in[13], d_in[5], d_in[14], d_in[15],
        flag, (float*)(ws + O_BIF), (float*)(ws + O_FFB), (float*)(ws + O_BBBF),
        (u32*)(ws + O_HWP), (float*)(ws + O_HBF));

    scan17<<<dim3(64), dim3(1024), 0, stream>>>(
        d_in[0], flag,
        (const u32*)(ws + O_WZX), (const u32*)(ws + O_WZ8), (const float*)(ws + O_SWZ),
        (const u32*)(ws + O_BB8), (const float*)(ws + O_SBB),
        (const u32*)(ws + O_FF8), (const float*)(ws + O_SFF),
        (const float*)(ws + O_BIF), (const float*)(ws + O_FFB),
        (const float*)(ws + O_BBBF), (const u32*)(ws + O_HWP),
        (const float*)(ws + O_HBF), (float*)d_out);
  } else {
    fb_scan<<<dim3(NB), dim3(256), 0, stream>>>(
        (const u16*)d_in[0],  (const u16*)d_in[1],  (const u16*)d_in[2],
        (const u16*)d_in[3],  (const u16*)d_in[4],  (const u16*)d_in[5],
        (const u16*)d_in[6],  (const u16*)d_in[7],  (const u16*)d_in[8],
        (const u16*)d_in[9],  (const u16*)d_in[10], (const u16*)d_in[11],
        (const u16*)d_in[12], (const u16*)d_in[13], (const u16*)d_in[14],
        (const u16*)d_in[15], (float*)d_out);
  }
}

// Round 11
// 13200.108 us; speedup vs baseline: 1.8812x; 1.1164x over previous
//
#include <hip/hip_runtime.h>

#define NB 128
#define TT 1024
#define DI 64
#define DH 512
#define DB 128
#define GZ 2048
#define KZ 576
#define BST 136   // bbL LDS row stride (136%32==8 -> 2-way max bank aliasing)

typedef unsigned short u16;
typedef unsigned char u8;
typedef unsigned int u32;
typedef unsigned long long u64;

#if defined(__has_builtin)
#if __has_builtin(__builtin_amdgcn_fdot2)
#define HAS_FDOT2 1
#endif
#if __has_builtin(__builtin_amdgcn_sdot4)
#define HAS_SDOT4 1
#endif
#endif

typedef _Float16 half2v __attribute__((ext_vector_type(2)));

__device__ __forceinline__ float bf2f(u16 u) {
  union { u32 i; float f; } v; v.i = ((u32)u) << 16; return v.f;
}
__device__ __forceinline__ float fsig(float x) {
  return __builtin_amdgcn_rcpf(1.f + __expf(-x));
}
__device__ __forceinline__ float ftanh(float x) {
  return 1.f - 2.f * __builtin_amdgcn_rcpf(__expf(2.f * x) + 1.f);
}
__device__ __forceinline__ float dot2p(u32 w, u32 a, float acc) {
#ifdef HAS_FDOT2
  return __builtin_amdgcn_fdot2(__builtin_bit_cast(half2v, w),
                                __builtin_bit_cast(half2v, a), acc, false);
#else
  half2v hw = __builtin_bit_cast(half2v, w), ha = __builtin_bit_cast(half2v, a);
  acc = fmaf((float)hw.x, (float)ha.x, acc);
  return fmaf((float)hw.y, (float)ha.y, acc);
#endif
}
__device__ __forceinline__ int dot4i(u32 w, u32 a, int acc) {
#ifdef HAS_SDOT4
  return __builtin_amdgcn_sdot4((int)w, (int)a, acc, false);
#else
  acc += (((int)(w << 24)) >> 24) * (((int)(a << 24)) >> 24);
  acc += (((int)(w << 16)) >> 24) * (((int)(a << 16)) >> 24);
  acc += (((int)(w << 8))  >> 24) * (((int)(a << 8))  >> 24);
  acc += (((int)w) >> 24)         * (((int)a) >> 24);
  return acc;
#endif
}
__device__ __forceinline__ u32 packf16(float x, float y) {
  half2v h; h.x = (_Float16)x; h.y = (_Float16)y;
  return __builtin_bit_cast(u32, h);
}
__device__ __forceinline__ u16 f16b(float x) {
  _Float16 h = (_Float16)x;
  return __builtin_bit_cast(u16, h);
}

// ---- ws layout (bytes, 256-aligned); GATE-INTERLEAVED content ----
#define O_WZX  256                       // wzxG: [k2][u] uint4 (4 gates f16-pairs): 32*2048 u32
#define O_WZ8  (O_WZX + 262144)          // wzG: [q][u] uint4 (4 gates i8-quads): 128*2048 u32
#define O_SWZ  (O_WZ8 + 1048576)         // swzG: [u][g] f32[2048]
#define O_BB8  (O_SWZ + 8192)            // bb i8 quads: 144*128 u32 (unchanged)
#define O_SBB  (O_BB8 + 73728)           // bb weight scales: f32[128]
#define O_FF8  (O_SBB + 512)             // ffG: [l][u] uint4 (4 mats): 32*2048 u32
#define O_SFF  (O_FF8 + 262144)          // sffG: [u][mat] f32[2048]
#define O_BIF  (O_SFF + 8192)            // bi f32[2048]
#define O_FFB  (O_BIF + 8192)            // ff biases f32[4*512]
#define O_BBBF (O_FFB + 8192)            // bbb f32[128]
#define O_HWP  (O_BBBF + 512)            // head pairs u32[512]
#define O_HBF  (O_HWP + 2048)            // hb f32[2]
#define WS_NEED ((u64)(O_HBF + 256))     // ~1.68 MB

// ---------------- dtype detection (validated rounds 3-8) ----------------
__global__ void detect_kernel(const u16* x, const u16* wi, const u16* wh, int* flag) {
  const int l = threadIdx.x;
  int cnt = (((x[2 * l] >> 7) & 0xFF) < 134)
          + (((wi[2 * l] >> 7) & 0xFF) < 134)
          + (((wh[2 * l] >> 7) & 0xFF) < 134);
#pragma unroll
  for (int off = 32; off > 0; off >>= 1) cnt += __shfl_down(cnt, off, 64);
  if (l == 0) *flag = (cnt >= 180) ? 1 : 0;
}

__device__ __forceinline__ float ldf(int f, const void* s, u32 i) {
  return f ? bf2f(((const u16*)s)[i]) : ((const float*)s)[i];
}

// ---- prep: Wz x-part f16 pairs, gate-interleaved ----
__global__ void pwzx_kernel(const void* Wi, const int* __restrict__ flag,
                            u32* __restrict__ wzxG) {
  const int o = blockIdx.x * 256 + threadIdx.x;   // z-row 0..2047
  const int k2 = blockIdx.y;
  const int f = *flag;
  const u32 i = (u32)o * DI + 2 * k2;
  wzxG[(u32)k2 * GZ + (((u32)(o & 511)) << 2) + (o >> 9)] =
      packf16(ldf(f, Wi, i), ldf(f, Wi, i + 1));
}

// ---- prep: Wz h-part -> i8, gate-interleaved; per-row scale ----
__global__ void qwz_kernel(const void* Wh, const int* __restrict__ flag,
                           u32* __restrict__ wzG, float* __restrict__ swzG) {
  const int o = blockIdx.x;       // z-row 0..2047
  const int l = threadIdx.x;
  const int f = *flag;
  float w[8]; float mx = 0.f;
#pragma unroll
  for (int qq = 0; qq < 2; ++qq) {
    const int q = l + 64 * qq;
#pragma unroll
    for (int e = 0; e < 4; ++e) {
      const float v = ldf(f, Wh, (u32)o * DH + 4 * q + e);
      w[qq * 4 + e] = v; mx = fmaxf(mx, fabsf(v));
    }
  }
#pragma unroll
  for (int off = 32; off > 0; off >>= 1) mx = fmaxf(mx, __shfl_xor(mx, off, 64));
  mx = fmaxf(mx, 1e-20f);
  const float inv = 127.f / mx;
  if (l == 0) swzG[(((u32)(o & 511)) << 2) + (o >> 9)] = mx / (127.f * 127.f);
#pragma unroll
  for (int qq = 0; qq < 2; ++qq) {
    const int q = l + 64 * qq;
    u32 p = 0;
#pragma unroll
    for (int e = 0; e < 4; ++e) {
      int b = (int)rintf(w[qq * 4 + e] * inv);
      b = b > 127 ? 127 : (b < -127 ? -127 : b);
      p |= ((u32)(b & 0xff)) << (8 * e);
    }
    wzG[(u32)q * GZ + (((u32)(o & 511)) << 2) + (o >> 9)] = p;
  }
}

// ---- prep: backbone -> i8, per-output scale (layout unchanged) ----
__global__ void qbb_kernel(const void* bb, const int* __restrict__ flag,
                           u32* __restrict__ bb8, float* __restrict__ sbb) {
  const int m = blockIdx.x;      // 0..127
  const int l = threadIdx.x;     // 0..63
  const int f = *flag;
  float mx = 0.f;
#pragma unroll
  for (int q = 0; q < 9; ++q)
    mx = fmaxf(mx, fabsf(ldf(f, bb, (u32)m * KZ + l + 64 * q)));
#pragma unroll
  for (int off = 32; off > 0; off >>= 1) mx = fmaxf(mx, __shfl_xor(mx, off, 64));
  mx = fmaxf(mx, 1e-20f);
  const float inv = 127.f / mx;
  if (l == 0) sbb[m] = mx / 127.f;
  for (int k4 = l; k4 < 144; k4 += 64) {
    u32 p = 0;
#pragma unroll
    for (int e = 0; e < 4; ++e) {
      int b = (int)rintf(ldf(f, bb, (u32)m * KZ + 4 * k4 + e) * inv);
      b = b > 127 ? 127 : (b < -127 ? -127 : b);
      p |= ((u32)(b & 0xff)) << (8 * e);
    }
    bb8[(u32)k4 * DB + m] = p;
  }
}

// ---- prep: ff -> i8, mat-interleaved uint4 per (l, unit) ----
__global__ void qff_kernel(const void* f1, const void* f2, const void* ta,
                           const void* tb, const int* __restrict__ flag,
                           u32* __restrict__ ffG, float* __restrict__ sffG) {
  const int o = blockIdx.x;      // 0..511 (unit)
  const int mat = blockIdx.y;    // 0..3
  const int l = threadIdx.x;     // 0..31 (k4)
  const void* s = (mat == 0) ? f1 : (mat == 1) ? f2 : (mat == 2) ? ta : tb;
  const int f = *flag;
  float w[4]; float mx = 0.f;
#pragma unroll
  for (int e = 0; e < 4; ++e) {
    w[e] = ldf(f, s, (u32)o * DB + 4 * l + e);
    mx = fmaxf(mx, fabsf(w[e]));
  }
#pragma unroll
  for (int off = 16; off > 0; off >>= 1) mx = fmaxf(mx, __shfl_xor(mx, off, 32));
  mx = fmaxf(mx, 1e-20f);
  const float inv = 127.f / mx;
  if (l == 0) sffG[((u32)o << 2) + mat] = (mx / 127.f) * (1.7159f / 127.f);
  u32 p = 0;
#pragma unroll
  for (int e = 0; e < 4; ++e) {
    int b = (int)rintf(w[e] * inv);
    b = b > 127 ? 127 : (b < -127 ? -127 : b);
    p |= ((u32)(b & 0xff)) << (8 * e);
  }
  ffG[(((u32)l * 512 + o) << 2) + mat] = p;
}

__global__ void psmall_kernel(const void* bi_s, const void* f1b_s, const void* f2b_s,
                              const void* tab_s, const void* tbb_s, const void* bbb_s,
                              const void* hw_s, const void* hb_s,
                              const int* __restrict__ flag,
                              float* __restrict__ bif, float* __restrict__ ffb,
                              float* __restrict__ bbbf, u32* __restrict__ hwp,
                              float* __restrict__ hbf) {
  const int f = *flag;
  for (int i = threadIdx.x; i < 2048; i += 1024) {
    bif[i] = ldf(f, bi_s, i);
    if (i < 512) {
      ffb[i]        = ldf(f, f1b_s, i);
      ffb[512 + i]  = ldf(f, f2b_s, i);
      ffb[1024 + i] = ldf(f, tab_s, i);
      ffb[1536 + i] = ldf(f, tbb_s, i);
      const int w = i >> 8, pr = i & 255;
      hwp[i] = packf16(ldf(f, hw_s, w * DH + 2 * pr), ldf(f, hw_s, w * DH + 2 * pr + 1));
    }
    if (i < 128) bbbf[i] = ldf(f, bbb_s, i);
    if (i < 2)   hbf[i] = ldf(f, hb_s, i);
  }
}

// ---- scan18 = scan17 structure, 1 batch row per block (128 blocks / 128 CUs),
//      bbL stride 136 (bank-spread), LDS padded >80KB to force 1 block/CU ----
// Per-row arithmetic identical to scan17 -> bit-identical output.
__global__ __launch_bounds__(1024, 1)
void scan18(const void* __restrict__ xraw, const int* __restrict__ flagp,
            const u32* __restrict__ wzxG, const u32* __restrict__ wzG,
            const float* __restrict__ swzG,
            const u32* __restrict__ bb8, const float* __restrict__ sbb,
            const u32* __restrict__ ffG, const float* __restrict__ sffG,
            const float* __restrict__ bif, const float* __restrict__ ffbv,
            const float* __restrict__ bbbf, const u32* __restrict__ hwp,
            const float* __restrict__ hbf, float* __restrict__ out)
{
  __shared__ __align__(16) u32   xf16q[32];            // x(t) f16 pairs [k2]
  __shared__ __align__(16) u32   ah8q[128];            // h(t-1) i8 quads [k4]
  __shared__ __align__(16) u32   hfR[256];             // h(t) f16 [unit] (u16 view)
  __shared__ __align__(16) u32   vcat8[144];           // [x|h_lstm] i8 quads [k4]
  __shared__ __align__(16) float sxq[4];               // [0]: x quant scale
  __shared__ __align__(16) u32   Fq8[32];              // F i8 quads [k4]
  __shared__ __align__(16) u32   bbL[144 * BST + 1024];// bb resident (stride 136) + pad
                                                       // total LDS ~83KB -> 1 block/CU

  const int j = threadIdx.x;
  const int b = blockIdx.x;          // batch row b (0..127)
  const int bf16in = *flagp;
  const int u = j & 511;

  // persistent per-unit state (j<512)
  float c0 = 0.f;
  float bgi = 0, bgg = 0, bgf = 0, bgo = 0, cb1 = 0, cb2 = 0, cba = 0, cbb = 0;
  float4 zscl = make_float4(0, 0, 0, 0), sfv = make_float4(0, 0, 0, 0);
  if (j < 512) {
    bgi = bif[0 * DH + u]; bgg = bif[1 * DH + u];
    bgf = bif[2 * DH + u]; bgo = bif[3 * DH + u];
    cb1 = ffbv[0 * DH + u]; cb2 = ffbv[1 * DH + u];
    cba = ffbv[2 * DH + u]; cbb = ffbv[3 * DH + u];
    zscl = *(const float4*)(swzG + 4 * u);
    sfv  = *(const float4*)(sffG + 4 * u);
  }
  float sbbr = 0.f, bbr = 0.f;
  if (j < 512) { sbbr = sbb[j >> 2]; bbr = bbbf[j >> 2]; }
  u32 hwreg[4] = {0, 0, 0, 0}; float hbr = 0.f;
  int hw_ = 0, hl = 0;
  if (j >= 576 && j < 704) {
    const int jj = j - 576;
    hw_ = jj >> 6; hl = jj & 63;
#pragma unroll
    for (int i = 0; i < 4; ++i) hwreg[i] = hwp[hw_ * 256 + hl + 64 * i];
    hbr = hbf[hw_];
  }
  const float C127 = 1.f / 127.f;

  // ---- bb weights resident in LDS (once), stride BST ----
  for (int idx = j; idx < 144 * DB; idx += 1024) {
    const int q = idx >> 7, m = idx & 127;
    bbL[q * BST + m] = bb8[idx];
  }

  // ---- preamble: h0 = 0; stage x(0) ----
  if (j < 256) { hfR[j] = 0u; if (j < 128) ah8q[j] = 0u; }
  if (j >= 512 && j < 544) {
    const int k2 = j - 512;
    const size_t xi = ((size_t)b * TT + 0) * 32 + k2;
    float a, bb_;
    if (bf16in) {
      const u32 w = ((const u32*)xraw)[xi];
      a = bf2f((u16)(w & 0xffffu)); bb_ = bf2f((u16)(w >> 16));
    } else {
      const float2 v = ((const float2*)xraw)[xi];
      a = v.x; bb_ = v.y;
    }
    xf16q[k2] = packf16(a, bb_);
    float m = fmaxf(fabsf(a), fabsf(bb_));
#pragma unroll
    for (int off = 16; off > 0; off >>= 1) m = fmaxf(m, __shfl_xor(m, off, 32));
    m = fmaxf(m, 1e-20f);
    if (k2 == 0) sxq[0] = m * C127;
    const float inv = 127.f / m;
    const int q0 = (int)rintf(a * inv), q1 = (int)rintf(bb_ * inv);
    ((u16*)vcat8)[k2] = (u16)((q0 & 0xff) | ((q1 & 0xff) << 8));
  }
  __syncthreads();

  for (int t = 0; t < TT; ++t) {
    // ---- phase 1: Z (all 4 gates) + LSTM gates, fused ----
    if (j < 512) {
      float xi0 = 0, xg0 = 0, xf0 = 0, xo0 = 0;
      const u32* wpx = wzxG + 4 * u;
#pragma unroll 8
      for (int k2 = 0; k2 < 32; ++k2) {
        const uint4 w = *(const uint4*)wpx; wpx += GZ;
        const u32 a0 = xf16q[k2];
        xi0 = dot2p(w.x, a0, xi0); xg0 = dot2p(w.y, a0, xg0);
        xf0 = dot2p(w.z, a0, xf0); xo0 = dot2p(w.w, a0, xo0);
      }
      int ii0 = 0, ig0 = 0, if0 = 0, io0 = 0;
      const u32* wph = wzG + 4 * u;
#pragma unroll 8
      for (int q = 0; q < 128; ++q) {
        const uint4 w = *(const uint4*)wph; wph += GZ;
        const u32 a0 = ah8q[q];
        ii0 = dot4i(w.x, a0, ii0); ig0 = dot4i(w.y, a0, ig0);
        if0 = dot4i(w.z, a0, if0); io0 = dot4i(w.w, a0, io0);
      }
      const float zi0 = bgi + xi0 + zscl.x * (float)ii0;
      const float zg0 = bgg + xg0 + zscl.y * (float)ig0;
      const float zf0 = bgf + xf0 + zscl.z * (float)if0;
      const float zo0 = bgo + xo0 + zscl.w * (float)io0;
      c0 = fmaf(c0, fsig(zf0 + 1.f), ftanh(zi0) * fsig(zg0));
      const float hl0 = ftanh(c0) * fsig(zo0);
      const int q0 = (int)rintf(hl0 * 127.f);
      ((u8*)vcat8)[64 + u] = (u8)(q0 & 0xff);
    }
    __syncthreads();                                   // B1: h_lstm ready

    // ---- phase 2: backbone + F, 4-lane split (m=j>>2, s4=j&3), shfl combine ----
    if (j < 512) {
      const int m = j >> 2, s4 = j & 3;
      const int qb = s4 * 36;
      int ax0 = 0, ah0 = 0;
#pragma unroll 12
      for (int q = 0; q < 36; ++q) {
        const int qq = qb + q;
        const u32 w = bbL[qq * BST + m];
        const int d0 = dot4i(w, vcat8[qq], 0);
        const bool isx = qq < 16;
        ax0 += isx ? d0 : 0; ah0 += isx ? 0 : d0;
      }
      ax0 += __shfl_xor(ax0, 1, 64); ax0 += __shfl_xor(ax0, 2, 64);
      ah0 += __shfl_xor(ah0, 1, 64); ah0 += __shfl_xor(ah0, 2, 64);
      if (s4 == 0) {
        const float r0 = bbr + sbbr * (sxq[0] * (float)ax0 + C127 * (float)ah0);
        const float F0 = 1.7159f * ftanh(0.666f * r0);
        const int q0 = (int)rintf(F0 * (127.f / 1.7159f));
        ((u8*)Fq8)[m] = (u8)(q0 & 0xff);
      }
    }
    __syncthreads();                                   // B2: F ready

    // ---- phase 3: ff (4 mats) + combine fused || stage x(t+1) ----
    if (j < 512) {
      int a10 = 0, a20 = 0, aa0 = 0, ab0 = 0;
      const u32* fw = ffG + 4 * u;
#pragma unroll 8
      for (int l = 0; l < 32; ++l) {
        const uint4 w = *(const uint4*)fw; fw += GZ;
        const u32 F0v = Fq8[l];
        a10 = dot4i(w.x, F0v, a10); a20 = dot4i(w.y, F0v, a20);
        aa0 = dot4i(w.z, F0v, aa0); ab0 = dot4i(w.w, F0v, ab0);
      }
      const float z10 = sfv.x * (float)a10 + cb1, z20 = sfv.y * (float)a20 + cb2;
      const float za0 = sfv.z * (float)aa0 + cba, zb0 = sfv.w * (float)ab0 + cbb;
      const float ti0 = fsig(za0 + zb0);
      const float hn0 = fmaf(ftanh(z10), 1.f - ti0, ti0 * ftanh(z20));
      ((u16*)hfR)[u] = f16b(hn0);
      const int q0 = (int)rintf(hn0 * 127.f);
      ((u8*)ah8q)[u] = (u8)(q0 & 0xff);
      if (t == TT - 1) {
        out[(size_t)NB * TT * 2 + (size_t)b * DH + u] = hn0;
      }
    } else if (j < 544 && t + 1 < TT) {
      const int k2 = j - 512;
      const size_t xi = ((size_t)b * TT + (t + 1)) * 32 + k2;
      float a, bb_;
      if (bf16in) {
        const u32 w = ((const u32*)xraw)[xi];
        a = bf2f((u16)(w & 0xffffu)); bb_ = bf2f((u16)(w >> 16));
      } else {
        const float2 v = ((const float2*)xraw)[xi];
        a = v.x; bb_ = v.y;
      }
      xf16q[k2] = packf16(a, bb_);
      float m = fmaxf(fabsf(a), fabsf(bb_));
#pragma unroll
      for (int off = 16; off > 0; off >>= 1) m = fmaxf(m, __shfl_xor(m, off, 32));
      m = fmaxf(m, 1e-20f);
      if (k2 == 0) sxq[0] = m * C127;
      const float inv = 127.f / m;
      const int q0 = (int)rintf(a * inv), q1 = (int)rintf(bb_ * inv);
      ((u16*)vcat8)[k2] = (u16)((q0 & 0xff) | ((q1 & 0xff) << 8));
    }
    __syncthreads();                                   // B3: h_new + x(t+1) ready

    // ---- phase 4: head (128 threads), runs in the shadow of next phase 1 ----
    if (j >= 576 && j < 704) {
      float acc = 0.f;
#pragma unroll
      for (int i = 0; i < 4; ++i)
        acc = dot2p(hwreg[i], hfR[hl + 64 * i], acc);
#pragma unroll
      for (int off = 32; off > 0; off >>= 1) acc += __shfl_down(acc, off, 64);
      if (hl == 0) out[((size_t)b * TT + t) * 2 + hw_] = acc + hbr;
    }
  }
}

// ---------------- fallback (round-3 verified, bf16 d_in, small ws) ----------------
__device__ __forceinline__ void fma8(float& acc, const uint4 u, const float* v) {
  union { u32 i; float f; } tt;
  tt.i = u.x << 16;          acc = fmaf(tt.f, v[0], acc);
  tt.i = u.x & 0xffff0000u;  acc = fmaf(tt.f, v[1], acc);
  tt.i = u.y << 16;          acc = fmaf(tt.f, v[2], acc);
  tt.i = u.y & 0xffff0000u;  acc = fmaf(tt.f, v[3], acc);
  tt.i = u.z << 16;          acc = fmaf(tt.f, v[4], acc);
  tt.i = u.z & 0xffff0000u;  acc = fmaf(tt.f, v[5], acc);
  tt.i = u.w << 16;          acc = fmaf(tt.f, v[6], acc);
  tt.i = u.w & 0xffff0000u;  acc = fmaf(tt.f, v[7], acc);
}
__global__ __launch_bounds__(256, 1)
void fb_scan(const u16* __restrict__ x,   const u16* __restrict__ Wi,
             const u16* __restrict__ bi,  const u16* __restrict__ Wh,
             const u16* __restrict__ bbW, const u16* __restrict__ bbb,
             const u16* __restrict__ f1W, const u16* __restrict__ f1b,
             const u16* __restrict__ f2W, const u16* __restrict__ f2b,
             const u16* __restrict__ taW, const u16* __restrict__ tab,
             const u16* __restrict__ tbW, const u16* __restrict__ tbb,
             const u16* __restrict__ hW,  const u16* __restrict__ hb,
             float* __restrict__ out)
{
  __shared__ __align__(16) float vcat[DI + DH];
  __shared__ __align__(16) float Fb2[DB];
  __shared__ __align__(16) float fpart[256];
  __shared__ __align__(16) float hprev[DH];
  const int j = threadIdx.x, b = blockIdx.x;
  const int u0 = j, u1 = j + 256;
  float bi_r[8];
#pragma unroll
  for (int k = 0; k < 8; ++k) bi_r[k] = bf2f(bi[j + 256 * k]);
  const float b_f1_0 = bf2f(f1b[u0]), b_f1_1 = bf2f(f1b[u1]);
  const float b_f2_0 = bf2f(f2b[u0]), b_f2_1 = bf2f(f2b[u1]);
  const float b_ta_0 = bf2f(tab[u0]), b_ta_1 = bf2f(tab[u1]);
  const float b_tb_0 = bf2f(tbb[u0]), b_tb_1 = bf2f(tbb[u1]);
  const float b_bb = (j < DB) ? bf2f(bbb[j]) : 0.f;
  float hwr[8]; float hbr = 0.f;
  if (j < 128) {
    const int w = j >> 6, l = j & 63;
#pragma unroll
    for (int q = 0; q < 8; ++q) hwr[q] = bf2f(hW[w * DH + q * 64 + l]);
    hbr = bf2f(hb[w]);
  }
  float c0 = 0.f, c1 = 0.f;
  hprev[u0] = 0.f; hprev[u1] = 0.f;
  const u16* xp = x + (size_t)b * TT * DI;
  __syncthreads();
  for (int t = 0; t < TT; ++t) {
    if (j < DI) vcat[j] = bf2f(xp[t * DI + j]);
    __syncthreads();
    float a[8];
#pragma unroll
    for (int k = 0; k < 8; ++k) a[k] = bi_r[k];
#pragma unroll
    for (int r = 0; r < 8; ++r) {
      const u16* wr = Wi + ((size_t)(j + 256 * r)) * DI;
      float acc = a[r];
#pragma unroll
      for (int kk = 0; kk < DI; kk += 8) fma8(acc, *(const uint4*)(wr + kk), vcat + kk);
      a[r] = acc;
    }
#pragma unroll 1
    for (int kb = 0; kb < DH; kb += 64) {
      float hreg[64];
#pragma unroll
      for (int q = 0; q < 16; ++q)
        *(float4*)(hreg + 4 * q) = *(const float4*)(hprev + kb + 4 * q);
#pragma unroll
      for (int r = 0; r < 8; ++r) {
        const u16* wr = Wh + ((size_t)(j + 256 * r)) * DH + kb;
        float acc = a[r];
#pragma unroll
        for (int cc = 0; cc < 8; ++cc) fma8(acc, *(const uint4*)(wr + 8 * cc), hreg + 8 * cc);
        a[r] = acc;
      }
    }
    {
      const float cn0 = fmaf(c0, fsig(a[4] + 1.f), ftanh(a[0]) * fsig(a[2]));
      const float cn1 = fmaf(c1, fsig(a[5] + 1.f), ftanh(a[1]) * fsig(a[3]));
      c0 = cn0; c1 = cn1;
      vcat[DI + u0] = ftanh(cn0) * fsig(a[6]);
      vcat[DI + u1] = ftanh(cn1) * fsig(a[7]);
    }
    __syncthreads();
    {
      const int mm = j & (DB - 1), pp = j >> 7;
      const u16* br = bbW + (size_t)mm * KZ + pp * 288;
      const float* vs = vcat + pp * 288;
      float s0 = 0.f, s1 = 0.f, s2v = 0.f, s3 = 0.f;
#pragma unroll
      for (int kk = 0; kk < 288; kk += 32) {
        fma8(s0, *(const uint4*)(br + kk), vs + kk);
        fma8(s1, *(const uint4*)(br + kk + 8), vs + kk + 8);
        fma8(s2v, *(const uint4*)(br + kk + 16), vs + kk + 16);
        fma8(s3, *(const uint4*)(br + kk + 24), vs + kk + 24);
      }
      fpart[j] = (s0 + s1) + (s2v + s3);
    }
    __syncthreads();
    if (j < DB) Fb2[j] = 1.7159f * ftanh(0.666f * (b_bb + fpart[j] + fpart[j + DB]));
    __syncthreads();
    {
      float Fr[DB];
#pragma unroll
      for (int q = 0; q < 32; ++q) *(float4*)(Fr + 4 * q) = *(const float4*)(Fb2 + 4 * q);
      const u16* rp[8] = {
        f1W + (size_t)u0 * DB, f1W + (size_t)u1 * DB,
        f2W + (size_t)u0 * DB, f2W + (size_t)u1 * DB,
        taW + (size_t)u0 * DB, taW + (size_t)u1 * DB,
        tbW + (size_t)u0 * DB, tbW + (size_t)u1 * DB };
      float sacc[8] = { b_f1_0, b_f1_1, b_f2_0, b_f2_1, b_ta_0, b_ta_1, b_tb_0, b_tb_1 };
#pragma unroll
      for (int rr = 0; rr < 8; ++rr) {
        float acc = sacc[rr];
        const u16* r = rp[rr];
#pragma unroll
        for (int kk = 0; kk < DB; kk += 8) fma8(acc, *(const uint4*)(r + kk), Fr + kk);
        sacc[rr] = acc;
      }
      const float ti0 = fsig(sacc[4] + sacc[6]);
      const float ti1 = fsig(sacc[5] + sacc[7]);
      hprev[u0] = fmaf(ftanh(sacc[0]), 1.f - ti0, ti0 * ftanh(sacc[2]));
      hprev[u1] = fmaf(ftanh(sacc[1]), 1.f - ti1, ti1 * ftanh(sacc[3]));
    }
    __syncthreads();
    if (j < 128) {
      const int l = j & 63;
      float acc = 0.f;
#pragma unroll
      for (int q = 0; q < 8; ++q) acc = fmaf(hprev[q * 64 + l], hwr[q], acc);
#pragma unroll
      for (int off = 32; off > 0; off >>= 1) acc += __shfl_down(acc, off, 64);
      if (l == 0) out[((size_t)b * TT + t) * 2 + (j >> 6)] = acc + hbr;
    }
  }
  out[(size_t)NB * TT * 2 + (size_t)b * DH + u0] = hprev[u0];
  out[(size_t)NB * TT * 2 + (size_t)b * DH + u1] = hprev[u1];
}

extern "C" void kernel_launch(void* const* d_in, const int* in_sizes, int n_in,
                              void* d_out, int out_size, void* d_ws, size_t ws_size,
                              hipStream_t stream) {
  (void)in_sizes; (void)n_in; (void)out_size;

  if (ws_size >= WS_NEED) {
    char* ws = (char*)d_ws;
    int* flag = (int*)ws;
    detect_kernel<<<dim3(1), dim3(64), 0, stream>>>(
        (const u16*)d_in[0], (const u16*)d_in[1], (const u16*)d_in[3], flag);
    pwzx_kernel<<<dim3(8, 32), dim3(256), 0, stream>>>(d_in[1], flag, (u32*)(ws + O_WZX));
    qwz_kernel<<<dim3(2048), dim3(64), 0, stream>>>(d_in[3], flag,
                                                    (u32*)(ws + O_WZ8), (float*)(ws + O_SWZ));
    qbb_kernel<<<dim3(128), dim3(64), 0, stream>>>(d_in[4], flag,
                                                   (u32*)(ws + O_BB8), (float*)(ws + O_SBB));
    qff_kernel<<<dim3(512, 4), dim3(32), 0, stream>>>(d_in[6], d_in[8], d_in[10],
                                                      d_in[12], flag,
                                                      (u32*)(ws + O_FF8), (float*)(ws + O_SFF));
    psmall_kernel<<<dim3(1), dim3(1024), 0, stream>>>(
        d_in[2], d_in[7], d_in[9], d_in[11], d_in[13], d_in[5], d_in[14], d_in[15],
        flag, (float*)(ws + O_BIF), (float*)(ws + O_FFB), (float*)(ws + O_BBBF),
        (u32*)(ws + O_HWP), (float*)(ws + O_HBF));

    scan18<<<dim3(128), dim3(1024), 0, stream>>>(
        d_in[0], flag,
        (const u32*)(ws + O_WZX), (const u32*)(ws + O_WZ8), (const float*)(ws + O_SWZ),
        (const u32*)(ws + O_BB8), (const float*)(ws + O_SBB),
        (const u32*)(ws + O_FF8), (const float*)(ws + O_SFF),
        (const float*)(ws + O_BIF), (const float*)(ws + O_FFB),
        (const float*)(ws + O_BBBF), (const u32*)(ws + O_HWP),
        (const float*)(ws + O_HBF), (float*)d_out);
  } else {
    fb_scan<<<dim3(NB), dim3(256), 0, stream>>>(
        (const u16*)d_in[0],  (const u16*)d_in[1],  (const u16*)d_in[2],
        (const u16*)d_in[3],  (const u16*)d_in[4],  (const u16*)d_in[5],
        (const u16*)d_in[6],  (const u16*)d_in[7],  (const u16*)d_in[8],
        (const u16*)d_in[9],  (const u16*)d_in[10], (const u16*)d_in[11],
        (const u16*)d_in[12], (const u16*)d_in[13], (const u16*)d_in[14],
        (const u16*)d_in[15], (float*)d_out);
  }
}

// Round 12
// 11816.342 us; speedup vs baseline: 2.1015x; 1.1171x over previous
//
#include <hip/hip_runtime.h>

#define NB 128
#define TT 1024
#define DI 64
#define DH 512
#define DB 128
#define GZ 2048
#define KZ 576
#define BST 136   // bbL LDS row stride; with qq=4q+s4 interleave -> 2-way max aliasing

typedef unsigned short u16;
typedef unsigned char u8;
typedef unsigned int u32;
typedef unsigned long long u64;

#if defined(__has_builtin)
#if __has_builtin(__builtin_amdgcn_fdot2)
#define HAS_FDOT2 1
#endif
#if __has_builtin(__builtin_amdgcn_sdot4)
#define HAS_SDOT4 1
#endif
#endif

typedef _Float16 half2v __attribute__((ext_vector_type(2)));

__device__ __forceinline__ float bf2f(u16 u) {
  union { u32 i; float f; } v; v.i = ((u32)u) << 16; return v.f;
}
__device__ __forceinline__ float fsig(float x) {
  return __builtin_amdgcn_rcpf(1.f + __expf(-x));
}
__device__ __forceinline__ float ftanh(float x) {
  return 1.f - 2.f * __builtin_amdgcn_rcpf(__expf(2.f * x) + 1.f);
}
__device__ __forceinline__ float dot2p(u32 w, u32 a, float acc) {
#ifdef HAS_FDOT2
  return __builtin_amdgcn_fdot2(__builtin_bit_cast(half2v, w),
                                __builtin_bit_cast(half2v, a), acc, false);
#else
  half2v hw = __builtin_bit_cast(half2v, w), ha = __builtin_bit_cast(half2v, a);
  acc = fmaf((float)hw.x, (float)ha.x, acc);
  return fmaf((float)hw.y, (float)ha.y, acc);
#endif
}
__device__ __forceinline__ int dot4i(u32 w, u32 a, int acc) {
#ifdef HAS_SDOT4
  return __builtin_amdgcn_sdot4((int)w, (int)a, acc, false);
#else
  acc += (((int)(w << 24)) >> 24) * (((int)(a << 24)) >> 24);
  acc += (((int)(w << 16)) >> 24) * (((int)(a << 16)) >> 24);
  acc += (((int)(w << 8))  >> 24) * (((int)(a << 8))  >> 24);
  acc += (((int)w) >> 24)         * (((int)a) >> 24);
  return acc;
#endif
}
__device__ __forceinline__ u32 packf16(float x, float y) {
  half2v h; h.x = (_Float16)x; h.y = (_Float16)y;
  return __builtin_bit_cast(u32, h);
}
__device__ __forceinline__ u16 f16b(float x) {
  _Float16 h = (_Float16)x;
  return __builtin_bit_cast(u16, h);
}

// ---- ws layout (bytes, 256-aligned); GATE-INTERLEAVED content ----
#define O_WZX  256                       // wzxG: [k2][u] uint4 (4 gates f16-pairs): 32*2048 u32
#define O_WZ8  (O_WZX + 262144)          // wzG: [q][u] uint4 (4 gates i8-quads): 128*2048 u32
#define O_SWZ  (O_WZ8 + 1048576)         // swzG: [u][g] f32[2048]
#define O_BB8  (O_SWZ + 8192)            // bb i8 quads: 144*128 u32 (unchanged)
#define O_SBB  (O_BB8 + 73728)           // bb weight scales: f32[128]
#define O_FF8  (O_SBB + 512)             // ffG: [l][u] uint4 (4 mats): 32*2048 u32
#define O_SFF  (O_FF8 + 262144)          // sffG: [u][mat] f32[2048]
#define O_BIF  (O_SFF + 8192)            // bi f32[2048]
#define O_FFB  (O_BIF + 8192)            // ff biases f32[4*512]
#define O_BBBF (O_FFB + 8192)            // bbb f32[128]
#define O_HWP  (O_BBBF + 512)            // head pairs u32[512]
#define O_HBF  (O_HWP + 2048)            // hb f32[2]
#define WS_NEED ((u64)(O_HBF + 256))     // ~1.68 MB

// ---------------- dtype detection (validated rounds 3-8) ----------------
__global__ void detect_kernel(const u16* x, const u16* wi, const u16* wh, int* flag) {
  const int l = threadIdx.x;
  int cnt = (((x[2 * l] >> 7) & 0xFF) < 134)
          + (((wi[2 * l] >> 7) & 0xFF) < 134)
          + (((wh[2 * l] >> 7) & 0xFF) < 134);
#pragma unroll
  for (int off = 32; off > 0; off >>= 1) cnt += __shfl_down(cnt, off, 64);
  if (l == 0) *flag = (cnt >= 180) ? 1 : 0;
}

__device__ __forceinline__ float ldf(int f, const void* s, u32 i) {
  return f ? bf2f(((const u16*)s)[i]) : ((const float*)s)[i];
}

// ---- prep: Wz x-part f16 pairs, gate-interleaved ----
__global__ void pwzx_kernel(const void* Wi, const int* __restrict__ flag,
                            u32* __restrict__ wzxG) {
  const int o = blockIdx.x * 256 + threadIdx.x;   // z-row 0..2047
  const int k2 = blockIdx.y;
  const int f = *flag;
  const u32 i = (u32)o * DI + 2 * k2;
  wzxG[(u32)k2 * GZ + (((u32)(o & 511)) << 2) + (o >> 9)] =
      packf16(ldf(f, Wi, i), ldf(f, Wi, i + 1));
}

// ---- prep: Wz h-part -> i8, gate-interleaved; per-row scale ----
__global__ void qwz_kernel(const void* Wh, const int* __restrict__ flag,
                           u32* __restrict__ wzG, float* __restrict__ swzG) {
  const int o = blockIdx.x;       // z-row 0..2047
  const int l = threadIdx.x;
  const int f = *flag;
  float w[8]; float mx = 0.f;
#pragma unroll
  for (int qq = 0; qq < 2; ++qq) {
    const int q = l + 64 * qq;
#pragma unroll
    for (int e = 0; e < 4; ++e) {
      const float v = ldf(f, Wh, (u32)o * DH + 4 * q + e);
      w[qq * 4 + e] = v; mx = fmaxf(mx, fabsf(v));
    }
  }
#pragma unroll
  for (int off = 32; off > 0; off >>= 1) mx = fmaxf(mx, __shfl_xor(mx, off, 64));
  mx = fmaxf(mx, 1e-20f);
  const float inv = 127.f / mx;
  if (l == 0) swzG[(((u32)(o & 511)) << 2) + (o >> 9)] = mx / (127.f * 127.f);
#pragma unroll
  for (int qq = 0; qq < 2; ++qq) {
    const int q = l + 64 * qq;
    u32 p = 0;
#pragma unroll
    for (int e = 0; e < 4; ++e) {
      int b = (int)rintf(w[qq * 4 + e] * inv);
      b = b > 127 ? 127 : (b < -127 ? -127 : b);
      p |= ((u32)(b & 0xff)) << (8 * e);
    }
    wzG[(u32)q * GZ + (((u32)(o & 511)) << 2) + (o >> 9)] = p;
  }
}

// ---- prep: backbone -> i8, per-output scale (layout unchanged) ----
__global__ void qbb_kernel(const void* bb, const int* __restrict__ flag,
                           u32* __restrict__ bb8, float* __restrict__ sbb) {
  const int m = blockIdx.x;      // 0..127
  const int l = threadIdx.x;     // 0..63
  const int f = *flag;
  float mx = 0.f;
#pragma unroll
  for (int q = 0; q < 9; ++q)
    mx = fmaxf(mx, fabsf(ldf(f, bb, (u32)m * KZ + l + 64 * q)));
#pragma unroll
  for (int off = 32; off > 0; off >>= 1) mx = fmaxf(mx, __shfl_xor(mx, off, 64));
  mx = fmaxf(mx, 1e-20f);
  const float inv = 127.f / mx;
  if (l == 0) sbb[m] = mx / 127.f;
  for (int k4 = l; k4 < 144; k4 += 64) {
    u32 p = 0;
#pragma unroll
    for (int e = 0; e < 4; ++e) {
      int b = (int)rintf(ldf(f, bb, (u32)m * KZ + 4 * k4 + e) * inv);
      b = b > 127 ? 127 : (b < -127 ? -127 : b);
      p |= ((u32)(b & 0xff)) << (8 * e);
    }
    bb8[(u32)k4 * DB + m] = p;
  }
}

// ---- prep: ff -> i8, mat-interleaved uint4 per (l, unit) ----
__global__ void qff_kernel(const void* f1, const void* f2, const void* ta,
                           const void* tb, const int* __restrict__ flag,
                           u32* __restrict__ ffG, float* __restrict__ sffG) {
  const int o = blockIdx.x;      // 0..511 (unit)
  const int mat = blockIdx.y;    // 0..3
  const int l = threadIdx.x;     // 0..31 (k4)
  const void* s = (mat == 0) ? f1 : (mat == 1) ? f2 : (mat == 2) ? ta : tb;
  const int f = *flag;
  float w[4]; float mx = 0.f;
#pragma unroll
  for (int e = 0; e < 4; ++e) {
    w[e] = ldf(f, s, (u32)o * DB + 4 * l + e);
    mx = fmaxf(mx, fabsf(w[e]));
  }
#pragma unroll
  for (int off = 16; off > 0; off >>= 1) mx = fmaxf(mx, __shfl_xor(mx, off, 32));
  mx = fmaxf(mx, 1e-20f);
  const float inv = 127.f / mx;
  if (l == 0) sffG[((u32)o << 2) + mat] = (mx / 127.f) * (1.7159f / 127.f);
  u32 p = 0;
#pragma unroll
  for (int e = 0; e < 4; ++e) {
    int b = (int)rintf(w[e] * inv);
    b = b > 127 ? 127 : (b < -127 ? -127 : b);
    p |= ((u32)(b & 0xff)) << (8 * e);
  }
  ffG[(((u32)l * 512 + o) << 2) + mat] = p;
}

__global__ void psmall_kernel(const void* bi_s, const void* f1b_s, const void* f2b_s,
                              const void* tab_s, const void* tbb_s, const void* bbb_s,
                              const void* hw_s, const void* hb_s,
                              const int* __restrict__ flag,
                              float* __restrict__ bif, float* __restrict__ ffb,
                              float* __restrict__ bbbf, u32* __restrict__ hwp,
                              float* __restrict__ hbf) {
  const int f = *flag;
  for (int i = threadIdx.x; i < 2048; i += 1024) {
    bif[i] = ldf(f, bi_s, i);
    if (i < 512) {
      ffb[i]        = ldf(f, f1b_s, i);
      ffb[512 + i]  = ldf(f, f2b_s, i);
      ffb[1024 + i] = ldf(f, tab_s, i);
      ffb[1536 + i] = ldf(f, tbb_s, i);
      const int w = i >> 8, pr = i & 255;
      hwp[i] = packf16(ldf(f, hw_s, w * DH + 2 * pr), ldf(f, hw_s, w * DH + 2 * pr + 1));
    }
    if (i < 128) bbbf[i] = ldf(f, bbb_s, i);
    if (i < 2)   hbf[i] = ldf(f, hb_s, i);
  }
}

// ---- scan19 = scan18 + interleaved phase-2 chunks (bank fix, exact) +
//      2-step Zx register batching (wzxG read on even steps only, exact) ----
// x staged 2 steps ahead in 4 parity slots (f16 + i8 + scale). Even phase 1
// dual-accumulates Zx(t) and Zx(t+1); odd phase 1 uses saved registers.
// Same values, same per-accumulator order -> bit-identical to scan18.
__global__ __launch_bounds__(1024, 1)
void scan19(const void* __restrict__ xraw, const int* __restrict__ flagp,
            const u32* __restrict__ wzxG, const u32* __restrict__ wzG,
            const float* __restrict__ swzG,
            const u32* __restrict__ bb8, const float* __restrict__ sbb,
            const u32* __restrict__ ffG, const float* __restrict__ sffG,
            const float* __restrict__ bif, const float* __restrict__ ffbv,
            const float* __restrict__ bbbf, const u32* __restrict__ hwp,
            const float* __restrict__ hbf, float* __restrict__ out)
{
  __shared__ __align__(16) u32   xf16q[128];           // x f16 pairs, 4 slots x [k2]
  __shared__ __align__(16) u32   xi8q[64];             // x i8 quads, 4 slots x [k4<16]
  __shared__ __align__(16) u32   hl8q[128];            // h_lstm i8 quads [k4]
  __shared__ __align__(16) u32   ah8q[128];            // h(t-1) i8 quads [k4]
  __shared__ __align__(16) u32   hfR[256];             // h(t) f16 [unit] (u16 view)
  __shared__ __align__(16) float sxq[4];               // x quant scale per slot
  __shared__ __align__(16) u32   Fq8[32];              // F i8 quads [k4]
  __shared__ __align__(16) u32   bbL[144 * BST + 1024];// bb resident (stride 136) + pad
                                                       // total LDS ~85KB -> 1 block/CU

  const int j = threadIdx.x;
  const int b = blockIdx.x;          // batch row b (0..127)
  const int bf16in = *flagp;
  const int u = j & 511;

  // persistent per-unit state (j<512)
  float c0 = 0.f;
  float sxi = 0.f, sxg = 0.f, sxf = 0.f, sxo = 0.f;   // saved Zx(t+1) gates
  float bgi = 0, bgg = 0, bgf = 0, bgo = 0, cb1 = 0, cb2 = 0, cba = 0, cbb = 0;
  float4 zscl = make_float4(0, 0, 0, 0), sfv = make_float4(0, 0, 0, 0);
  if (j < 512) {
    bgi = bif[0 * DH + u]; bgg = bif[1 * DH + u];
    bgf = bif[2 * DH + u]; bgo = bif[3 * DH + u];
    cb1 = ffbv[0 * DH + u]; cb2 = ffbv[1 * DH + u];
    cba = ffbv[2 * DH + u]; cbb = ffbv[3 * DH + u];
    zscl = *(const float4*)(swzG + 4 * u);
    sfv  = *(const float4*)(sffG + 4 * u);
  }
  float sbbr = 0.f, bbr = 0.f;
  if (j < 512) { sbbr = sbb[j >> 2]; bbr = bbbf[j >> 2]; }
  u32 hwreg[4] = {0, 0, 0, 0}; float hbr = 0.f;
  int hw_ = 0, hl = 0;
  if (j >= 576 && j < 704) {
    const int jj = j - 576;
    hw_ = jj >> 6; hl = jj & 63;
#pragma unroll
    for (int i = 0; i < 4; ++i) hwreg[i] = hwp[hw_ * 256 + hl + 64 * i];
    hbr = hbf[hw_];
  }
  const float C127 = 1.f / 127.f;

  // ---- bb weights resident in LDS (once), stride BST ----
  for (int idx = j; idx < 144 * DB; idx += 1024) {
    const int q = idx >> 7, m = idx & 127;
    bbL[q * BST + m] = bb8[idx];
  }

  // ---- preamble: h0 = 0; stage x(0)->slot0, x(1)->slot1 (f16+i8+scale) ----
  if (j < 256) { hfR[j] = 0u; if (j < 128) ah8q[j] = 0u; }
  if (j >= 512 && j < 576) {
    const int s = (j - 512) >> 5, k2 = (j - 512) & 31;   // s in {0,1}
    const size_t xi = ((size_t)b * TT + s) * 32 + k2;
    float a, bb_;
    if (bf16in) {
      const u32 w = ((const u32*)xraw)[xi];
      a = bf2f((u16)(w & 0xffffu)); bb_ = bf2f((u16)(w >> 16));
    } else {
      const float2 v = ((const float2*)xraw)[xi];
      a = v.x; bb_ = v.y;
    }
    xf16q[s * 32 + k2] = packf16(a, bb_);
    float m = fmaxf(fabsf(a), fabsf(bb_));
#pragma unroll
    for (int off = 16; off > 0; off >>= 1) m = fmaxf(m, __shfl_xor(m, off, 32));
    m = fmaxf(m, 1e-20f);
    if (k2 == 0) sxq[s] = m * C127;
    const float inv = 127.f / m;
    const int q0 = (int)rintf(a * inv), q1 = (int)rintf(bb_ * inv);
    ((u16*)xi8q)[s * 32 + k2] = (u16)((q0 & 0xff) | ((q1 & 0xff) << 8));
  }
  __syncthreads();

  for (int t = 0; t < TT; ++t) {
    // ---- phase 1: Z h-part every step; Zx dual-batch on even steps ----
    if (j < 512) {
      int ii0 = 0, ig0 = 0, if0 = 0, io0 = 0;
      const u32* wph = wzG + 4 * u;
#pragma unroll 8
      for (int q = 0; q < 128; ++q) {
        const uint4 w = *(const uint4*)wph; wph += GZ;
        const u32 a0 = ah8q[q];
        ii0 = dot4i(w.x, a0, ii0); ig0 = dot4i(w.y, a0, ig0);
        if0 = dot4i(w.z, a0, if0); io0 = dot4i(w.w, a0, io0);
      }
      float xi0, xg0, xf0, xo0;
      if ((t & 1) == 0) {
        xi0 = 0; xg0 = 0; xf0 = 0; xo0 = 0;
        float xiN = 0, xgN = 0, xfN = 0, xoN = 0;
        const u32* wpx = wzxG + 4 * u;
        const u32* xc = xf16q + (t & 3) * 32;
        const u32* xn = xf16q + ((t + 1) & 3) * 32;
#pragma unroll 8
        for (int k2 = 0; k2 < 32; ++k2) {
          const uint4 w = *(const uint4*)wpx; wpx += GZ;
          const u32 a0 = xc[k2], a1 = xn[k2];
          xi0 = dot2p(w.x, a0, xi0); xg0 = dot2p(w.y, a0, xg0);
          xf0 = dot2p(w.z, a0, xf0); xo0 = dot2p(w.w, a0, xo0);
          xiN = dot2p(w.x, a1, xiN); xgN = dot2p(w.y, a1, xgN);
          xfN = dot2p(w.z, a1, xfN); xoN = dot2p(w.w, a1, xoN);
        }
        sxi = xiN; sxg = xgN; sxf = xfN; sxo = xoN;
      } else {
        xi0 = sxi; xg0 = sxg; xf0 = sxf; xo0 = sxo;
      }
      const float zi0 = bgi + xi0 + zscl.x * (float)ii0;
      const float zg0 = bgg + xg0 + zscl.y * (float)ig0;
      const float zf0 = bgf + xf0 + zscl.z * (float)if0;
      const float zo0 = bgo + xo0 + zscl.w * (float)io0;
      c0 = fmaf(c0, fsig(zf0 + 1.f), ftanh(zi0) * fsig(zg0));
      const float hl0 = ftanh(c0) * fsig(zo0);
      const int q0 = (int)rintf(hl0 * 127.f);
      ((u8*)hl8q)[u] = (u8)(q0 & 0xff);
    }
    __syncthreads();                                   // B1: h_lstm ready

    // ---- phase 2: backbone + F, interleaved 4-lane split (qq=4q+s4) ----
    if (j < 512) {
      const int m = j >> 2, s4 = j & 3;
      int ax0 = 0, ah0 = 0;
      const u32* xq = xi8q + (t & 3) * 16;
#pragma unroll
      for (int q = 0; q < 4; ++q) {
        const int qq = 4 * q + s4;                   // 0..15: x segment
        ax0 = dot4i(bbL[qq * BST + m], xq[qq], ax0);
      }
#pragma unroll 8
      for (int q = 4; q < 36; ++q) {
        const int qq = 4 * q + s4;                   // 16..143: h segment
        ah0 = dot4i(bbL[qq * BST + m], hl8q[qq - 16], ah0);
      }
      ax0 += __shfl_xor(ax0, 1, 64); ax0 += __shfl_xor(ax0, 2, 64);
      ah0 += __shfl_xor(ah0, 1, 64); ah0 += __shfl_xor(ah0, 2, 64);
      if (s4 == 0) {
        const float r0 = bbr + sbbr * (sxq[t & 3] * (float)ax0 + C127 * (float)ah0);
        const float F0 = 1.7159f * ftanh(0.666f * r0);
        const int q0 = (int)rintf(F0 * (127.f / 1.7159f));
        ((u8*)Fq8)[m] = (u8)(q0 & 0xff);
      }
    }
    __syncthreads();                                   // B2: F ready

    // ---- phase 3: ff (4 mats) + combine fused || stage x(t+2) ----
    if (j < 512) {
      int a10 = 0, a20 = 0, aa0 = 0, ab0 = 0;
      const u32* fw = ffG + 4 * u;
#pragma unroll 8
      for (int l = 0; l < 32; ++l) {
        const uint4 w = *(const uint4*)fw; fw += GZ;
        const u32 F0v = Fq8[l];
        a10 = dot4i(w.x, F0v, a10); a20 = dot4i(w.y, F0v, a20);
        aa0 = dot4i(w.z, F0v, aa0); ab0 = dot4i(w.w, F0v, ab0);
      }
      const float z10 = sfv.x * (float)a10 + cb1, z20 = sfv.y * (float)a20 + cb2;
      const float za0 = sfv.z * (float)aa0 + cba, zb0 = sfv.w * (float)ab0 + cbb;
      const float ti0 = fsig(za0 + zb0);
      const float hn0 = fmaf(ftanh(z10), 1.f - ti0, ti0 * ftanh(z20));
      ((u16*)hfR)[u] = f16b(hn0);
      const int q0 = (int)rintf(hn0 * 127.f);
      ((u8*)ah8q)[u] = (u8)(q0 & 0xff);
      if (t == TT - 1) {
        out[(size_t)NB * TT * 2 + (size_t)b * DH + u] = hn0;
      }
    } else if (j < 544 && t + 2 < TT) {
      const int k2 = j - 512;
      const int slot = (t + 2) & 3;
      const size_t xi = ((size_t)b * TT + (t + 2)) * 32 + k2;
      float a, bb_;
      if (bf16in) {
        const u32 w = ((const u32*)xraw)[xi];
        a = bf2f((u16)(w & 0xffffu)); bb_ = bf2f((u16)(w >> 16));
      } else {
        const float2 v = ((const float2*)xraw)[xi];
        a = v.x; bb_ = v.y;
      }
      xf16q[slot * 32 + k2] = packf16(a, bb_);
      float m = fmaxf(fabsf(a), fabsf(bb_));
#pragma unroll
      for (int off = 16; off > 0; off >>= 1) m = fmaxf(m, __shfl_xor(m, off, 32));
      m = fmaxf(m, 1e-20f);
      if (k2 == 0) sxq[slot] = m * C127;
      const float inv = 127.f / m;
      const int q0 = (int)rintf(a * inv), q1 = (int)rintf(bb_ * inv);
      ((u16*)xi8q)[slot * 32 + k2] = (u16)((q0 & 0xff) | ((q1 & 0xff) << 8));
    }
    __syncthreads();                                   // B3: h_new + x(t+2) ready

    // ---- phase 4: head (128 threads), runs in the shadow of next phase 1 ----
    if (j >= 576 && j < 704) {
      float acc = 0.f;
#pragma unroll
      for (int i = 0; i < 4; ++i)
        acc = dot2p(hwreg[i], hfR[hl + 64 * i], acc);
#pragma unroll
      for (int off = 32; off > 0; off >>= 1) acc += __shfl_down(acc, off, 64);
      if (hl == 0) out[((size_t)b * TT + t) * 2 + hw_] = acc + hbr;
    }
  }
}

// ---------------- fallback (round-3 verified, bf16 d_in, small ws) ----------------
__device__ __forceinline__ void fma8(float& acc, const uint4 u, const float* v) {
  union { u32 i; float f; } tt;
  tt.i = u.x << 16;          acc = fmaf(tt.f, v[0], acc);
  tt.i = u.x & 0xffff0000u;  acc = fmaf(tt.f, v[1], acc);
  tt.i = u.y << 16;          acc = fmaf(tt.f, v[2], acc);
  tt.i = u.y & 0xffff0000u;  acc = fmaf(tt.f, v[3], acc);
  tt.i = u.z << 16;          acc = fmaf(tt.f, v[4], acc);
  tt.i = u.z & 0xffff0000u;  acc = fmaf(tt.f, v[5], acc);
  tt.i = u.w << 16;          acc = fmaf(tt.f, v[6], acc);
  tt.i = u.w & 0xffff0000u;  acc = fmaf(tt.f, v[7], acc);
}
__global__ __launch_bounds__(256, 1)
void fb_scan(const u16* __restrict__ x,   const u16* __restrict__ Wi,
             const u16* __restrict__ bi,  const u16* __restrict__ Wh,
             const u16* __restrict__ bbW, const u16* __restrict__ bbb,
             const u16* __restrict__ f1W, const u16* __restrict__ f1b,
             const u16* __restrict__ f2W, const u16* __restrict__ f2b,
             const u16* __restrict__ taW, const u16* __restrict__ tab,
             const u16* __restrict__ tbW, const u16* __restrict__ tbb,
             const u16* __restrict__ hW,  const u16* __restrict__ hb,
             float* __restrict__ out)
{
  __shared__ __align__(16) float vcat[DI + DH];
  __shared__ __align__(16) float Fb2[DB];
  __shared__ __align__(16) float fpart[256];
  __shared__ __align__(16) float hprev[DH];
  const int j = threadIdx.x, b = blockIdx.x;
  const int u0 = j, u1 = j + 256;
  float bi_r[8];
#pragma unroll
  for (int k = 0; k < 8; ++k) bi_r[k] = bf2f(bi[j + 256 * k]);
  const float b_f1_0 = bf2f(f1b[u0]), b_f1_1 = bf2f(f1b[u1]);
  const float b_f2_0 = bf2f(f2b[u0]), b_f2_1 = bf2f(f2b[u1]);
  const float b_ta_0 = bf2f(tab[u0]), b_ta_1 = bf2f(tab[u1]);
  const float b_tb_0 = bf2f(tbb[u0]), b_tb_1 = bf2f(tbb[u1]);
  const float b_bb = (j < DB) ? bf2f(bbb[j]) : 0.f;
  float hwr[8]; float hbr = 0.f;
  if (j < 128) {
    const int w = j >> 6, l = j & 63;
#pragma unroll
    for (int q = 0; q < 8; ++q) hwr[q] = bf2f(hW[w * DH + q * 64 + l]);
    hbr = bf2f(hb[w]);
  }
  float c0 = 0.f, c1 = 0.f;
  hprev[u0] = 0.f; hprev[u1] = 0.f;
  const u16* xp = x + (size_t)b * TT * DI;
  __syncthreads();
  for (int t = 0; t < TT; ++t) {
    if (j < DI) vcat[j] = bf2f(xp[t * DI + j]);
    __syncthreads();
    float a[8];
#pragma unroll
    for (int k = 0; k < 8; ++k) a[k] = bi_r[k];
#pragma unroll
    for (int r = 0; r < 8; ++r) {
      const u16* wr = Wi + ((size_t)(j + 256 * r)) * DI;
      float acc = a[r];
#pragma unroll
      for (int kk = 0; kk < DI; kk += 8) fma8(acc, *(const uint4*)(wr + kk), vcat + kk);
      a[r] = acc;
    }
#pragma unroll 1
    for (int kb = 0; kb < DH; kb += 64) {
      float hreg[64];
#pragma unroll
      for (int q = 0; q < 16; ++q)
        *(float4*)(hreg + 4 * q) = *(const float4*)(hprev + kb + 4 * q);
#pragma unroll
      for (int r = 0; r < 8; ++r) {
        const u16* wr = Wh + ((size_t)(j + 256 * r)) * DH + kb;
        float acc = a[r];
#pragma unroll
        for (int cc = 0; cc < 8; ++cc) fma8(acc, *(const uint4*)(wr + 8 * cc), hreg + 8 * cc);
        a[r] = acc;
      }
    }
    {
      const float cn0 = fmaf(c0, fsig(a[4] + 1.f), ftanh(a[0]) * fsig(a[2]));
      const float cn1 = fmaf(c1, fsig(a[5] + 1.f), ftanh(a[1]) * fsig(a[3]));
      c0 = cn0; c1 = cn1;
      vcat[DI + u0] = ftanh(cn0) * fsig(a[6]);
      vcat[DI + u1] = ftanh(cn1) * fsig(a[7]);
    }
    __syncthreads();
    {
      const int mm = j & (DB - 1), pp = j >> 7;
      const u16* br = bbW + (size_t)mm * KZ + pp * 288;
      const float* vs = vcat + pp * 288;
      float s0 = 0.f, s1 = 0.f, s2v = 0.f, s3 = 0.f;
#pragma unroll
      for (int kk = 0; kk < 288; kk += 32) {
        fma8(s0, *(const uint4*)(br + kk), vs + kk);
        fma8(s1, *(const uint4*)(br + kk + 8), vs + kk + 8);
        fma8(s2v, *(const uint4*)(br + kk + 16), vs + kk + 16);
        fma8(s3, *(const uint4*)(br + kk + 24), vs + kk + 24);
      }
      fpart[j] = (s0 + s1) + (s2v + s3);
    }
    __syncthreads();
    if (j < DB) Fb2[j] = 1.7159f * ftanh(0.666f * (b_bb + fpart[j] + fpart[j + DB]));
    __syncthreads();
    {
      float Fr[DB];
#pragma unroll
      for (int q = 0; q < 32; ++q) *(float4*)(Fr + 4 * q) = *(const float4*)(Fb2 + 4 * q);
      const u16* rp[8] = {
        f1W + (size_t)u0 * DB, f1W + (size_t)u1 * DB,
        f2W + (size_t)u0 * DB, f2W + (size_t)u1 * DB,
        taW + (size_t)u0 * DB, taW + (size_t)u1 * DB,
        tbW + (size_t)u0 * DB, tbW + (size_t)u1 * DB };
      float sacc[8] = { b_f1_0, b_f1_1, b_f2_0, b_f2_1, b_ta_0, b_ta_1, b_tb_0, b_tb_1 };
#pragma unroll
      for (int rr = 0; rr < 8; ++rr) {
        float acc = sacc[rr];
        const u16* r = rp[rr];
#pragma unroll
        for (int kk = 0; kk < DB; kk += 8) fma8(acc, *(const uint4*)(r + kk), Fr + kk);
        sacc[rr] = acc;
      }
      const float ti0 = fsig(sacc[4] + sacc[6]);
      const float ti1 = fsig(sacc[5] + sacc[7]);
      hprev[u0] = fmaf(ftanh(sacc[0]), 1.f - ti0, ti0 * ftanh(sacc[2]));
      hprev[u1] = fmaf(ftanh(sacc[1]), 1.f - ti1, ti1 * ftanh(sacc[3]));
    }
    __syncthreads();
    if (j < 128) {
      const int l = j & 63;
      float acc = 0.f;
#pragma unroll
      for (int q = 0; q < 8; ++q) acc = fmaf(hprev[q * 64 + l], hwr[q], acc);
#pragma unroll
      for (int off = 32; off > 0; off >>= 1) acc += __shfl_down(acc, off, 64);
      if (l == 0) out[((size_t)b * TT + t) * 2 + (j >> 6)] = acc + hbr;
    }
  }
  out[(size_t)NB * TT * 2 + (size_t)b * DH + u0] = hprev[u0];
  out[(size_t)NB * TT * 2 + (size_t)b * DH + u1] = hprev[u1];
}

extern "C" void kernel_launch(void* const* d_in, const int* in_sizes, int n_in,
                              void* d_out, int out_size, void* d_ws, size_t ws_size,
                              hipStream_t stream) {
  (void)in_sizes; (void)n_in; (void)out_size;

  if (ws_size >= WS_NEED) {
    char* ws = (char*)d_ws;
    int* flag = (int*)ws;
    detect_kernel<<<dim3(1), dim3(64), 0, stream>>>(
        (const u16*)d_in[0], (const u16*)d_in[1], (const u16*)d_in[3], flag);
    pwzx_kernel<<<dim3(8, 32), dim3(256), 0, stream>>>(d_in[1], flag, (u32*)(ws + O_WZX));
    qwz_kernel<<<dim3(2048), dim3(64), 0, stream>>>(d_in[3], flag,
                                                    (u32*)(ws + O_WZ8), (float*)(ws + O_SWZ));
    qbb_kernel<<<dim3(128), dim3(64), 0, stream>>>(d_in[4], flag,
                                                   (u32*)(ws + O_BB8), (float*)(ws + O_SBB));
    qff_kernel<<<dim3(512, 4), dim3(32), 0, stream>>>(d_in[6], d_in[8], d_in[10],
                                                      d_in[12], flag,
                                                      (u32*)(ws + O_FF8), (float*)(ws + O_SFF));
    psmall_kernel<<<dim3(1), dim3(1024), 0, stream>>>(
        d_in[2], d_in[7], d_in[9], d_in[11], d_in[13], d_in[5], d_in[14], d_in[15],
        flag, (float*)(ws + O_BIF), (float*)(ws + O_FFB), (float*)(ws + O_BBBF),
        (u32*)(ws + O_HWP), (float*)(ws + O_HBF));

    scan19<<<dim3(128), dim3(1024), 0, stream>>>(
        d_in[0], flag,
        (const u32*)(ws + O_WZX), (const u32*)(ws + O_WZ8), (const float*)(ws + O_SWZ),
        (const u32*)(ws + O_BB8), (const float*)(ws + O_SBB),
        (const u32*)(ws + O_FF8), (const float*)(ws + O_SFF),
        (const float*)(ws + O_BIF), (const float*)(ws + O_FFB),
        (const float*)(ws + O_BBBF), (const u32*)(ws + O_HWP),
        (const float*)(ws + O_HBF), (float*)d_out);
  } else {
    fb_scan<<<dim3(NB), dim3(256), 0, stream>>>(
        (const u16*)d_in[0],  (const u16*)d_in[1],  (const u16*)d_in[2],
        (const u16*)d_in[3],  (const u16*)d_in[4],  (const u16*)d_in[5],
        (const u16*)d_in[6],  (const u16*)d_in[7],  (const u16*)d_in[8],
        (const u16*)d_in[9],  (const u16*)d_in[10], (const u16*)d_in[11],
        (const u16*)d_in[12], (const u16*)d_in[13], (const u16*)d_in[14],
        (const u16*)d_in[15], (float*)d_out);
  }
}

// Round 13
// 11486.137 us; speedup vs baseline: 2.1619x; 1.0287x over previous
//
#include <hip/hip_runtime.h>

#define NB 128
#define TT 1024
#define DI 64
#define DH 512
#define DB 128
#define GZ 2048
#define KZ 576
#define BST 136   // bbL LDS row stride; with qq=4q+s4 interleave -> 2-way max aliasing

typedef unsigned short u16;
typedef unsigned char u8;
typedef unsigned int u32;
typedef unsigned long long u64;

#if defined(__has_builtin)
#if __has_builtin(__builtin_amdgcn_fdot2)
#define HAS_FDOT2 1
#endif
#if __has_builtin(__builtin_amdgcn_sdot4)
#define HAS_SDOT4 1
#endif
#endif

typedef _Float16 half2v __attribute__((ext_vector_type(2)));

__device__ __forceinline__ float bf2f(u16 u) {
  union { u32 i; float f; } v; v.i = ((u32)u) << 16; return v.f;
}
__device__ __forceinline__ float fsig(float x) {
  return __builtin_amdgcn_rcpf(1.f + __expf(-x));
}
__device__ __forceinline__ float ftanh(float x) {
  return 1.f - 2.f * __builtin_amdgcn_rcpf(__expf(2.f * x) + 1.f);
}
__device__ __forceinline__ float dot2p(u32 w, u32 a, float acc) {
#ifdef HAS_FDOT2
  return __builtin_amdgcn_fdot2(__builtin_bit_cast(half2v, w),
                                __builtin_bit_cast(half2v, a), acc, false);
#else
  half2v hw = __builtin_bit_cast(half2v, w), ha = __builtin_bit_cast(half2v, a);
  acc = fmaf((float)hw.x, (float)ha.x, acc);
  return fmaf((float)hw.y, (float)ha.y, acc);
#endif
}
__device__ __forceinline__ int dot4i(u32 w, u32 a, int acc) {
#ifdef HAS_SDOT4
  return __builtin_amdgcn_sdot4((int)w, (int)a, acc, false);
#else
  acc += (((int)(w << 24)) >> 24) * (((int)(a << 24)) >> 24);
  acc += (((int)(w << 16)) >> 24) * (((int)(a << 16)) >> 24);
  acc += (((int)(w << 8))  >> 24) * (((int)(a << 8))  >> 24);
  acc += (((int)w) >> 24)         * (((int)a) >> 24);
  return acc;
#endif
}
__device__ __forceinline__ u32 packf16(float x, float y) {
  half2v h; h.x = (_Float16)x; h.y = (_Float16)y;
  return __builtin_bit_cast(u32, h);
}
__device__ __forceinline__ u16 f16b(float x) {
  _Float16 h = (_Float16)x;
  return __builtin_bit_cast(u16, h);
}

// ---- ws layout (bytes, 256-aligned); GATE-INTERLEAVED content ----
#define O_WZX  256                       // wzxG: [k2][u] uint4 (4 gates f16-pairs): 32*2048 u32
#define O_WZ8  (O_WZX + 262144)          // wzG: [q][u] uint4 (4 gates i8-quads): 128*2048 u32
#define O_SWZ  (O_WZ8 + 1048576)         // swzG: [u][g] f32[2048]
#define O_BB8  (O_SWZ + 8192)            // bb i8 quads: 144*128 u32 (unchanged)
#define O_SBB  (O_BB8 + 73728)           // bb weight scales: f32[128]
#define O_FF8  (O_SBB + 512)             // ffG: [l][u] uint4 (4 mats): 32*2048 u32
#define O_SFF  (O_FF8 + 262144)          // sffG: [u][mat] f32[2048]
#define O_BIF  (O_SFF + 8192)            // bi f32[2048]
#define O_FFB  (O_BIF + 8192)            // ff biases f32[4*512]
#define O_BBBF (O_FFB + 8192)            // bbb f32[128]
#define O_HWP  (O_BBBF + 512)            // head pairs u32[512]
#define O_HBF  (O_HWP + 2048)            // hb f32[2]
#define WS_NEED ((u64)(O_HBF + 256))     // ~1.68 MB

// ---------------- dtype detection (validated rounds 3-8) ----------------
__global__ void detect_kernel(const u16* x, const u16* wi, const u16* wh, int* flag) {
  const int l = threadIdx.x;
  int cnt = (((x[2 * l] >> 7) & 0xFF) < 134)
          + (((wi[2 * l] >> 7) & 0xFF) < 134)
          + (((wh[2 * l] >> 7) & 0xFF) < 134);
#pragma unroll
  for (int off = 32; off > 0; off >>= 1) cnt += __shfl_down(cnt, off, 64);
  if (l == 0) *flag = (cnt >= 180) ? 1 : 0;
}

__device__ __forceinline__ float ldf(int f, const void* s, u32 i) {
  return f ? bf2f(((const u16*)s)[i]) : ((const float*)s)[i];
}

// ---- prep: Wz x-part f16 pairs, gate-interleaved ----
__global__ void pwzx_kernel(const void* Wi, const int* __restrict__ flag,
                            u32* __restrict__ wzxG) {
  const int o = blockIdx.x * 256 + threadIdx.x;   // z-row 0..2047
  const int k2 = blockIdx.y;
  const int f = *flag;
  const u32 i = (u32)o * DI + 2 * k2;
  wzxG[(u32)k2 * GZ + (((u32)(o & 511)) << 2) + (o >> 9)] =
      packf16(ldf(f, Wi, i), ldf(f, Wi, i + 1));
}

// ---- prep: Wz h-part -> i8, gate-interleaved; per-row scale ----
__global__ void qwz_kernel(const void* Wh, const int* __restrict__ flag,
                           u32* __restrict__ wzG, float* __restrict__ swzG) {
  const int o = blockIdx.x;       // z-row 0..2047
  const int l = threadIdx.x;
  const int f = *flag;
  float w[8]; float mx = 0.f;
#pragma unroll
  for (int qq = 0; qq < 2; ++qq) {
    const int q = l + 64 * qq;
#pragma unroll
    for (int e = 0; e < 4; ++e) {
      const float v = ldf(f, Wh, (u32)o * DH + 4 * q + e);
      w[qq * 4 + e] = v; mx = fmaxf(mx, fabsf(v));
    }
  }
#pragma unroll
  for (int off = 32; off > 0; off >>= 1) mx = fmaxf(mx, __shfl_xor(mx, off, 64));
  mx = fmaxf(mx, 1e-20f);
  const float inv = 127.f / mx;
  if (l == 0) swzG[(((u32)(o & 511)) << 2) + (o >> 9)] = mx / (127.f * 127.f);
#pragma unroll
  for (int qq = 0; qq < 2; ++qq) {
    const int q = l + 64 * qq;
    u32 p = 0;
#pragma unroll
    for (int e = 0; e < 4; ++e) {
      int b = (int)rintf(w[qq * 4 + e] * inv);
      b = b > 127 ? 127 : (b < -127 ? -127 : b);
      p |= ((u32)(b & 0xff)) << (8 * e);
    }
    wzG[(u32)q * GZ + (((u32)(o & 511)) << 2) + (o >> 9)] = p;
  }
}

// ---- prep: backbone -> i8, per-output scale (layout unchanged) ----
__global__ void qbb_kernel(const void* bb, const int* __restrict__ flag,
                           u32* __restrict__ bb8, float* __restrict__ sbb) {
  const int m = blockIdx.x;      // 0..127
  const int l = threadIdx.x;     // 0..63
  const int f = *flag;
  float mx = 0.f;
#pragma unroll
  for (int q = 0; q < 9; ++q)
    mx = fmaxf(mx, fabsf(ldf(f, bb, (u32)m * KZ + l + 64 * q)));
#pragma unroll
  for (int off = 32; off > 0; off >>= 1) mx = fmaxf(mx, __shfl_xor(mx, off, 64));
  mx = fmaxf(mx, 1e-20f);
  const float inv = 127.f / mx;
  if (l == 0) sbb[m] = mx / 127.f;
  for (int k4 = l; k4 < 144; k4 += 64) {
    u32 p = 0;
#pragma unroll
    for (int e = 0; e < 4; ++e) {
      int b = (int)rintf(ldf(f, bb, (u32)m * KZ + 4 * k4 + e) * inv);
      b = b > 127 ? 127 : (b < -127 ? -127 : b);
      p |= ((u32)(b & 0xff)) << (8 * e);
    }
    bb8[(u32)k4 * DB + m] = p;
  }
}

// ---- prep: ff -> i8, mat-interleaved uint4 per (l, unit) ----
__global__ void qff_kernel(const void* f1, const void* f2, const void* ta,
                           const void* tb, const int* __restrict__ flag,
                           u32* __restrict__ ffG, float* __restrict__ sffG) {
  const int o = blockIdx.x;      // 0..511 (unit)
  const int mat = blockIdx.y;    // 0..3
  const int l = threadIdx.x;     // 0..31 (k4)
  const void* s = (mat == 0) ? f1 : (mat == 1) ? f2 : (mat == 2) ? ta : tb;
  const int f = *flag;
  float w[4]; float mx = 0.f;
#pragma unroll
  for (int e = 0; e < 4; ++e) {
    w[e] = ldf(f, s, (u32)o * DB + 4 * l + e);
    mx = fmaxf(mx, fabsf(w[e]));
  }
#pragma unroll
  for (int off = 16; off > 0; off >>= 1) mx = fmaxf(mx, __shfl_xor(mx, off, 32));
  mx = fmaxf(mx, 1e-20f);
  const float inv = 127.f / mx;
  if (l == 0) sffG[((u32)o << 2) + mat] = (mx / 127.f) * (1.7159f / 127.f);
  u32 p = 0;
#pragma unroll
  for (int e = 0; e < 4; ++e) {
    int b = (int)rintf(w[e] * inv);
    b = b > 127 ? 127 : (b < -127 ? -127 : b);
    p |= ((u32)(b & 0xff)) << (8 * e);
  }
  ffG[(((u32)l * 512 + o) << 2) + mat] = p;
}

__global__ void psmall_kernel(const void* bi_s, const void* f1b_s, const void* f2b_s,
                              const void* tab_s, const void* tbb_s, const void* bbb_s,
                              const void* hw_s, const void* hb_s,
                              const int* __restrict__ flag,
                              float* __restrict__ bif, float* __restrict__ ffb,
                              float* __restrict__ bbbf, u32* __restrict__ hwp,
                              float* __restrict__ hbf) {
  const int f = *flag;
  for (int i = threadIdx.x; i < 2048; i += 1024) {
    bif[i] = ldf(f, bi_s, i);
    if (i < 512) {
      ffb[i]        = ldf(f, f1b_s, i);
      ffb[512 + i]  = ldf(f, f2b_s, i);
      ffb[1024 + i] = ldf(f, tab_s, i);
      ffb[1536 + i] = ldf(f, tbb_s, i);
      const int w = i >> 8, pr = i & 255;
      hwp[i] = packf16(ldf(f, hw_s, w * DH + 2 * pr), ldf(f, hw_s, w * DH + 2 * pr + 1));
    }
    if (i < 128) bbbf[i] = ldf(f, bbb_s, i);
    if (i < 2)   hbf[i] = ldf(f, hb_s, i);
  }
}

// ---- scan20 = scan19 with W=4 Zx register batching (wzxG read every 4th step)
// x staged 4 steps ahead in 8 parity slots (f16 + i8 + scale). Steps t%4==0
// quad-accumulate Zx(t..t+3); steps 1-3 use saved registers. Same values,
// same per-accumulator order -> bit-identical to scan19.
__global__ __launch_bounds__(1024, 1)
void scan20(const void* __restrict__ xraw, const int* __restrict__ flagp,
            const u32* __restrict__ wzxG, const u32* __restrict__ wzG,
            const float* __restrict__ swzG,
            const u32* __restrict__ bb8, const float* __restrict__ sbb,
            const u32* __restrict__ ffG, const float* __restrict__ sffG,
            const float* __restrict__ bif, const float* __restrict__ ffbv,
            const float* __restrict__ bbbf, const u32* __restrict__ hwp,
            const float* __restrict__ hbf, float* __restrict__ out)
{
  __shared__ __align__(16) u32   xf16q[256];           // x f16 pairs, 8 slots x [k2]
  __shared__ __align__(16) u32   xi8q[128];            // x i8 quads, 8 slots x [k4<16]
  __shared__ __align__(16) u32   hl8q[128];            // h_lstm i8 quads [k4]
  __shared__ __align__(16) u32   ah8q[128];            // h(t-1) i8 quads [k4]
  __shared__ __align__(16) u32   hfR[256];             // h(t) f16 [unit] (u16 view)
  __shared__ __align__(16) float sxq[8];               // x quant scale per slot
  __shared__ __align__(16) u32   Fq8[32];              // F i8 quads [k4]
  __shared__ __align__(16) u32   bbL[144 * BST + 1024];// bb resident (stride 136) + pad
                                                       // total LDS ~86KB -> 1 block/CU

  const int j = threadIdx.x;
  const int b = blockIdx.x;          // batch row b (0..127)
  const int bf16in = *flagp;
  const int u = j & 511;

  // persistent per-unit state (j<512)
  float c0 = 0.f;
  // saved Zx for steps t+1..t+3 (filled on t%4==0)
  float s1i = 0, s1g = 0, s1f = 0, s1o = 0;
  float s2i = 0, s2g = 0, s2f = 0, s2o = 0;
  float s3i = 0, s3g = 0, s3f = 0, s3o = 0;
  float bgi = 0, bgg = 0, bgf = 0, bgo = 0, cb1 = 0, cb2 = 0, cba = 0, cbb = 0;
  float4 zscl = make_float4(0, 0, 0, 0), sfv = make_float4(0, 0, 0, 0);
  if (j < 512) {
    bgi = bif[0 * DH + u]; bgg = bif[1 * DH + u];
    bgf = bif[2 * DH + u]; bgo = bif[3 * DH + u];
    cb1 = ffbv[0 * DH + u]; cb2 = ffbv[1 * DH + u];
    cba = ffbv[2 * DH + u]; cbb = ffbv[3 * DH + u];
    zscl = *(const float4*)(swzG + 4 * u);
    sfv  = *(const float4*)(sffG + 4 * u);
  }
  float sbbr = 0.f, bbr = 0.f;
  if (j < 512) { sbbr = sbb[j >> 2]; bbr = bbbf[j >> 2]; }
  u32 hwreg[4] = {0, 0, 0, 0}; float hbr = 0.f;
  int hw_ = 0, hl = 0;
  if (j >= 576 && j < 704) {
    const int jj = j - 576;
    hw_ = jj >> 6; hl = jj & 63;
#pragma unroll
    for (int i = 0; i < 4; ++i) hwreg[i] = hwp[hw_ * 256 + hl + 64 * i];
    hbr = hbf[hw_];
  }
  const float C127 = 1.f / 127.f;

  // ---- bb weights resident in LDS (once), stride BST ----
  for (int idx = j; idx < 144 * DB; idx += 1024) {
    const int q = idx >> 7, m = idx & 127;
    bbL[q * BST + m] = bb8[idx];
  }

  // ---- preamble: h0 = 0; stage x(0..3) -> slots 0..3 (f16+i8+scale) ----
  if (j < 256) { hfR[j] = 0u; if (j < 128) ah8q[j] = 0u; }
  if (j >= 512 && j < 640) {
    const int s = (j - 512) >> 5, k2 = (j - 512) & 31;   // s in {0..3}
    const size_t xi = ((size_t)b * TT + s) * 32 + k2;
    float a, bb_;
    if (bf16in) {
      const u32 w = ((const u32*)xraw)[xi];
      a = bf2f((u16)(w & 0xffffu)); bb_ = bf2f((u16)(w >> 16));
    } else {
      const float2 v = ((const float2*)xraw)[xi];
      a = v.x; bb_ = v.y;
    }
    xf16q[s * 32 + k2] = packf16(a, bb_);
    float m = fmaxf(fabsf(a), fabsf(bb_));
#pragma unroll
    for (int off = 16; off > 0; off >>= 1) m = fmaxf(m, __shfl_xor(m, off, 32));
    m = fmaxf(m, 1e-20f);
    if (k2 == 0) sxq[s] = m * C127;
    const float inv = 127.f / m;
    const int q0 = (int)rintf(a * inv), q1 = (int)rintf(bb_ * inv);
    ((u16*)xi8q)[s * 32 + k2] = (u16)((q0 & 0xff) | ((q1 & 0xff) << 8));
  }
  __syncthreads();

  for (int t = 0; t < TT; ++t) {
    // ---- phase 1: Z h-part every step; Zx quad-batch on t%4==0 ----
    if (j < 512) {
      int ii0 = 0, ig0 = 0, if0 = 0, io0 = 0;
      const u32* wph = wzG + 4 * u;
#pragma unroll 8
      for (int q = 0; q < 128; ++q) {
        const uint4 w = *(const uint4*)wph; wph += GZ;
        const u32 a0 = ah8q[q];
        ii0 = dot4i(w.x, a0, ii0); ig0 = dot4i(w.y, a0, ig0);
        if0 = dot4i(w.z, a0, if0); io0 = dot4i(w.w, a0, io0);
      }
      float xi0, xg0, xf0, xo0;
      const int ph = t & 3;
      if (ph == 0) {
        float a0i = 0, a0g = 0, a0f = 0, a0o = 0;
        float a1i = 0, a1g = 0, a1f = 0, a1o = 0;
        float a2i = 0, a2g = 0, a2f = 0, a2o = 0;
        float a3i = 0, a3g = 0, a3f = 0, a3o = 0;
        const u32* wpx = wzxG + 4 * u;
        const int base = t & 7;                       // slots base..base+3
        const u32* x0 = xf16q + ((base + 0) & 7) * 32;
        const u32* x1 = xf16q + ((base + 1) & 7) * 32;
        const u32* x2 = xf16q + ((base + 2) & 7) * 32;
        const u32* x3 = xf16q + ((base + 3) & 7) * 32;
#pragma unroll 4
        for (int k2 = 0; k2 < 32; ++k2) {
          const uint4 w = *(const uint4*)wpx; wpx += GZ;
          u32 a;
          a = x0[k2];
          a0i = dot2p(w.x, a, a0i); a0g = dot2p(w.y, a, a0g);
          a0f = dot2p(w.z, a, a0f); a0o = dot2p(w.w, a, a0o);
          a = x1[k2];
          a1i = dot2p(w.x, a, a1i); a1g = dot2p(w.y, a, a1g);
          a1f = dot2p(w.z, a, a1f); a1o = dot2p(w.w, a, a1o);
          a = x2[k2];
          a2i = dot2p(w.x, a, a2i); a2g = dot2p(w.y, a, a2g);
          a2f = dot2p(w.z, a, a2f); a2o = dot2p(w.w, a, a2o);
          a = x3[k2];
          a3i = dot2p(w.x, a, a3i); a3g = dot2p(w.y, a, a3g);
          a3f = dot2p(w.z, a, a3f); a3o = dot2p(w.w, a, a3o);
        }
        xi0 = a0i; xg0 = a0g; xf0 = a0f; xo0 = a0o;
        s1i = a1i; s1g = a1g; s1f = a1f; s1o = a1o;
        s2i = a2i; s2g = a2g; s2f = a2f; s2o = a2o;
        s3i = a3i; s3g = a3g; s3f = a3f; s3o = a3o;
      } else if (ph == 1) {
        xi0 = s1i; xg0 = s1g; xf0 = s1f; xo0 = s1o;
      } else if (ph == 2) {
        xi0 = s2i; xg0 = s2g; xf0 = s2f; xo0 = s2o;
      } else {
        xi0 = s3i; xg0 = s3g; xf0 = s3f; xo0 = s3o;
      }
      const float zi0 = bgi + xi0 + zscl.x * (float)ii0;
      const float zg0 = bgg + xg0 + zscl.y * (float)ig0;
      const float zf0 = bgf + xf0 + zscl.z * (float)if0;
      const float zo0 = bgo + xo0 + zscl.w * (float)io0;
      c0 = fmaf(c0, fsig(zf0 + 1.f), ftanh(zi0) * fsig(zg0));
      const float hl0 = ftanh(c0) * fsig(zo0);
      const int q0 = (int)rintf(hl0 * 127.f);
      ((u8*)hl8q)[u] = (u8)(q0 & 0xff);
    }
    __syncthreads();                                   // B1: h_lstm ready

    // ---- phase 2: backbone + F, interleaved 4-lane split (qq=4q+s4) ----
    if (j < 512) {
      const int m = j >> 2, s4 = j & 3;
      int ax0 = 0, ah0 = 0;
      const u32* xq = xi8q + (t & 7) * 16;
#pragma unroll
      for (int q = 0; q < 4; ++q) {
        const int qq = 4 * q + s4;                   // 0..15: x segment
        ax0 = dot4i(bbL[qq * BST + m], xq[qq], ax0);
      }
#pragma unroll 8
      for (int q = 4; q < 36; ++q) {
        const int qq = 4 * q + s4;                   // 16..143: h segment
        ah0 = dot4i(bbL[qq * BST + m], hl8q[qq - 16], ah0);
      }
      ax0 += __shfl_xor(ax0, 1, 64); ax0 += __shfl_xor(ax0, 2, 64);
      ah0 += __shfl_xor(ah0, 1, 64); ah0 += __shfl_xor(ah0, 2, 64);
      if (s4 == 0) {
        const float r0 = bbr + sbbr * (sxq[t & 7] * (float)ax0 + C127 * (float)ah0);
        const float F0 = 1.7159f * ftanh(0.666f * r0);
        const int q0 = (int)rintf(F0 * (127.f / 1.7159f));
        ((u8*)Fq8)[m] = (u8)(q0 & 0xff);
      }
    }
    __syncthreads();                                   // B2: F ready

    // ---- phase 3: ff (4 mats) + combine fused || stage x(t+4) ----
    if (j < 512) {
      int a10 = 0, a20 = 0, aa0 = 0, ab0 = 0;
      const u32* fw = ffG + 4 * u;
#pragma unroll 8
      for (int l = 0; l < 32; ++l) {
        const uint4 w = *(const uint4*)fw; fw += GZ;
        const u32 F0v = Fq8[l];
        a10 = dot4i(w.x, F0v, a10); a20 = dot4i(w.y, F0v, a20);
        aa0 = dot4i(w.z, F0v, aa0); ab0 = dot4i(w.w, F0v, ab0);
      }
      const float z10 = sfv.x * (float)a10 + cb1, z20 = sfv.y * (float)a20 + cb2;
      const float za0 = sfv.z * (float)aa0 + cba, zb0 = sfv.w * (float)ab0 + cbb;
      const float ti0 = fsig(za0 + zb0);
      const float hn0 = fmaf(ftanh(z10), 1.f - ti0, ti0 * ftanh(z20));
      ((u16*)hfR)[u] = f16b(hn0);
      const int q0 = (int)rintf(hn0 * 127.f);
      ((u8*)ah8q)[u] = (u8)(q0 & 0xff);
      if (t == TT - 1) {
        out[(size_t)NB * TT * 2 + (size_t)b * DH + u] = hn0;
      }
    } else if (j < 544 && t + 4 < TT) {
      const int k2 = j - 512;
      const int slot = (t + 4) & 7;
      const size_t xi = ((size_t)b * TT + (t + 4)) * 32 + k2;
      float a, bb_;
      if (bf16in) {
        const u32 w = ((const u32*)xraw)[xi];
        a = bf2f((u16)(w & 0xffffu)); bb_ = bf2f((u16)(w >> 16));
      } else {
        const float2 v = ((const float2*)xraw)[xi];
        a = v.x; bb_ = v.y;
      }
      xf16q[slot * 32 + k2] = packf16(a, bb_);
      float m = fmaxf(fabsf(a), fabsf(bb_));
#pragma unroll
      for (int off = 16; off > 0; off >>= 1) m = fmaxf(m, __shfl_xor(m, off, 32));
      m = fmaxf(m, 1e-20f);
      if (k2 == 0) sxq[slot] = m * C127;
      const float inv = 127.f / m;
      const int q0 = (int)rintf(a * inv), q1 = (int)rintf(bb_ * inv);
      ((u16*)xi8q)[slot * 32 + k2] = (u16)((q0 & 0xff) | ((q1 & 0xff) << 8));
    }
    __syncthreads();                                   // B3: h_new + x(t+4) ready

    // ---- phase 4: head (128 threads), runs in the shadow of next phase 1 ----
    if (j >= 576 && j < 704) {
      float acc = 0.f;
#pragma unroll
      for (int i = 0; i < 4; ++i)
        acc = dot2p(hwreg[i], hfR[hl + 64 * i], acc);
#pragma unroll
      for (int off = 32; off > 0; off >>= 1) acc += __shfl_down(acc, off, 64);
      if (hl == 0) out[((size_t)b * TT + t) * 2 + hw_] = acc + hbr;
    }
  }
}

// ---------------- fallback (round-3 verified, bf16 d_in, small ws) ----------------
__device__ __forceinline__ void fma8(float& acc, const uint4 u, const float* v) {
  union { u32 i; float f; } tt;
  tt.i = u.x << 16;          acc = fmaf(tt.f, v[0], acc);
  tt.i = u.x & 0xffff0000u;  acc = fmaf(tt.f, v[1], acc);
  tt.i = u.y << 16;          acc = fmaf(tt.f, v[2], acc);
  tt.i = u.y & 0xffff0000u;  acc = fmaf(tt.f, v[3], acc);
  tt.i = u.z << 16;          acc = fmaf(tt.f, v[4], acc);
  tt.i = u.z & 0xffff0000u;  acc = fmaf(tt.f, v[5], acc);
  tt.i = u.w << 16;          acc = fmaf(tt.f, v[6], acc);
  tt.i = u.w & 0xffff0000u;  acc = fmaf(tt.f, v[7], acc);
}
__global__ __launch_bounds__(256, 1)
void fb_scan(const u16* __restrict__ x,   const u16* __restrict__ Wi,
             const u16* __restrict__ bi,  const u16* __restrict__ Wh,
             const u16* __restrict__ bbW, const u16* __restrict__ bbb,
             const u16* __restrict__ f1W, const u16* __restrict__ f1b,
             const u16* __restrict__ f2W, const u16* __restrict__ f2b,
             const u16* __restrict__ taW, const u16* __restrict__ tab,
             const u16* __restrict__ tbW, const u16* __restrict__ tbb,
             const u16* __restrict__ hW,  const u16* __restrict__ hb,
             float* __restrict__ out)
{
  __shared__ __align__(16) float vcat[DI + DH];
  __shared__ __align__(16) float Fb2[DB];
  __shared__ __align__(16) float fpart[256];
  __shared__ __align__(16) float hprev[DH];
  const int j = threadIdx.x, b = blockIdx.x;
  const int u0 = j, u1 = j + 256;
  float bi_r[8];
#pragma unroll
  for (int k = 0; k < 8; ++k) bi_r[k] = bf2f(bi[j + 256 * k]);
  const float b_f1_0 = bf2f(f1b[u0]), b_f1_1 = bf2f(f1b[u1]);
  const float b_f2_0 = bf2f(f2b[u0]), b_f2_1 = bf2f(f2b[u1]);
  const float b_ta_0 = bf2f(tab[u0]), b_ta_1 = bf2f(tab[u1]);
  const float b_tb_0 = bf2f(tbb[u0]), b_tb_1 = bf2f(tbb[u1]);
  const float b_bb = (j < DB) ? bf2f(bbb[j]) : 0.f;
  float hwr[8]; float hbr = 0.f;
  if (j < 128) {
    const int w = j >> 6, l = j & 63;
#pragma unroll
    for (int q = 0; q < 8; ++q) hwr[q] = bf2f(hW[w * DH + q * 64 + l]);
    hbr = bf2f(hb[w]);
  }
  float c0 = 0.f, c1 = 0.f;
  hprev[u0] = 0.f; hprev[u1] = 0.f;
  const u16* xp = x + (size_t)b * TT * DI;
  __syncthreads();
  for (int t = 0; t < TT; ++t) {
    if (j < DI) vcat[j] = bf2f(xp[t * DI + j]);
    __syncthreads();
    float a[8];
#pragma unroll
    for (int k = 0; k < 8; ++k) a[k] = bi_r[k];
#pragma unroll
    for (int r = 0; r < 8; ++r) {
      const u16* wr = Wi + ((size_t)(j + 256 * r)) * DI;
      float acc = a[r];
#pragma unroll
      for (int kk = 0; kk < DI; kk += 8) fma8(acc, *(const uint4*)(wr + kk), vcat + kk);
      a[r] = acc;
    }
#pragma unroll 1
    for (int kb = 0; kb < DH; kb += 64) {
      float hreg[64];
#pragma unroll
      for (int q = 0; q < 16; ++q)
        *(float4*)(hreg + 4 * q) = *(const float4*)(hprev + kb + 4 * q);
#pragma unroll
      for (int r = 0; r < 8; ++r) {
        const u16* wr = Wh + ((size_t)(j + 256 * r)) * DH + kb;
        float acc = a[r];
#pragma unroll
        for (int cc = 0; cc < 8; ++cc) fma8(acc, *(const uint4*)(wr + 8 * cc), hreg + 8 * cc);
        a[r] = acc;
      }
    }
    {
      const float cn0 = fmaf(c0, fsig(a[4] + 1.f), ftanh(a[0]) * fsig(a[2]));
      const float cn1 = fmaf(c1, fsig(a[5] + 1.f), ftanh(a[1]) * fsig(a[3]));
      c0 = cn0; c1 = cn1;
      vcat[DI + u0] = ftanh(cn0) * fsig(a[6]);
      vcat[DI + u1] = ftanh(cn1) * fsig(a[7]);
    }
    __syncthreads();
    {
      const int mm = j & (DB - 1), pp = j >> 7;
      const u16* br = bbW + (size_t)mm * KZ + pp * 288;
      const float* vs = vcat + pp * 288;
      float s0 = 0.f, s1 = 0.f, s2v = 0.f, s3 = 0.f;
#pragma unroll
      for (int kk = 0; kk < 288; kk += 32) {
        fma8(s0, *(const uint4*)(br + kk), vs + kk);
        fma8(s1, *(const uint4*)(br + kk + 8), vs + kk + 8);
        fma8(s2v, *(const uint4*)(br + kk + 16), vs + kk + 16);
        fma8(s3, *(const uint4*)(br + kk + 24), vs + kk + 24);
      }
      fpart[j] = (s0 + s1) + (s2v + s3);
    }
    __syncthreads();
    if (j < DB) Fb2[j] = 1.7159f * ftanh(0.666f * (b_bb + fpart[j] + fpart[j + DB]));
    __syncthreads();
    {
      float Fr[DB];
#pragma unroll
      for (int q = 0; q < 32; ++q) *(float4*)(Fr + 4 * q) = *(const float4*)(Fb2 + 4 * q);
      const u16* rp[8] = {
        f1W + (size_t)u0 * DB, f1W + (size_t)u1 * DB,
        f2W + (size_t)u0 * DB, f2W + (size_t)u1 * DB,
        taW + (size_t)u0 * DB, taW + (size_t)u1 * DB,
        tbW + (size_t)u0 * DB, tbW + (size_t)u1 * DB };
      float sacc[8] = { b_f1_0, b_f1_1, b_f2_0, b_f2_1, b_ta_0, b_ta_1, b_tb_0, b_tb_1 };
#pragma unroll
      for (int rr = 0; rr < 8; ++rr) {
        float acc = sacc[rr];
        const u16* r = rp[rr];
#pragma unroll
        for (int kk = 0; kk < DB; kk += 8) fma8(acc, *(const uint4*)(r + kk), Fr + kk);
        sacc[rr] = acc;
      }
      const float ti0 = fsig(sacc[4] + sacc[6]);
      const float ti1 = fsig(sacc[5] + sacc[7]);
      hprev[u0] = fmaf(ftanh(sacc[0]), 1.f - ti0, ti0 * ftanh(sacc[2]));
      hprev[u1] = fmaf(ftanh(sacc[1]), 1.f - ti1, ti1 * ftanh(sacc[3]));
    }
    __syncthreads();
    if (j < 128) {
      const int l = j & 63;
      float acc = 0.f;
#pragma unroll
      for (int q = 0; q < 8; ++q) acc = fmaf(hprev[q * 64 + l], hwr[q], acc);
#pragma unroll
      for (int off = 32; off > 0; off >>= 1) acc += __shfl_down(acc, off, 64);
      if (l == 0) out[((size_t)b * TT + t) * 2 + (j >> 6)] = acc + hbr;
    }
  }
  out[(size_t)NB * TT * 2 + (size_t)b * DH + u0] = hprev[u0];
  out[(size_t)NB * TT * 2 + (size_t)b * DH + u1] = hprev[u1];
}

extern "C" void kernel_launch(void* const* d_in, const int* in_sizes, int n_in,
                              void* d_out, int out_size, void* d_ws, size_t ws_size,
                              hipStream_t stream) {
  (void)in_sizes; (void)n_in; (void)out_size;

  if (ws_size >= WS_NEED) {
    char* ws = (char*)d_ws;
    int* flag = (int*)ws;
    detect_kernel<<<dim3(1), dim3(64), 0, stream>>>(
        (const u16*)d_in[0], (const u16*)d_in[1], (const u16*)d_in[3], flag);
    pwzx_kernel<<<dim3(8, 32), dim3(256), 0, stream>>>(d_in[1], flag, (u32*)(ws + O_WZX));
    qwz_kernel<<<dim3(2048), dim3(64), 0, stream>>>(d_in[3], flag,
                                                    (u32*)(ws + O_WZ8), (float*)(ws + O_SWZ));
    qbb_kernel<<<dim3(128), dim3(64), 0, stream>>>(d_in[4], flag,
                                                   (u32*)(ws + O_BB8), (float*)(ws + O_SBB));
    qff_kernel<<<dim3(512, 4), dim3(32), 0, stream>>>(d_in[6], d_in[8], d_in[10],
                                                      d_in[12], flag,
                                                      (u32*)(ws + O_FF8), (float*)(ws + O_SFF));
    psmall_kernel<<<dim3(1), dim3(1024), 0, stream>>>(
        d_in[2], d_in[7], d_in[9], d_in[11], d_in[13], d_in[5], d_in[14], d_in[15],
        flag, (float*)(ws + O_BIF), (float*)(ws + O_FFB), (float*)(ws + O_BBBF),
        (u32*)(ws + O_HWP), (float*)(ws + O_HBF));

    scan20<<<dim3(128), dim3(1024), 0, stream>>>(
        d_in[0], flag,
        (const u32*)(ws + O_WZX), (const u32*)(ws + O_WZ8), (const float*)(ws + O_SWZ),
        (const u32*)(ws + O_BB8), (const float*)(ws + O_SBB),
        (const u32*)(ws + O_FF8), (const float*)(ws + O_SFF),
        (const float*)(ws + O_BIF), (const float*)(ws + O_FFB),
        (const float*)(ws + O_BBBF), (const u32*)(ws + O_HWP),
        (const float*)(ws + O_HBF), (float*)d_out);
  } else {
    fb_scan<<<dim3(NB), dim3(256), 0, stream>>>(
        (const u16*)d_in[0],  (const u16*)d_in[1],  (const u16*)d_in[2],
        (const u16*)d_in[3],  (const u16*)d_in[4],  (const u16*)d_in[5],
        (const u16*)d_in[6],  (const u16*)d_in[7],  (const u16*)d_in[8],
        (const u16*)d_in[9],  (const u16*)d_in[10], (const u16*)d_in[11],
        (const u16*)d_in[12], (const u16*)d_in[13], (const u16*)d_in[14],
        (const u16*)d_in[15], (float*)d_out);
  }
}

// Round 14
// 11180.400 us; speedup vs baseline: 2.2210x; 1.0273x over previous
//
#include <hip/hip_runtime.h>

#define NB 128
#define TT 1024
#define DI 64
#define DH 512
#define DB 128
#define GZ 2048
#define KZ 576
#define BST 136   // bbL LDS row stride; with qq=4q+s4 interleave -> 2-way max aliasing
#define WZL_Q 8   // wzG q-rows resident in LDS (8 rows x 8KB = 64KB)

typedef unsigned short u16;
typedef unsigned char u8;
typedef unsigned int u32;
typedef unsigned long long u64;

#if defined(__has_builtin)
#if __has_builtin(__builtin_amdgcn_fdot2)
#define HAS_FDOT2 1
#endif
#if __has_builtin(__builtin_amdgcn_sdot4)
#define HAS_SDOT4 1
#endif
#endif

typedef _Float16 half2v __attribute__((ext_vector_type(2)));

__device__ __forceinline__ float bf2f(u16 u) {
  union { u32 i; float f; } v; v.i = ((u32)u) << 16; return v.f;
}
__device__ __forceinline__ float fsig(float x) {
  return __builtin_amdgcn_rcpf(1.f + __expf(-x));
}
__device__ __forceinline__ float ftanh(float x) {
  return 1.f - 2.f * __builtin_amdgcn_rcpf(__expf(2.f * x) + 1.f);
}
__device__ __forceinline__ float dot2p(u32 w, u32 a, float acc) {
#ifdef HAS_FDOT2
  return __builtin_amdgcn_fdot2(__builtin_bit_cast(half2v, w),
                                __builtin_bit_cast(half2v, a), acc, false);
#else
  half2v hw = __builtin_bit_cast(half2v, w), ha = __builtin_bit_cast(half2v, a);
  acc = fmaf((float)hw.x, (float)ha.x, acc);
  return fmaf((float)hw.y, (float)ha.y, acc);
#endif
}
__device__ __forceinline__ int dot4i(u32 w, u32 a, int acc) {
#ifdef HAS_SDOT4
  return __builtin_amdgcn_sdot4((int)w, (int)a, acc, false);
#else
  acc += (((int)(w << 24)) >> 24) * (((int)(a << 24)) >> 24);
  acc += (((int)(w << 16)) >> 24) * (((int)(a << 16)) >> 24);
  acc += (((int)(w << 8))  >> 24) * (((int)(a << 8))  >> 24);
  acc += (((int)w) >> 24)         * (((int)a) >> 24);
  return acc;
#endif
}
__device__ __forceinline__ u32 packf16(float x, float y) {
  half2v h; h.x = (_Float16)x; h.y = (_Float16)y;
  return __builtin_bit_cast(u32, h);
}
__device__ __forceinline__ u16 f16b(float x) {
  _Float16 h = (_Float16)x;
  return __builtin_bit_cast(u16, h);
}

// ---- ws layout (bytes, 256-aligned); GATE-INTERLEAVED content ----
#define O_WZX  256                       // wzxG: [k2][u] uint4 (4 gates f16-pairs): 32*2048 u32
#define O_WZ8  (O_WZX + 262144)          // wzG: [q][u] uint4 (4 gates i8-quads): 128*2048 u32
#define O_SWZ  (O_WZ8 + 1048576)         // swzG: [u][g] f32[2048]
#define O_BB8  (O_SWZ + 8192)            // bb i8 quads: 144*128 u32 (unchanged)
#define O_SBB  (O_BB8 + 73728)           // bb weight scales: f32[128]
#define O_FF8  (O_SBB + 512)             // ffG: [l][u] uint4 (4 mats): 32*2048 u32
#define O_SFF  (O_FF8 + 262144)          // sffG: [u][mat] f32[2048]
#define O_BIF  (O_SFF + 8192)            // bi f32[2048]
#define O_FFB  (O_BIF + 8192)            // ff biases f32[4*512]
#define O_BBBF (O_FFB + 8192)            // bbb f32[128]
#define O_HWP  (O_BBBF + 512)            // head pairs u32[512]
#define O_HBF  (O_HWP + 2048)            // hb f32[2]
#define WS_NEED ((u64)(O_HBF + 256))     // ~1.68 MB

// ---------------- dtype detection (validated rounds 3-8) ----------------
__global__ void detect_kernel(const u16* x, const u16* wi, const u16* wh, int* flag) {
  const int l = threadIdx.x;
  int cnt = (((x[2 * l] >> 7) & 0xFF) < 134)
          + (((wi[2 * l] >> 7) & 0xFF) < 134)
          + (((wh[2 * l] >> 7) & 0xFF) < 134);
#pragma unroll
  for (int off = 32; off > 0; off >>= 1) cnt += __shfl_down(cnt, off, 64);
  if (l == 0) *flag = (cnt >= 180) ? 1 : 0;
}

__device__ __forceinline__ float ldf(int f, const void* s, u32 i) {
  return f ? bf2f(((const u16*)s)[i]) : ((const float*)s)[i];
}

// ---- prep: Wz x-part f16 pairs, gate-interleaved ----
__global__ void pwzx_kernel(const void* Wi, const int* __restrict__ flag,
                            u32* __restrict__ wzxG) {
  const int o = blockIdx.x * 256 + threadIdx.x;   // z-row 0..2047
  const int k2 = blockIdx.y;
  const int f = *flag;
  const u32 i = (u32)o * DI + 2 * k2;
  wzxG[(u32)k2 * GZ + (((u32)(o & 511)) << 2) + (o >> 9)] =
      packf16(ldf(f, Wi, i), ldf(f, Wi, i + 1));
}

// ---- prep: Wz h-part -> i8, gate-interleaved; per-row scale ----
__global__ void qwz_kernel(const void* Wh, const int* __restrict__ flag,
                           u32* __restrict__ wzG, float* __restrict__ swzG) {
  const int o = blockIdx.x;       // z-row 0..2047
  const int l = threadIdx.x;
  const int f = *flag;
  float w[8]; float mx = 0.f;
#pragma unroll
  for (int qq = 0; qq < 2; ++qq) {
    const int q = l + 64 * qq;
#pragma unroll
    for (int e = 0; e < 4; ++e) {
      const float v = ldf(f, Wh, (u32)o * DH + 4 * q + e);
      w[qq * 4 + e] = v; mx = fmaxf(mx, fabsf(v));
    }
  }
#pragma unroll
  for (int off = 32; off > 0; off >>= 1) mx = fmaxf(mx, __shfl_xor(mx, off, 64));
  mx = fmaxf(mx, 1e-20f);
  const float inv = 127.f / mx;
  if (l == 0) swzG[(((u32)(o & 511)) << 2) + (o >> 9)] = mx / (127.f * 127.f);
#pragma unroll
  for (int qq = 0; qq < 2; ++qq) {
    const int q = l + 64 * qq;
    u32 p = 0;
#pragma unroll
    for (int e = 0; e < 4; ++e) {
      int b = (int)rintf(w[qq * 4 + e] * inv);
      b = b > 127 ? 127 : (b < -127 ? -127 : b);
      p |= ((u32)(b & 0xff)) << (8 * e);
    }
    wzG[(u32)q * GZ + (((u32)(o & 511)) << 2) + (o >> 9)] = p;
  }
}

// ---- prep: backbone -> i8, per-output scale (layout unchanged) ----
__global__ void qbb_kernel(const void* bb, const int* __restrict__ flag,
                           u32* __restrict__ bb8, float* __restrict__ sbb) {
  const int m = blockIdx.x;      // 0..127
  const int l = threadIdx.x;     // 0..63
  const int f = *flag;
  float mx = 0.f;
#pragma unroll
  for (int q = 0; q < 9; ++q)
    mx = fmaxf(mx, fabsf(ldf(f, bb, (u32)m * KZ + l + 64 * q)));
#pragma unroll
  for (int off = 32; off > 0; off >>= 1) mx = fmaxf(mx, __shfl_xor(mx, off, 64));
  mx = fmaxf(mx, 1e-20f);
  const float inv = 127.f / mx;
  if (l == 0) sbb[m] = mx / 127.f;
  for (int k4 = l; k4 < 144; k4 += 64) {
    u32 p = 0;
#pragma unroll
    for (int e = 0; e < 4; ++e) {
      int b = (int)rintf(ldf(f, bb, (u32)m * KZ + 4 * k4 + e) * inv);
      b = b > 127 ? 127 : (b < -127 ? -127 : b);
      p |= ((u32)(b & 0xff)) << (8 * e);
    }
    bb8[(u32)k4 * DB + m] = p;
  }
}

// ---- prep: ff -> i8, mat-interleaved uint4 per (l, unit) ----
__global__ void qff_kernel(const void* f1, const void* f2, const void* ta,
                           const void* tb, const int* __restrict__ flag,
                           u32* __restrict__ ffG, float* __restrict__ sffG) {
  const int o = blockIdx.x;      // 0..511 (unit)
  const int mat = blockIdx.y;    // 0..3
  const int l = threadIdx.x;     // 0..31 (k4)
  const void* s = (mat == 0) ? f1 : (mat == 1) ? f2 : (mat == 2) ? ta : tb;
  const int f = *flag;
  float w[4]; float mx = 0.f;
#pragma unroll
  for (int e = 0; e < 4; ++e) {
    w[e] = ldf(f, s, (u32)o * DB + 4 * l + e);
    mx = fmaxf(mx, fabsf(w[e]));
  }
#pragma unroll
  for (int off = 16; off > 0; off >>= 1) mx = fmaxf(mx, __shfl_xor(mx, off, 32));
  mx = fmaxf(mx, 1e-20f);
  const float inv = 127.f / mx;
  if (l == 0) sffG[((u32)o << 2) + mat] = (mx / 127.f) * (1.7159f / 127.f);
  u32 p = 0;
#pragma unroll
  for (int e = 0; e < 4; ++e) {
    int b = (int)rintf(w[e] * inv);
    b = b > 127 ? 127 : (b < -127 ? -127 : b);
    p |= ((u32)(b & 0xff)) << (8 * e);
  }
  ffG[(((u32)l * 512 + o) << 2) + mat] = p;
}

__global__ void psmall_kernel(const void* bi_s, const void* f1b_s, const void* f2b_s,
                              const void* tab_s, const void* tbb_s, const void* bbb_s,
                              const void* hw_s, const void* hb_s,
                              const int* __restrict__ flag,
                              float* __restrict__ bif, float* __restrict__ ffb,
                              float* __restrict__ bbbf, u32* __restrict__ hwp,
                              float* __restrict__ hbf) {
  const int f = *flag;
  for (int i = threadIdx.x; i < 2048; i += 1024) {
    bif[i] = ldf(f, bi_s, i);
    if (i < 512) {
      ffb[i]        = ldf(f, f1b_s, i);
      ffb[512 + i]  = ldf(f, f2b_s, i);
      ffb[1024 + i] = ldf(f, tab_s, i);
      ffb[1536 + i] = ldf(f, tbb_s, i);
      const int w = i >> 8, pr = i & 255;
      hwp[i] = packf16(ldf(f, hw_s, w * DH + 2 * pr), ldf(f, hw_s, w * DH + 2 * pr + 1));
    }
    if (i < 128) bbbf[i] = ldf(f, bbb_s, i);
    if (i < 2)   hbf[i] = ldf(f, hb_s, i);
  }
}

// ---- scan21 = scan20 + first WZL_Q q-rows of wzG resident in LDS (64 KB) ----
// Port bytes for wzG: 1MB -> 896KB/step. Accumulation order q=0..127 kept
// (LDS rows first, then global rows) -> int-exact, bit-identical to scan20.
__global__ __launch_bounds__(1024, 1)
void scan21(const void* __restrict__ xraw, const int* __restrict__ flagp,
            const u32* __restrict__ wzxG, const u32* __restrict__ wzG,
            const float* __restrict__ swzG,
            const u32* __restrict__ bb8, const float* __restrict__ sbb,
            const u32* __restrict__ ffG, const float* __restrict__ sffG,
            const float* __restrict__ bif, const float* __restrict__ ffbv,
            const float* __restrict__ bbbf, const u32* __restrict__ hwp,
            const float* __restrict__ hbf, float* __restrict__ out)
{
  __shared__ __align__(16) u32   xf16q[256];           // x f16 pairs, 8 slots x [k2]
  __shared__ __align__(16) u32   xi8q[128];            // x i8 quads, 8 slots x [k4<16]
  __shared__ __align__(16) u32   hl8q[128];            // h_lstm i8 quads [k4]
  __shared__ __align__(16) u32   ah8q[128];            // h(t-1) i8 quads [k4]
  __shared__ __align__(16) u32   hfR[256];             // h(t) f16 [unit] (u16 view)
  __shared__ __align__(16) float sxq[8];               // x quant scale per slot
  __shared__ __align__(16) u32   Fq8[32];              // F i8 quads [k4]
  __shared__ __align__(16) u32   bbL[144 * BST + 1024];// bb resident (stride 136) + pad
  __shared__ __align__(16) u32   wzL[WZL_Q * GZ];      // wzG rows 0..7 resident: 64 KB
                                                       // total LDS ~148KB -> 1 block/CU

  const int j = threadIdx.x;
  const int b = blockIdx.x;          // batch row b (0..127)
  const int bf16in = *flagp;
  const int u = j & 511;

  // persistent per-unit state (j<512)
  float c0 = 0.f;
  // saved Zx for steps t+1..t+3 (filled on t%4==0)
  float s1i = 0, s1g = 0, s1f = 0, s1o = 0;
  float s2i = 0, s2g = 0, s2f = 0, s2o = 0;
  float s3i = 0, s3g = 0, s3f = 0, s3o = 0;
  float bgi = 0, bgg = 0, bgf = 0, bgo = 0, cb1 = 0, cb2 = 0, cba = 0, cbb = 0;
  float4 zscl = make_float4(0, 0, 0, 0), sfv = make_float4(0, 0, 0, 0);
  if (j < 512) {
    bgi = bif[0 * DH + u]; bgg = bif[1 * DH + u];
    bgf = bif[2 * DH + u]; bgo = bif[3 * DH + u];
    cb1 = ffbv[0 * DH + u]; cb2 = ffbv[1 * DH + u];
    cba = ffbv[2 * DH + u]; cbb = ffbv[3 * DH + u];
    zscl = *(const float4*)(swzG + 4 * u);
    sfv  = *(const float4*)(sffG + 4 * u);
  }
  float sbbr = 0.f, bbr = 0.f;
  if (j < 512) { sbbr = sbb[j >> 2]; bbr = bbbf[j >> 2]; }
  u32 hwreg[4] = {0, 0, 0, 0}; float hbr = 0.f;
  int hw_ = 0, hl = 0;
  if (j >= 576 && j < 704) {
    const int jj = j - 576;
    hw_ = jj >> 6; hl = jj & 63;
#pragma unroll
    for (int i = 0; i < 4; ++i) hwreg[i] = hwp[hw_ * 256 + hl + 64 * i];
    hbr = hbf[hw_];
  }
  const float C127 = 1.f / 127.f;

  // ---- resident LDS copies (once): bb (stride BST) + wzG rows 0..WZL_Q-1 ----
  for (int idx = j; idx < 144 * DB; idx += 1024) {
    const int q = idx >> 7, m = idx & 127;
    bbL[q * BST + m] = bb8[idx];
  }
  for (int idx = j; idx < WZL_Q * GZ; idx += 1024) wzL[idx] = wzG[idx];

  // ---- preamble: h0 = 0; stage x(0..3) -> slots 0..3 (f16+i8+scale) ----
  if (j < 256) { hfR[j] = 0u; if (j < 128) ah8q[j] = 0u; }
  if (j >= 512 && j < 640) {
    const int s = (j - 512) >> 5, k2 = (j - 512) & 31;   // s in {0..3}
    const size_t xi = ((size_t)b * TT + s) * 32 + k2;
    float a, bb_;
    if (bf16in) {
      const u32 w = ((const u32*)xraw)[xi];
      a = bf2f((u16)(w & 0xffffu)); bb_ = bf2f((u16)(w >> 16));
    } else {
      const float2 v = ((const float2*)xraw)[xi];
      a = v.x; bb_ = v.y;
    }
    xf16q[s * 32 + k2] = packf16(a, bb_);
    float m = fmaxf(fabsf(a), fabsf(bb_));
#pragma unroll
    for (int off = 16; off > 0; off >>= 1) m = fmaxf(m, __shfl_xor(m, off, 32));
    m = fmaxf(m, 1e-20f);
    if (k2 == 0) sxq[s] = m * C127;
    const float inv = 127.f / m;
    const int q0 = (int)rintf(a * inv), q1 = (int)rintf(bb_ * inv);
    ((u16*)xi8q)[s * 32 + k2] = (u16)((q0 & 0xff) | ((q1 & 0xff) << 8));
  }
  __syncthreads();

  for (int t = 0; t < TT; ++t) {
    // ---- phase 1: Z h-part (LDS rows then global rows); Zx quad-batch t%4==0 ----
    if (j < 512) {
      int ii0 = 0, ig0 = 0, if0 = 0, io0 = 0;
      const u32* wpl = wzL + 4 * u;
#pragma unroll
      for (int q = 0; q < WZL_Q; ++q) {
        const uint4 w = *(const uint4*)wpl; wpl += GZ;
        const u32 a0 = ah8q[q];
        ii0 = dot4i(w.x, a0, ii0); ig0 = dot4i(w.y, a0, ig0);
        if0 = dot4i(w.z, a0, if0); io0 = dot4i(w.w, a0, io0);
      }
      const u32* wph = wzG + (size_t)WZL_Q * GZ + 4 * u;
#pragma unroll 8
      for (int q = WZL_Q; q < 128; ++q) {
        const uint4 w = *(const uint4*)wph; wph += GZ;
        const u32 a0 = ah8q[q];
        ii0 = dot4i(w.x, a0, ii0); ig0 = dot4i(w.y, a0, ig0);
        if0 = dot4i(w.z, a0, if0); io0 = dot4i(w.w, a0, io0);
      }
      float xi0, xg0, xf0, xo0;
      const int ph = t & 3;
      if (ph == 0) {
        float a0i = 0, a0g = 0, a0f = 0, a0o = 0;
        float a1i = 0, a1g = 0, a1f = 0, a1o = 0;
        float a2i = 0, a2g = 0, a2f = 0, a2o = 0;
        float a3i = 0, a3g = 0, a3f = 0, a3o = 0;
        const u32* wpx = wzxG + 4 * u;
        const int base = t & 7;                       // slots base..base+3
        const u32* x0 = xf16q + ((base + 0) & 7) * 32;
        const u32* x1 = xf16q + ((base + 1) & 7) * 32;
        const u32* x2 = xf16q + ((base + 2) & 7) * 32;
        const u32* x3 = xf16q + ((base + 3) & 7) * 32;
#pragma unroll 4
        for (int k2 = 0; k2 < 32; ++k2) {
          const uint4 w = *(const uint4*)wpx; wpx += GZ;
          u32 a;
          a = x0[k2];
          a0i = dot2p(w.x, a, a0i); a0g = dot2p(w.y, a, a0g);
          a0f = dot2p(w.z, a, a0f); a0o = dot2p(w.w, a, a0o);
          a = x1[k2];
          a1i = dot2p(w.x, a, a1i); a1g = dot2p(w.y, a, a1g);
          a1f = dot2p(w.z, a, a1f); a1o = dot2p(w.w, a, a1o);
          a = x2[k2];
          a2i = dot2p(w.x, a, a2i); a2g = dot2p(w.y, a, a2g);
          a2f = dot2p(w.z, a, a2f); a2o = dot2p(w.w, a, a2o);
          a = x3[k2];
          a3i = dot2p(w.x, a, a3i); a3g = dot2p(w.y, a, a3g);
          a3f = dot2p(w.z, a, a3f); a3o = dot2p(w.w, a, a3o);
        }
        xi0 = a0i; xg0 = a0g; xf0 = a0f; xo0 = a0o;
        s1i = a1i; s1g = a1g; s1f = a1f; s1o = a1o;
        s2i = a2i; s2g = a2g; s2f = a2f; s2o = a2o;
        s3i = a3i; s3g = a3g; s3f = a3f; s3o = a3o;
      } else if (ph == 1) {
        xi0 = s1i; xg0 = s1g; xf0 = s1f; xo0 = s1o;
      } else if (ph == 2) {
        xi0 = s2i; xg0 = s2g; xf0 = s2f; xo0 = s2o;
      } else {
        xi0 = s3i; xg0 = s3g; xf0 = s3f; xo0 = s3o;
      }
      const float zi0 = bgi + xi0 + zscl.x * (float)ii0;
      const float zg0 = bgg + xg0 + zscl.y * (float)ig0;
      const float zf0 = bgf + xf0 + zscl.z * (float)if0;
      const float zo0 = bgo + xo0 + zscl.w * (float)io0;
      c0 = fmaf(c0, fsig(zf0 + 1.f), ftanh(zi0) * fsig(zg0));
      const float hl0 = ftanh(c0) * fsig(zo0);
      const int q0 = (int)rintf(hl0 * 127.f);
      ((u8*)hl8q)[u] = (u8)(q0 & 0xff);
    }
    __syncthreads();                                   // B1: h_lstm ready

    // ---- phase 2: backbone + F, interleaved 4-lane split (qq=4q+s4) ----
    if (j < 512) {
      const int m = j >> 2, s4 = j & 3;
      int ax0 = 0, ah0 = 0;
      const u32* xq = xi8q + (t & 7) * 16;
#pragma unroll
      for (int q = 0; q < 4; ++q) {
        const int qq = 4 * q + s4;                   // 0..15: x segment
        ax0 = dot4i(bbL[qq * BST + m], xq[qq], ax0);
      }
#pragma unroll 8
      for (int q = 4; q < 36; ++q) {
        const int qq = 4 * q + s4;                   // 16..143: h segment
        ah0 = dot4i(bbL[qq * BST + m], hl8q[qq - 16], ah0);
      }
      ax0 += __shfl_xor(ax0, 1, 64); ax0 += __shfl_xor(ax0, 2, 64);
      ah0 += __shfl_xor(ah0, 1, 64); ah0 += __shfl_xor(ah0, 2, 64);
      if (s4 == 0) {
        const float r0 = bbr + sbbr * (sxq[t & 7] * (float)ax0 + C127 * (float)ah0);
        const float F0 = 1.7159f * ftanh(0.666f * r0);
        const int q0 = (int)rintf(F0 * (127.f / 1.7159f));
        ((u8*)Fq8)[m] = (u8)(q0 & 0xff);
      }
    }
    __syncthreads();                                   // B2: F ready

    // ---- phase 3: ff (4 mats) + combine fused || stage x(t+4) ----
    if (j < 512) {
      int a10 = 0, a20 = 0, aa0 = 0, ab0 = 0;
      const u32* fw = ffG + 4 * u;
#pragma unroll 8
      for (int l = 0; l < 32; ++l) {
        const uint4 w = *(const uint4*)fw; fw += GZ;
        const u32 F0v = Fq8[l];
        a10 = dot4i(w.x, F0v, a10); a20 = dot4i(w.y, F0v, a20);
        aa0 = dot4i(w.z, F0v, aa0); ab0 = dot4i(w.w, F0v, ab0);
      }
      const float z10 = sfv.x * (float)a10 + cb1, z20 = sfv.y * (float)a20 + cb2;
      const float za0 = sfv.z * (float)aa0 + cba, zb0 = sfv.w * (float)ab0 + cbb;
      const float ti0 = fsig(za0 + zb0);
      const float hn0 = fmaf(ftanh(z10), 1.f - ti0, ti0 * ftanh(z20));
      ((u16*)hfR)[u] = f16b(hn0);
      const int q0 = (int)rintf(hn0 * 127.f);
      ((u8*)ah8q)[u] = (u8)(q0 & 0xff);
      if (t == TT - 1) {
        out[(size_t)NB * TT * 2 + (size_t)b * DH + u] = hn0;
      }
    } else if (j < 544 && t + 4 < TT) {
      const int k2 = j - 512;
      const int slot = (t + 4) & 7;
      const size_t xi = ((size_t)b * TT + (t + 4)) * 32 + k2;
      float a, bb_;
      if (bf16in) {
        const u32 w = ((const u32*)xraw)[xi];
        a = bf2f((u16)(w & 0xffffu)); bb_ = bf2f((u16)(w >> 16));
      } else {
        const float2 v = ((const float2*)xraw)[xi];
        a = v.x; bb_ = v.y;
      }
      xf16q[slot * 32 + k2] = packf16(a, bb_);
      float m = fmaxf(fabsf(a), fabsf(bb_));
#pragma unroll
      for (int off = 16; off > 0; off >>= 1) m = fmaxf(m, __shfl_xor(m, off, 32));
      m = fmaxf(m, 1e-20f);
      if (k2 == 0) sxq[slot] = m * C127;
      const float inv = 127.f / m;
      const int q0 = (int)rintf(a * inv), q1 = (int)rintf(bb_ * inv);
      ((u16*)xi8q)[slot * 32 + k2] = (u16)((q0 & 0xff) | ((q1 & 0xff) << 8));
    }
    __syncthreads();                                   // B3: h_new + x(t+4) ready

    // ---- phase 4: head (128 threads), runs in the shadow of next phase 1 ----
    if (j >= 576 && j < 704) {
      float acc = 0.f;
#pragma unroll
      for (int i = 0; i < 4; ++i)
        acc = dot2p(hwreg[i], hfR[hl + 64 * i], acc);
#pragma unroll
      for (int off = 32; off > 0; off >>= 1) acc += __shfl_down(acc, off, 64);
      if (hl == 0) out[((size_t)b * TT + t) * 2 + hw_] = acc + hbr;
    }
  }
}

// ---------------- fallback (round-3 verified, bf16 d_in, small ws) ----------------
__device__ __forceinline__ void fma8(float& acc, const uint4 u, const float* v) {
  union { u32 i; float f; } tt;
  tt.i = u.x << 16;          acc = fmaf(tt.f, v[0], acc);
  tt.i = u.x & 0xffff0000u;  acc = fmaf(tt.f, v[1], acc);
  tt.i = u.y << 16;          acc = fmaf(tt.f, v[2], acc);
  tt.i = u.y & 0xffff0000u;  acc = fmaf(tt.f, v[3], acc);
  tt.i = u.z << 16;          acc = fmaf(tt.f, v[4], acc);
  tt.i = u.z & 0xffff0000u;  acc = fmaf(tt.f, v[5], acc);
  tt.i = u.w << 16;          acc = fmaf(tt.f, v[6], acc);
  tt.i = u.w & 0xffff0000u;  acc = fmaf(tt.f, v[7], acc);
}
__global__ __launch_bounds__(256, 1)
void fb_scan(const u16* __restrict__ x,   const u16* __restrict__ Wi,
             const u16* __restrict__ bi,  const u16* __restrict__ Wh,
             const u16* __restrict__ bbW, const u16* __restrict__ bbb,
             const u16* __restrict__ f1W, const u16* __restrict__ f1b,
             const u16* __restrict__ f2W, const u16* __restrict__ f2b,
             const u16* __restrict__ taW, const u16* __restrict__ tab,
             const u16* __restrict__ tbW, const u16* __restrict__ tbb,
             const u16* __restrict__ hW,  const u16* __restrict__ hb,
             float* __restrict__ out)
{
  __shared__ __align__(16) float vcat[DI + DH];
  __shared__ __align__(16) float Fb2[DB];
  __shared__ __align__(16) float fpart[256];
  __shared__ __align__(16) float hprev[DH];
  const int j = threadIdx.x, b = blockIdx.x;
  const int u0 = j, u1 = j + 256;
  float bi_r[8];
#pragma unroll
  for (int k = 0; k < 8; ++k) bi_r[k] = bf2f(bi[j + 256 * k]);
  const float b_f1_0 = bf2f(f1b[u0]), b_f1_1 = bf2f(f1b[u1]);
  const float b_f2_0 = bf2f(f2b[u0]), b_f2_1 = bf2f(f2b[u1]);
  const float b_ta_0 = bf2f(tab[u0]), b_ta_1 = bf2f(tab[u1]);
  const float b_tb_0 = bf2f(tbb[u0]), b_tb_1 = bf2f(tbb[u1]);
  const float b_bb = (j < DB) ? bf2f(bbb[j]) : 0.f;
  float hwr[8]; float hbr = 0.f;
  if (j < 128) {
    const int w = j >> 6, l = j & 63;
#pragma unroll
    for (int q = 0; q < 8; ++q) hwr[q] = bf2f(hW[w * DH + q * 64 + l]);
    hbr = bf2f(hb[w]);
  }
  float c0 = 0.f, c1 = 0.f;
  hprev[u0] = 0.f; hprev[u1] = 0.f;
  const u16* xp = x + (size_t)b * TT * DI;
  __syncthreads();
  for (int t = 0; t < TT; ++t) {
    if (j < DI) vcat[j] = bf2f(xp[t * DI + j]);
    __syncthreads();
    float a[8];
#pragma unroll
    for (int k = 0; k < 8; ++k) a[k] = bi_r[k];
#pragma unroll
    for (int r = 0; r < 8; ++r) {
      const u16* wr = Wi + ((size_t)(j + 256 * r)) * DI;
      float acc = a[r];
#pragma unroll
      for (int kk = 0; kk < DI; kk += 8) fma8(acc, *(const uint4*)(wr + kk), vcat + kk);
      a[r] = acc;
    }
#pragma unroll 1
    for (int kb = 0; kb < DH; kb += 64) {
      float hreg[64];
#pragma unroll
      for (int q = 0; q < 16; ++q)
        *(float4*)(hreg + 4 * q) = *(const float4*)(hprev + kb + 4 * q);
#pragma unroll
      for (int r = 0; r < 8; ++r) {
        const u16* wr = Wh + ((size_t)(j + 256 * r)) * DH + kb;
        float acc = a[r];
#pragma unroll
        for (int cc = 0; cc < 8; ++cc) fma8(acc, *(const uint4*)(wr + 8 * cc), hreg + 8 * cc);
        a[r] = acc;
      }
    }
    {
      const float cn0 = fmaf(c0, fsig(a[4] + 1.f), ftanh(a[0]) * fsig(a[2]));
      const float cn1 = fmaf(c1, fsig(a[5] + 1.f), ftanh(a[1]) * fsig(a[3]));
      c0 = cn0; c1 = cn1;
      vcat[DI + u0] = ftanh(cn0) * fsig(a[6]);
      vcat[DI + u1] = ftanh(cn1) * fsig(a[7]);
    }
    __syncthreads();
    {
      const int mm = j & (DB - 1), pp = j >> 7;
      const u16* br = bbW + (size_t)mm * KZ + pp * 288;
      const float* vs = vcat + pp * 288;
      float s0 = 0.f, s1 = 0.f, s2v = 0.f, s3 = 0.f;
#pragma unroll
      for (int kk = 0; kk < 288; kk += 32) {
        fma8(s0, *(const uint4*)(br + kk), vs + kk);
        fma8(s1, *(const uint4*)(br + kk + 8), vs + kk + 8);
        fma8(s2v, *(const uint4*)(br + kk + 16), vs + kk + 16);
        fma8(s3, *(const uint4*)(br + kk + 24), vs + kk + 24);
      }
      fpart[j] = (s0 + s1) + (s2v + s3);
    }
    __syncthreads();
    if (j < DB) Fb2[j] = 1.7159f * ftanh(0.666f * (b_bb + fpart[j] + fpart[j + DB]));
    __syncthreads();
    {
      float Fr[DB];
#pragma unroll
      for (int q = 0; q < 32; ++q) *(float4*)(Fr + 4 * q) = *(const float4*)(Fb2 + 4 * q);
      const u16* rp[8] = {
        f1W + (size_t)u0 * DB, f1W + (size_t)u1 * DB,
        f2W + (size_t)u0 * DB, f2W + (size_t)u1 * DB,
        taW + (size_t)u0 * DB, taW + (size_t)u1 * DB,
        tbW + (size_t)u0 * DB, tbW + (size_t)u1 * DB };
      float sacc[8] = { b_f1_0, b_f1_1, b_f2_0, b_f2_1, b_ta_0, b_ta_1, b_tb_0, b_tb_1 };
#pragma unroll
      for (int rr = 0; rr < 8; ++rr) {
        float acc = sacc[rr];
        const u16* r = rp[rr];
#pragma unroll
        for (int kk = 0; kk < DB; kk += 8) fma8(acc, *(const uint4*)(r + kk), Fr + kk);
        sacc[rr] = acc;
      }
      const float ti0 = fsig(sacc[4] + sacc[6]);
      const float ti1 = fsig(sacc[5] + sacc[7]);
      hprev[u0] = fmaf(ftanh(sacc[0]), 1.f - ti0, ti0 * ftanh(sacc[2]));
      hprev[u1] = fmaf(ftanh(sacc[1]), 1.f - ti1, ti1 * ftanh(sacc[3]));
    }
    __syncthreads();
    if (j < 128) {
      const int l = j & 63;
      float acc = 0.f;
#pragma unroll
      for (int q = 0; q < 8; ++q) acc = fmaf(hprev[q * 64 + l], hwr[q], acc);
#pragma unroll
      for (int off = 32; off > 0; off >>= 1) acc += __shfl_down(acc, off, 64);
      if (l == 0) out[((size_t)b * TT + t) * 2 + (j >> 6)] = acc + hbr;
    }
  }
  out[(size_t)NB * TT * 2 + (size_t)b * DH + u0] = hprev[u0];
  out[(size_t)NB * TT * 2 + (size_t)b * DH + u1] = hprev[u1];
}

extern "C" void kernel_launch(void* const* d_in, const int* in_sizes, int n_in,
                              void* d_out, int out_size, void* d_ws, size_t ws_size,
                              hipStream_t stream) {
  (void)in_sizes; (void)n_in; (void)out_size;

  if (ws_size >= WS_NEED) {
    char* ws = (char*)d_ws;
    int* flag = (int*)ws;
    detect_kernel<<<dim3(1), dim3(64), 0, stream>>>(
        (const u16*)d_in[0], (const u16*)d_in[1], (const u16*)d_in[3], flag);
    pwzx_kernel<<<dim3(8, 32), dim3(256), 0, stream>>>(d_in[1], flag, (u32*)(ws + O_WZX));
    qwz_kernel<<<dim3(2048), dim3(64), 0, stream>>>(d_in[3], flag,
                                                    (u32*)(ws + O_WZ8), (float*)(ws + O_SWZ));
    qbb_kernel<<<dim3(128), dim3(64), 0, stream>>>(d_in[4], flag,
                                                   (u32*)(ws + O_BB8), (float*)(ws + O_SBB));
    qff_kernel<<<dim3(512, 4), dim3(32), 0, stream>>>(d_in[6], d_in[8], d_in[10],
                                                      d_in[12], flag,
                                                      (u32*)(ws + O_FF8), (float*)(ws + O_SFF));
    psmall_kernel<<<dim3(1), dim3(1024), 0, stream>>>(
        d_in[2], d_in[7], d_in[9], d_in[11], d_in[13], d_in[5], d_in[14], d_in[15],
        flag, (float*)(ws + O_BIF), (float*)(ws + O_FFB), (float*)(ws + O_BBBF),
        (u32*)(ws + O_HWP), (float*)(ws + O_HBF));

    scan21<<<dim3(128), dim3(1024), 0, stream>>>(
        d_in[0], flag,
        (const u32*)(ws + O_WZX), (const u32*)(ws + O_WZ8), (const float*)(ws + O_SWZ),
        (const u32*)(ws + O_BB8), (const float*)(ws + O_SBB),
        (const u32*)(ws + O_FF8), (const float*)(ws + O_SFF),
        (const float*)(ws + O_BIF), (const float*)(ws + O_FFB),
        (const float*)(ws + O_BBBF), (const u32*)(ws + O_HWP),
        (const float*)(ws + O_HBF), (float*)d_out);
  } else {
    fb_scan<<<dim3(NB), dim3(256), 0, stream>>>(
        (const u16*)d_in[0],  (const u16*)d_in[1],  (const u16*)d_in[2],
        (const u16*)d_in[3],  (const u16*)d_in[4],  (const u16*)d_in[5],
        (const u16*)d_in[6],  (const u16*)d_in[7],  (const u16*)d_in[8],
        (const u16*)d_in[9],  (const u16*)d_in[10], (const u16*)d_in[11],
        (const u16*)d_in[12], (const u16*)d_in[13], (const u16*)d_in[14],
        (const u16*)d_in[15], (float*)d_out);
  }
}